// Round 2
// baseline (5453.536 us; speedup 1.0000x reference)
//
#include <hip/hip_runtime.h>
#include <hip/hip_bf16.h>

#define MT 14400
#define NCHK 120
#define CLW 120

typedef unsigned short u16;

__device__ __forceinline__ float b2f(u16 u){
  union { unsigned int i; float f; } v; v.i = ((unsigned int)u) << 16; return v.f;
}
__device__ __forceinline__ u16 f2b(float f){
  union { unsigned int i; float f; } v; v.f = f;
  unsigned int x = v.i;
  return (u16)((x + 0x7fffu + ((x >> 16) & 1u)) >> 16);
}
__device__ __forceinline__ float siluf(float x){ return x / (1.f + expf(-x)); }
__device__ __forceinline__ float softplusf(float x){ return (x > 20.f) ? x : log1pf(expf(x)); }

// ---------------- dtype detection ----------------
// Decodes candidate buffer as bf16; true A_log values are in [0, ln16]. If the
// buffer is really fp32, half the u16s are mantissa noise -> |v|>1e9 or NaN.
__global__ __launch_bounds__(256) void k_detect(const u16* __restrict__ a, int n, int* __restrict__ flag){
  __shared__ int found;
  if (threadIdx.x == 0) found = 0;
  __syncthreads();
  int f = 0;
  for (int i = threadIdx.x; i < n; i += 256){
    float v = b2f(a[i]);
    if (!(fabsf(v) <= 1e9f)) f = 1;   // catches huge and NaN
  }
  if (f) atomicOr(&found, 1);
  __syncthreads();
  if (threadIdx.x == 0) *flag = found;
}

// ---------------- param conversion ----------------
struct PTab {
  const void* src[27];
  float* dst[27];
  int n[27];
  int neg[27];   // 1 -> store -exp(v)  (A_log -> A)
};

__global__ __launch_bounds__(256) void k_cvt(PTab tb, const int* __restrict__ flag){
  int id = blockIdx.y;
  int n = tb.n[id];
  int fp32 = *flag;
  float* d = tb.dst[id];
  int ng = tb.neg[id];
  for (int i = blockIdx.x * 256 + threadIdx.x; i < n; i += gridDim.x * 256){
    float v = fp32 ? ((const float*)tb.src[id])[i] : b2f(((const u16*)tb.src[id])[i]);
    if (ng) v = -expf(v);
    d[i] = v;
  }
}

// x ([64][120][120]) -> imgA[0] (fp32) and imgA[1] (transposed image)
__global__ __launch_bounds__(256) void k_cvt_x(const void* __restrict__ x, float* __restrict__ imgA,
                                               const int* __restrict__ flag){
  int idx = blockIdx.x * 256 + threadIdx.x;  // c*MT + l
  int l = idx % MT, c = idx / MT;
  float v = (*flag) ? ((const float*)x)[idx] : b2f(((const u16*)x)[idx]);
  imgA[idx] = v;
  imgA[(size_t)64 * MT + (size_t)c * MT + (l % 120) * 120 + l / 120] = v;
}

// ---------------- layernorm + token-order gather ----------------
__global__ __launch_bounds__(256) void k_prep_xn(const float* __restrict__ img, const float* __restrict__ lng,
                                                 const float* __restrict__ lnb, float* __restrict__ xn,
                                                 int s, int pixelMode){
  int tid = threadIdx.x;
  int q = blockIdx.x * 4 + (tid >> 6);
  int c = tid & 63;
  int g = q / MT, t = q % MT;
  int hw;
  if (pixelMode){
    int b = t / 576, l = t % 576;
    int ph = b / 5, pw = b % 5, nh = l / 24, nw = l % 24;
    hw = (nh * 5 + ph) * 120 + (nw * 5 + pw);
  } else hw = t;
  float v = img[(size_t)g * 64 * MT + (size_t)c * MT + hw];
  float sm = v;
  #pragma unroll
  for (int m = 32; m >= 1; m >>= 1) sm += __shfl_xor(sm, m);
  float mean = sm * (1.f / 64.f);
  float dv = v - mean;
  float s2 = dv * dv;
  #pragma unroll
  for (int m = 32; m >= 1; m >>= 1) s2 += __shfl_xor(s2, m);
  float var = s2 * (1.f / 64.f);
  int i2 = g * 2 + s;
  float o = dv * rsqrtf(var + 1e-5f) * lng[i2 * 64 + c] + lnb[i2 * 64 + c];
  xn[(size_t)g * MT * 64 + (size_t)t * 64 + c] = o;
}

// ---------------- in-projection ----------------
__global__ __launch_bounds__(256) void k_inproj(const float* __restrict__ xn, const float* __restrict__ Wb,
                                                float* __restrict__ xh, float* __restrict__ z,
                                                int s, int pixelMode){
  int gd = blockIdx.y, g = gd >> 1, dir = gd & 1;
  const float* Wm = Wb + (size_t)((g * 2 + s) * 2 + dir) * 256 * 64;
  int t0 = blockIdx.x * 16;
  __shared__ __align__(16) float xt[16][64];
  int tid = threadIdx.x;
  for (int idx = tid; idx < 16 * 64; idx += 256){
    int tt = idx >> 6, k = idx & 63;
    int tq = t0 + tt, src = tq;
    if (dir){
      if (pixelMode){ int b = tq / 576, l = tq % 576; src = b * 576 + 575 - l; }
      else src = MT - 1 - tq;
    }
    xt[tt][k] = xn[(size_t)g * MT * 64 + (size_t)src * 64 + k];
  }
  __syncthreads();
  int tt = tid >> 4, eg = tid & 15;
  float xr[64];
  #pragma unroll
  for (int k = 0; k < 64; k++) xr[k] = xt[tt][k];
  int tq = t0 + tt;
  for (int j = 0; j < 16; j++){
    int e = eg * 16 + j;
    const float4* wr = (const float4*)(Wm + (size_t)e * 64);
    float acc = 0.f;
    #pragma unroll
    for (int k4 = 0; k4 < 16; k4++){
      float4 w4 = wr[k4];
      acc += xr[4*k4+0]*w4.x + xr[4*k4+1]*w4.y + xr[4*k4+2]*w4.z + xr[4*k4+3]*w4.w;
    }
    float* dst = (e < 128) ? xh : z;
    dst[(size_t)gd * MT * 128 + (size_t)tq * 128 + (e & 127)] = acc;
  }
}

// ---------------- causal depthwise conv (K=4) + SiLU ----------------
__global__ __launch_bounds__(256) void k_conv(const float* __restrict__ raw, const float* __restrict__ cw,
                                              const float* __restrict__ cb, float* __restrict__ xhs,
                                              int s, int pixelMode){
  int gd = blockIdx.y, g = gd >> 1, dir = gd & 1;
  int i2 = (g * 2 + s) * 2 + dir;
  int idx = blockIdx.x * 256 + threadIdx.x;  // t*128+ch
  int t = idx >> 7, ch = idx & 127;
  int SL = pixelMode ? 576 : MT;
  int pos = t % SL;
  const float* src = raw + (size_t)gd * MT * 128;
  const float* wrow = cw + (size_t)(i2 * 128 + ch) * 4;
  float acc = cb[i2 * 128 + ch];
  #pragma unroll
  for (int i = 0; i < 4; i++){
    int d = 3 - i;
    if (pos >= d) acc += src[(size_t)(t - d) * 128 + ch] * wrow[i];
  }
  xhs[(size_t)gd * MT * 128 + idx] = siluf(acc);
}

// ---------------- x-projection -> delta(softplus), B, C ----------------
__global__ __launch_bounds__(256) void k_xproj(const float* __restrict__ xhs, const float* __restrict__ xpb,
                                               const float* __restrict__ dtw, const float* __restrict__ dtb,
                                               float* __restrict__ delta, float* __restrict__ Bm,
                                               float* __restrict__ Cm, int s){
  int gd = blockIdx.y, g = gd >> 1, dir = gd & 1;
  int i2 = (g * 2 + s) * 2 + dir;
  const float* XP = xpb + (size_t)i2 * 36 * 128;
  const float* DW = dtw + (size_t)i2 * 128 * 4;
  const float* DB = dtb + (size_t)i2 * 128;
  int t0 = blockIdx.x * 8;
  __shared__ __align__(16) float xv[8][128];
  __shared__ float dbl[8][36];
  int tid = threadIdx.x;
  const float* src = xhs + (size_t)gd * MT * 128 + (size_t)t0 * 128;
  for (int idx = tid; idx < 8 * 128; idx += 256) xv[idx >> 7][idx & 127] = src[idx];
  __syncthreads();
  for (int o = tid; o < 8 * 36; o += 256){
    int tok = o / 36, e = o - tok * 36;
    const float4* a4 = (const float4*)xv[tok];
    const float4* w4 = (const float4*)(XP + (size_t)e * 128);
    float acc = 0.f;
    #pragma unroll 8
    for (int k = 0; k < 32; k++){
      float4 a = a4[k], w = w4[k];
      acc += a.x*w.x + a.y*w.y + a.z*w.z + a.w*w.w;
    }
    dbl[tok][e] = acc;
  }
  __syncthreads();
  for (int o = tid; o < 8 * 128; o += 256){
    int tok = o >> 7, d = o & 127;
    float v = DB[d];
    #pragma unroll
    for (int r = 0; r < 4; r++) v += dbl[tok][r] * DW[d * 4 + r];
    delta[(size_t)gd * MT * 128 + (size_t)(t0 + tok) * 128 + d] = softplusf(v);
  }
  for (int o = tid; o < 8 * 32; o += 256){
    int tok = o >> 5, n = o & 31;
    int t = t0 + tok;
    if (n < 16) Bm[(size_t)gd * MT * 16 + (size_t)t * 16 + n] = dbl[tok][4 + n];
    else        Cm[(size_t)gd * MT * 16 + (size_t)t * 16 + (n - 16)] = dbl[tok][20 + (n - 16)];
  }
}

// ---------------- selective scan (pixel: 25 seq x 576) ----------------
__global__ __launch_bounds__(256) void k_scan_pixel(const float* __restrict__ delta, const float* __restrict__ xhs,
                                                    const float* __restrict__ Bm, const float* __restrict__ Cm,
                                                    const float* __restrict__ z, const float* __restrict__ Ab,
                                                    const float* __restrict__ Db, float* __restrict__ ys, int s){
  int gd = blockIdx.y, g = gd >> 1, dir = gd & 1;
  int i2 = (g * 2 + s) * 2 + dir;
  int blk = blockIdx.x;
  int seq = blk >> 3, chg = blk & 7;
  int tid = threadIdx.x, n = tid & 15, ch = chg * 16 + (tid >> 4);
  float Av = Ab[((size_t)i2 * 128 + ch) * 16 + n];
  float Dv = Db[(size_t)i2 * 128 + ch];
  size_t b128 = (size_t)gd * MT * 128, b16 = (size_t)gd * MT * 16;
  float h = 0.f;
  for (int l = 0; l < 576; l++){
    int t = seq * 576 + l;
    float dt = delta[b128 + (size_t)t * 128 + ch];
    float u  = xhs [b128 + (size_t)t * 128 + ch];
    float bb = Bm[b16 + (size_t)t * 16 + n];
    float cc = Cm[b16 + (size_t)t * 16 + n];
    h = h * expf(dt * Av) + dt * u * bb;
    float p = h * cc;
    p += __shfl_xor(p, 8); p += __shfl_xor(p, 4); p += __shfl_xor(p, 2); p += __shfl_xor(p, 1);
    if (n == 0){
      float zz = z[b128 + (size_t)t * 128 + ch];
      ys[b128 + (size_t)t * 128 + ch] = (p + u * Dv) * siluf(zz);
    }
  }
}

// ---------------- window scan, 3-phase chunked ----------------
__global__ __launch_bounds__(256) void k_scan_win_p1(const float* __restrict__ delta, const float* __restrict__ xhs,
                                                     const float* __restrict__ Bm, const float* __restrict__ Ab,
                                                     float* __restrict__ Acar, float* __restrict__ Bcar, int s){
  int gd = blockIdx.y, g = gd >> 1, dir = gd & 1;
  int i2 = (g * 2 + s) * 2 + dir;
  int flat = blockIdx.x * 256 + threadIdx.x;
  int n = flat & 15, ch = (flat >> 4) & 127, chunk = flat >> 11;
  float Av = Ab[((size_t)i2 * 128 + ch) * 16 + n];
  size_t b128 = (size_t)gd * MT * 128, b16 = (size_t)gd * MT * 16;
  float ap = 1.f, bc = 0.f;
  for (int j = 0; j < CLW; j++){
    int t = chunk * CLW + j;
    float dt = delta[b128 + (size_t)t * 128 + ch];
    float u  = xhs [b128 + (size_t)t * 128 + ch];
    float bb = Bm[b16 + (size_t)t * 16 + n];
    float a = expf(dt * Av);
    bc = bc * a + dt * u * bb;
    ap *= a;
  }
  size_t o = (size_t)gd * NCHK * 2048 + (size_t)chunk * 2048 + ch * 16 + n;
  Acar[o] = ap; Bcar[o] = bc;
}

__global__ __launch_bounds__(256) void k_scan_win_p2(const float* __restrict__ Acar, const float* __restrict__ Bcar,
                                                     float* __restrict__ Hin){
  int flat = blockIdx.x * 256 + threadIdx.x;  // 8192 total
  int cs = flat & 2047, gd = flat >> 11;
  float h = 0.f;
  for (int c = 0; c < NCHK; c++){
    size_t o = (size_t)gd * NCHK * 2048 + (size_t)c * 2048 + cs;
    Hin[o] = h;
    h = Acar[o] * h + Bcar[o];
  }
}

__global__ __launch_bounds__(256) void k_scan_win_p3(const float* __restrict__ delta, const float* __restrict__ xhs,
                                                     const float* __restrict__ Bm, const float* __restrict__ Cm,
                                                     const float* __restrict__ z, const float* __restrict__ Ab,
                                                     const float* __restrict__ Db, const float* __restrict__ Hin,
                                                     float* __restrict__ ys, int s){
  int gd = blockIdx.y, g = gd >> 1, dir = gd & 1;
  int i2 = (g * 2 + s) * 2 + dir;
  int blk = blockIdx.x;
  int chunk = blk >> 3, chg = blk & 7;
  int tid = threadIdx.x, n = tid & 15, ch = chg * 16 + (tid >> 4);
  float Av = Ab[((size_t)i2 * 128 + ch) * 16 + n];
  float Dv = Db[(size_t)i2 * 128 + ch];
  size_t b128 = (size_t)gd * MT * 128, b16 = (size_t)gd * MT * 16;
  float h = Hin[(size_t)gd * NCHK * 2048 + (size_t)chunk * 2048 + ch * 16 + n];
  for (int j = 0; j < CLW; j++){
    int t = chunk * CLW + j;
    float dt = delta[b128 + (size_t)t * 128 + ch];
    float u  = xhs [b128 + (size_t)t * 128 + ch];
    float bb = Bm[b16 + (size_t)t * 16 + n];
    float cc = Cm[b16 + (size_t)t * 16 + n];
    h = h * expf(dt * Av) + dt * u * bb;
    float p = h * cc;
    p += __shfl_xor(p, 8); p += __shfl_xor(p, 4); p += __shfl_xor(p, 2); p += __shfl_xor(p, 1);
    if (n == 0){
      float zz = z[b128 + (size_t)t * 128 + ch];
      ys[b128 + (size_t)t * 128 + ch] = (p + u * Dv) * siluf(zz);
    }
  }
}

// ---------------- out-projection + residual ----------------
__global__ __launch_bounds__(256) void k_outproj_pixel(const float* __restrict__ ys, const float* __restrict__ owb,
                                                       const float* __restrict__ imgA, float* __restrict__ imgB, int s){
  int idx = blockIdx.x * 256 + threadIdx.x;
  int c = idx & 63, q = idx >> 6;
  int t = q % MT, g = q / MT;
  int i2 = g * 2 + s;
  const float4* ow = (const float4*)(owb + (size_t)(i2 * 64 + c) * 128);
  int b = t / 576, l = t % 576;
  int rt = b * 576 + 575 - l;
  const float4* yf = (const float4*)(ys + (size_t)(g * 2 + 0) * MT * 128 + (size_t)t * 128);
  const float4* yb = (const float4*)(ys + (size_t)(g * 2 + 1) * MT * 128 + (size_t)rt * 128);
  float acc = 0.f;
  #pragma unroll 8
  for (int k = 0; k < 32; k++){
    float4 a = yf[k], bb = yb[k], w = ow[k];
    acc += (a.x + bb.x) * w.x + (a.y + bb.y) * w.y + (a.z + bb.z) * w.z + (a.w + bb.w) * w.w;
  }
  int ph = b / 5, pw = b % 5, nh = l / 24, nw = l % 24;
  size_t io = (size_t)g * 64 * MT + (size_t)c * MT + (nh * 5 + ph) * 120 + (nw * 5 + pw);
  imgB[io] = imgA[io] + acc;
}

__global__ __launch_bounds__(256) void k_outproj_win(const float* __restrict__ ys, const float* __restrict__ owb,
                                                     const float* __restrict__ obwb, float* __restrict__ imgA,
                                                     float* __restrict__ imgB, float* __restrict__ xM,
                                                     float* __restrict__ yM, int s, int writeM){
  int idx = blockIdx.x * 256 + threadIdx.x;
  int c = idx & 63, q = idx >> 6;
  int l = q % MT, g = q / MT;
  int i2 = g * 2 + s;
  const float4* ow  = (const float4*)(owb  + (size_t)(i2 * 64 + c) * 128);
  const float4* obw = (const float4*)(obwb + (size_t)(i2 * 64 + c) * 128);
  const float4* yf  = (const float4*)(ys + (size_t)(g * 2 + 0) * MT * 128 + (size_t)l * 128);
  const float4* ybr = (const float4*)(ys + (size_t)(g * 2 + 1) * MT * 128 + (size_t)(MT - 1 - l) * 128);
  const float4* ybd = (const float4*)(ys + (size_t)(g * 2 + 1) * MT * 128 + (size_t)l * 128);
  float accC = 0.f, accF = 0.f, accB = 0.f;
  #pragma unroll 4
  for (int k = 0; k < 32; k++){
    float4 a = yf[k], br = ybr[k], w = ow[k];
    accC += (a.x + br.x) * w.x + (a.y + br.y) * w.y + (a.z + br.z) * w.z + (a.w + br.w) * w.w;
    accF += a.x * w.x + a.y * w.y + a.z * w.z + a.w * w.w;
    float4 bd = ybd[k], wb = obw[k];
    accB += bd.x * wb.x + bd.y * wb.y + bd.z * wb.z + bd.w * wb.w;
  }
  size_t io = (size_t)g * 64 * MT + (size_t)c * MT + l;
  float nb = imgB[io] + accC;
  imgB[io] = nb;
  imgA[io] += nb;
  if (writeM){
    xM[(size_t)g * MT * 64 + (size_t)l * 64 + c] = accF;
    yM[(size_t)g * MT * 64 + (size_t)l * 64 + c] = accB;
  }
}

// ---------------- GCN (hub graph -> closed form) ----------------
__global__ __launch_bounds__(256) void k_gcn1(const float* __restrict__ xM, const float* __restrict__ yM,
                                              const float* __restrict__ W1, float* __restrict__ t1){
  __shared__ __align__(16) float nf[2][256];
  int l0 = blockIdx.x * 2;
  int tid = threadIdx.x;
  for (int idx = tid; idx < 512; idx += 256){
    int ll = idx >> 8, k = idx & 255;
    int l = l0 + ll;
    int which = k >> 6, cc = k & 63;
    const float* srcp = (which == 0) ? xM : (which == 1) ? yM
                       : (which == 2) ? (xM + (size_t)MT * 64) : (yM + (size_t)MT * 64);
    nf[ll][k] = srcp[(size_t)l * 64 + cc];
  }
  __syncthreads();
  int f = tid & 127, ll = tid >> 7;
  const float4* w4 = (const float4*)(W1 + (size_t)f * 256);
  const float4* a4 = (const float4*)nf[ll];
  float acc = 0.f;
  #pragma unroll 8
  for (int k = 0; k < 64; k++){
    float4 a = a4[k], w = w4[k];
    acc += a.x * w.x + a.y * w.y + a.z * w.z + a.w * w.w;
  }
  t1[(size_t)(l0 + ll) * 128 + f] = acc;
}

__global__ __launch_bounds__(128) void k_hub1(const float* __restrict__ t1, float* __restrict__ hubm){
  int f = threadIdx.x;
  float sum = 0.f;
  for (int hb = 0; hb < 450; hb++) sum += t1[(size_t)(hb * 32) * 128 + f];
  hubm[f] = sum * (1.f / 450.f);
}

__global__ __launch_bounds__(128) void k_gcn2(const float* __restrict__ t1, const float* __restrict__ hubm,
                                              const float* __restrict__ b1, const float* __restrict__ W2,
                                              float* __restrict__ t2){
  __shared__ __align__(16) float hbuf[2][128];
  int l0 = blockIdx.x * 2;
  int tid = threadIdx.x;
  for (int idx = tid; idx < 256; idx += 128){
    int ll = idx >> 7, k = idx & 127;
    int l = l0 + ll;
    float raw = ((l & 31) == 0) ? hubm[k] : t1[(size_t)l * 128 + k];
    hbuf[ll][k] = fmaxf(raw + b1[k], 0.f);
  }
  __syncthreads();
  int c = tid & 63, ll = tid >> 6;
  const float4* w4 = (const float4*)(W2 + (size_t)c * 128);
  const float4* a4 = (const float4*)hbuf[ll];
  float acc = 0.f;
  #pragma unroll 8
  for (int k = 0; k < 32; k++){
    float4 a = a4[k], w = w4[k];
    acc += a.x * w.x + a.y * w.y + a.z * w.z + a.w * w.w;
  }
  t2[(size_t)(l0 + ll) * 64 + c] = acc;
}

__global__ __launch_bounds__(64) void k_hub2(const float* __restrict__ t2, float* __restrict__ hubm2){
  int c = threadIdx.x;
  float sum = 0.f;
  for (int hb = 0; hb < 450; hb++) sum += t2[(size_t)(hb * 32) * 64 + c];
  hubm2[c] = sum * (1.f / 450.f);
}

__global__ __launch_bounds__(256) void k_final(const void* __restrict__ x, const float* __restrict__ t2,
                                               const float* __restrict__ hubm2, const float* __restrict__ b2,
                                               const float* __restrict__ imgA, void* __restrict__ out,
                                               const int* __restrict__ flag){
  int idx = blockIdx.x * 256 + threadIdx.x;  // c*MT + l
  int l = idx % MT, c = idx / MT;
  int fp32 = *flag;
  float gval = (((l & 31) == 0) ? hubm2[c] : t2[(size_t)l * 64 + c]) + b2[c];
  float a0 = imgA[idx];
  float a1 = imgA[(size_t)64 * MT + (size_t)c * MT + (l % 120) * 120 + l / 120];
  float xv = fp32 ? ((const float*)x)[idx] : b2f(((const u16*)x)[idx]);
  float val = gval + xv + a0 + a1;
  if (fp32) ((float*)out)[idx] = val;
  else      ((u16*)out)[idx] = f2b(val);
}

extern "C" void kernel_launch(void* const* d_in, const int* in_sizes, int n_in,
                              void* d_out, int out_size, void* d_ws, size_t ws_size,
                              hipStream_t stream){
  int I_X=0,I_PIW=1,I_PCW=2,I_PCB=3,I_PXP=4,I_PDTW=5,I_PDTB=6,I_PAL=7,I_PD=8,I_PLG=9,I_PLB=10,
      I_WIW=11,I_WCW=12,I_WCB=13,I_WXP=14,I_WDTW=15,I_WDTB=16,I_WAL=17,I_WD=18,I_WLG=19,I_WLB=20,
      I_POW=21,I_WOW=22,I_WOBW=23,I_G1=24,I_GB1=25,I_G2=26,I_GB2=27;
  if (n_in >= 28 && in_sizes[9] == 131072){
    I_WIW=9;I_WCW=10;I_WCB=11;I_WXP=12;I_WDTW=13;I_WDTB=14;I_WAL=15;I_WD=16;
    I_PLG=17;I_PLB=18;I_WLG=19;I_WLB=20;
  }
  if (n_in < 28 || in_sizes[I_PIW] != 131072 || out_size != 921600) return;

  float* Wp = (float*)d_ws;
  size_t off = 0;
  auto alloc = [&](size_t n){ size_t r = off; off += (n + 63) & ~(size_t)63; return r; };
  size_t oFlag=alloc(64);
  size_t oPIW=alloc(131072), oPCW=alloc(4096), oPCB=alloc(1024), oPXP=alloc(36864),
         oPDTW=alloc(4096), oPDTB=alloc(1024), oPA=alloc(16384), oPD=alloc(1024),
         oPLG=alloc(256), oPLB=alloc(256);
  size_t oWIW=alloc(131072), oWCW=alloc(4096), oWCB=alloc(1024), oWXP=alloc(36864),
         oWDTW=alloc(4096), oWDTB=alloc(1024), oWA=alloc(16384), oWD=alloc(1024),
         oWLG=alloc(256), oWLB=alloc(256);
  size_t oPOW=alloc(32768), oWOW=alloc(32768), oWOBW=alloc(32768),
         oG1=alloc(32768), oGB1=alloc(128), oG2=alloc(8192), oGB2=alloc(64);
  size_t oImgA=alloc(2UL*64*MT), oImgB=alloc(2UL*64*MT), oXn=alloc(2UL*MT*64);
  size_t oRaw=alloc(4UL*MT*128);             // xh_raw; aliased as ys after conv
  size_t oZ=alloc(4UL*MT*128), oXhs=alloc(4UL*MT*128), oDelta=alloc(4UL*MT*128);
  size_t oBm=alloc(4UL*MT*16), oCm=alloc(4UL*MT*16);
  size_t oAc=alloc(4UL*NCHK*2048), oBc=alloc(4UL*NCHK*2048), oHin=alloc(4UL*NCHK*2048);
  size_t oXM=alloc(2UL*MT*64), oYM=alloc(2UL*MT*64);
  size_t oT1=alloc((size_t)MT*128), oHub1=alloc(128), oT2=alloc((size_t)MT*64), oHub2=alloc(64);
  if (ws_size < off * sizeof(float)) return;   // ~190 MB needed

  int* flag = (int*)(Wp + oFlag);
  k_detect<<<dim3(1), dim3(256), 0, stream>>>((const u16*)d_in[I_PAL], 16384, flag);

  PTab tb;
  int ti = 0;
  auto add = [&](int inIdx, size_t o, int n, int neg){
    tb.src[ti] = d_in[inIdx]; tb.dst[ti] = Wp + o; tb.n[ti] = n; tb.neg[ti] = neg; ti++;
  };
  add(I_PIW,oPIW,131072,0); add(I_PCW,oPCW,4096,0); add(I_PCB,oPCB,1024,0); add(I_PXP,oPXP,36864,0);
  add(I_PDTW,oPDTW,4096,0); add(I_PDTB,oPDTB,1024,0); add(I_PAL,oPA,16384,1); add(I_PD,oPD,1024,0);
  add(I_PLG,oPLG,256,0); add(I_PLB,oPLB,256,0);
  add(I_WIW,oWIW,131072,0); add(I_WCW,oWCW,4096,0); add(I_WCB,oWCB,1024,0); add(I_WXP,oWXP,36864,0);
  add(I_WDTW,oWDTW,4096,0); add(I_WDTB,oWDTB,1024,0); add(I_WAL,oWA,16384,1); add(I_WD,oWD,1024,0);
  add(I_WLG,oWLG,256,0); add(I_WLB,oWLB,256,0);
  add(I_POW,oPOW,32768,0); add(I_WOW,oWOW,32768,0); add(I_WOBW,oWOBW,32768,0);
  add(I_G1,oG1,32768,0); add(I_GB1,oGB1,128,0); add(I_G2,oG2,8192,0); add(I_GB2,oGB2,64,0);

  k_cvt<<<dim3(128, 27), dim3(256), 0, stream>>>(tb, flag);
  k_cvt_x<<<dim3(3600), dim3(256), 0, stream>>>(d_in[I_X], Wp + oImgA, flag);

  float *imgA = Wp+oImgA, *imgB = Wp+oImgB, *xn = Wp+oXn, *raw = Wp+oRaw, *ys = Wp+oRaw,
        *zz = Wp+oZ, *xhs = Wp+oXhs, *delta = Wp+oDelta, *Bm = Wp+oBm, *Cm = Wp+oCm,
        *Ac = Wp+oAc, *Bc = Wp+oBc, *Hin = Wp+oHin, *xM = Wp+oXM, *yM = Wp+oYM;

  for (int s = 0; s < 2; s++){
    k_prep_xn<<<dim3(7200), dim3(256), 0, stream>>>(imgA, Wp+oPLG, Wp+oPLB, xn, s, 1);
    k_inproj <<<dim3(900, 4), dim3(256), 0, stream>>>(xn, Wp+oPIW, raw, zz, s, 1);
    k_conv   <<<dim3(7200, 4), dim3(256), 0, stream>>>(raw, Wp+oPCW, Wp+oPCB, xhs, s, 1);
    k_xproj  <<<dim3(1800, 4), dim3(256), 0, stream>>>(xhs, Wp+oPXP, Wp+oPDTW, Wp+oPDTB, delta, Bm, Cm, s);
    k_scan_pixel<<<dim3(200, 4), dim3(256), 0, stream>>>(delta, xhs, Bm, Cm, zz, Wp+oPA, Wp+oPD, ys, s);
    k_outproj_pixel<<<dim3(7200), dim3(256), 0, stream>>>(ys, Wp+oPOW, imgA, imgB, s);

    k_prep_xn<<<dim3(7200), dim3(256), 0, stream>>>(imgB, Wp+oWLG, Wp+oWLB, xn, s, 0);
    k_inproj <<<dim3(900, 4), dim3(256), 0, stream>>>(xn, Wp+oWIW, raw, zz, s, 0);
    k_conv   <<<dim3(7200, 4), dim3(256), 0, stream>>>(raw, Wp+oWCW, Wp+oWCB, xhs, s, 0);
    k_xproj  <<<dim3(1800, 4), dim3(256), 0, stream>>>(xhs, Wp+oWXP, Wp+oWDTW, Wp+oWDTB, delta, Bm, Cm, s);
    k_scan_win_p1<<<dim3(960, 4), dim3(256), 0, stream>>>(delta, xhs, Bm, Wp+oWA, Ac, Bc, s);
    k_scan_win_p2<<<dim3(32), dim3(256), 0, stream>>>(Ac, Bc, Hin);
    k_scan_win_p3<<<dim3(960, 4), dim3(256), 0, stream>>>(delta, xhs, Bm, Cm, zz, Wp+oWA, Wp+oWD, Hin, ys, s);
    k_outproj_win<<<dim3(7200), dim3(256), 0, stream>>>(ys, Wp+oWOW, Wp+oWOBW, imgA, imgB, xM, yM, s, (s == 1) ? 1 : 0);
  }

  k_gcn1<<<dim3(7200), dim3(256), 0, stream>>>(xM, yM, Wp+oG1, Wp+oT1);
  k_hub1<<<dim3(1), dim3(128), 0, stream>>>(Wp+oT1, Wp+oHub1);
  k_gcn2<<<dim3(7200), dim3(128), 0, stream>>>(Wp+oT1, Wp+oHub1, Wp+oGB1, Wp+oG2, Wp+oT2);
  k_hub2<<<dim3(1), dim3(64), 0, stream>>>(Wp+oT2, Wp+oHub2);
  k_final<<<dim3(3600), dim3(256), 0, stream>>>(d_in[I_X], Wp+oT2, Wp+oHub2, Wp+oGB2, imgA, d_out, flag);
}

// Round 3
// 4510.289 us; speedup vs baseline: 1.2091x; 1.2091x over previous
//
#include <hip/hip_runtime.h>
#include <hip/hip_bf16.h>

#define MT 14400
#define WNC 150     // window scan chunks
#define WCL 96      // window chunk length (WNC*WCL = MT)
#define PT 16       // LDS tile (timesteps) for all scans

typedef unsigned short u16;

__device__ __forceinline__ float b2f(u16 u){
  union { unsigned int i; float f; } v; v.i = ((unsigned int)u) << 16; return v.f;
}
__device__ __forceinline__ u16 f2b(float f){
  union { unsigned int i; float f; } v; v.f = f;
  unsigned int x = v.i;
  return (u16)((x + 0x7fffu + ((x >> 16) & 1u)) >> 16);
}
__device__ __forceinline__ float siluf(float x){ return x / (1.f + expf(-x)); }
__device__ __forceinline__ float softplusf(float x){ return (x > 20.f) ? x : log1pf(expf(x)); }

// ---------------- dtype detection ----------------
__global__ __launch_bounds__(256) void k_detect(const u16* __restrict__ a, int n, int* __restrict__ flag){
  __shared__ int found;
  if (threadIdx.x == 0) found = 0;
  __syncthreads();
  int f = 0;
  for (int i = threadIdx.x; i < n; i += 256){
    float v = b2f(a[i]);
    if (!(fabsf(v) <= 1e9f)) f = 1;
  }
  if (f) atomicOr(&found, 1);
  __syncthreads();
  if (threadIdx.x == 0) *flag = found;
}

// ---------------- param conversion ----------------
struct PTab {
  const void* src[27];
  float* dst[27];
  int n[27];
  int neg[27];   // 1 -> store -exp(v)*log2(e)  (A_log -> A2 for exp2f scans)
};

__global__ __launch_bounds__(256) void k_cvt(PTab tb, const int* __restrict__ flag){
  int id = blockIdx.y;
  int n = tb.n[id];
  int fp32 = *flag;
  float* d = tb.dst[id];
  int ng = tb.neg[id];
  for (int i = blockIdx.x * 256 + threadIdx.x; i < n; i += gridDim.x * 256){
    float v = fp32 ? ((const float*)tb.src[id])[i] : b2f(((const u16*)tb.src[id])[i]);
    if (ng) v = -expf(v) * 1.4426950408889634f;
    d[i] = v;
  }
}

__global__ __launch_bounds__(256) void k_cvt_x(const void* __restrict__ x, float* __restrict__ imgA,
                                               const int* __restrict__ flag){
  int idx = blockIdx.x * 256 + threadIdx.x;  // c*MT + l
  int l = idx % MT, c = idx / MT;
  float v = (*flag) ? ((const float*)x)[idx] : b2f(((const u16*)x)[idx]);
  imgA[idx] = v;
  imgA[(size_t)64 * MT + (size_t)c * MT + (l % 120) * 120 + l / 120] = v;
}

// ---------------- layernorm + token-order gather ----------------
__global__ __launch_bounds__(256) void k_prep_xn(const float* __restrict__ img, const float* __restrict__ lng,
                                                 const float* __restrict__ lnb, float* __restrict__ xn,
                                                 int s, int pixelMode){
  int tid = threadIdx.x;
  int q = blockIdx.x * 4 + (tid >> 6);
  int c = tid & 63;
  int g = q / MT, t = q % MT;
  int hw;
  if (pixelMode){
    int b = t / 576, l = t % 576;
    int ph = b / 5, pw = b % 5, nh = l / 24, nw = l % 24;
    hw = (nh * 5 + ph) * 120 + (nw * 5 + pw);
  } else hw = t;
  float v = img[(size_t)g * 64 * MT + (size_t)c * MT + hw];
  float sm = v;
  #pragma unroll
  for (int m = 32; m >= 1; m >>= 1) sm += __shfl_xor(sm, m);
  float mean = sm * (1.f / 64.f);
  float dv = v - mean;
  float s2 = dv * dv;
  #pragma unroll
  for (int m = 32; m >= 1; m >>= 1) s2 += __shfl_xor(s2, m);
  float var = s2 * (1.f / 64.f);
  int i2 = g * 2 + s;
  float o = dv * rsqrtf(var + 1e-5f) * lng[i2 * 64 + c] + lnb[i2 * 64 + c];
  xn[(size_t)g * MT * 64 + (size_t)t * 64 + c] = o;
}

// ---------------- in-projection ----------------
__global__ __launch_bounds__(256) void k_inproj(const float* __restrict__ xn, const float* __restrict__ Wb,
                                                float* __restrict__ xh, float* __restrict__ z,
                                                int s, int pixelMode){
  int gd = blockIdx.y, g = gd >> 1, dir = gd & 1;
  const float* Wm = Wb + (size_t)((g * 2 + s) * 2 + dir) * 256 * 64;
  int t0 = blockIdx.x * 16;
  __shared__ __align__(16) float xt[16][64];
  int tid = threadIdx.x;
  for (int idx = tid; idx < 16 * 64; idx += 256){
    int tt = idx >> 6, k = idx & 63;
    int tq = t0 + tt, src = tq;
    if (dir){
      if (pixelMode){ int b = tq / 576, l = tq % 576; src = b * 576 + 575 - l; }
      else src = MT - 1 - tq;
    }
    xt[tt][k] = xn[(size_t)g * MT * 64 + (size_t)src * 64 + k];
  }
  __syncthreads();
  int tt = tid >> 4, eg = tid & 15;
  float xr[64];
  #pragma unroll
  for (int k = 0; k < 64; k++) xr[k] = xt[tt][k];
  int tq = t0 + tt;
  for (int j = 0; j < 16; j++){
    int e = eg * 16 + j;
    const float4* wr = (const float4*)(Wm + (size_t)e * 64);
    float acc = 0.f;
    #pragma unroll
    for (int k4 = 0; k4 < 16; k4++){
      float4 w4 = wr[k4];
      acc += xr[4*k4+0]*w4.x + xr[4*k4+1]*w4.y + xr[4*k4+2]*w4.z + xr[4*k4+3]*w4.w;
    }
    float* dst = (e < 128) ? xh : z;
    dst[(size_t)gd * MT * 128 + (size_t)tq * 128 + (e & 127)] = acc;
  }
}

// ---------------- causal depthwise conv (K=4) + SiLU ----------------
__global__ __launch_bounds__(256) void k_conv(const float* __restrict__ raw, const float* __restrict__ cw,
                                              const float* __restrict__ cb, float* __restrict__ xhs,
                                              int s, int pixelMode){
  int gd = blockIdx.y, g = gd >> 1, dir = gd & 1;
  int i2 = (g * 2 + s) * 2 + dir;
  int idx = blockIdx.x * 256 + threadIdx.x;  // t*128+ch
  int t = idx >> 7, ch = idx & 127;
  int SL = pixelMode ? 576 : MT;
  int pos = t % SL;
  const float* src = raw + (size_t)gd * MT * 128;
  const float* wrow = cw + (size_t)(i2 * 128 + ch) * 4;
  float acc = cb[i2 * 128 + ch];
  #pragma unroll
  for (int i = 0; i < 4; i++){
    int d = 3 - i;
    if (pos >= d) acc += src[(size_t)(t - d) * 128 + ch] * wrow[i];
  }
  xhs[(size_t)gd * MT * 128 + idx] = siluf(acc);
}

// ---------------- x-projection -> delta(softplus), B, C ----------------
__global__ __launch_bounds__(256) void k_xproj(const float* __restrict__ xhs, const float* __restrict__ xpb,
                                               const float* __restrict__ dtw, const float* __restrict__ dtb,
                                               float* __restrict__ delta, float* __restrict__ Bm,
                                               float* __restrict__ Cm, int s){
  int gd = blockIdx.y, g = gd >> 1, dir = gd & 1;
  int i2 = (g * 2 + s) * 2 + dir;
  const float* XP = xpb + (size_t)i2 * 36 * 128;
  const float* DW = dtw + (size_t)i2 * 128 * 4;
  const float* DB = dtb + (size_t)i2 * 128;
  int t0 = blockIdx.x * 8;
  __shared__ __align__(16) float xv[8][128];
  __shared__ float dbl[8][36];
  int tid = threadIdx.x;
  const float* src = xhs + (size_t)gd * MT * 128 + (size_t)t0 * 128;
  for (int idx = tid; idx < 8 * 128; idx += 256) xv[idx >> 7][idx & 127] = src[idx];
  __syncthreads();
  for (int o = tid; o < 8 * 36; o += 256){
    int tok = o / 36, e = o - tok * 36;
    const float4* a4 = (const float4*)xv[tok];
    const float4* w4 = (const float4*)(XP + (size_t)e * 128);
    float acc = 0.f;
    #pragma unroll 8
    for (int k = 0; k < 32; k++){
      float4 a = a4[k], w = w4[k];
      acc += a.x*w.x + a.y*w.y + a.z*w.z + a.w*w.w;
    }
    dbl[tok][e] = acc;
  }
  __syncthreads();
  for (int o = tid; o < 8 * 128; o += 256){
    int tok = o >> 7, d = o & 127;
    float v = DB[d];
    #pragma unroll
    for (int r = 0; r < 4; r++) v += dbl[tok][r] * DW[d * 4 + r];
    delta[(size_t)gd * MT * 128 + (size_t)(t0 + tok) * 128 + d] = softplusf(v);
  }
  for (int o = tid; o < 8 * 32; o += 256){
    int tok = o >> 5, n = o & 31;
    int t = t0 + tok;
    if (n < 16) Bm[(size_t)gd * MT * 16 + (size_t)t * 16 + n] = dbl[tok][4 + n];
    else        Cm[(size_t)gd * MT * 16 + (size_t)t * 16 + (n - 16)] = dbl[tok][20 + (n - 16)];
  }
}

// ---------------- selective scan, LDS-staged ----------------
// block = 256 threads; thread owns 8 (ch,n) states: ch = tid>>1, n = (tid&1)*8 + j
// pixel: one block per (seq 0..24, gd); 36 tiles of 16 steps
__global__ __launch_bounds__(256) void k_scan_pixel(const float* __restrict__ delta, const float* __restrict__ xhs,
                                                    const float* __restrict__ Bm, const float* __restrict__ Cm,
                                                    const float* __restrict__ zz, const float* __restrict__ A2b,
                                                    const float* __restrict__ Db, float* __restrict__ ys, int s){
  int gd = blockIdx.y, g = gd >> 1, dir = gd & 1;
  int i2 = (g * 2 + s) * 2 + dir;
  int seq = blockIdx.x;
  int tid = threadIdx.x, ch = tid >> 1, nb = (tid & 1) * 8;
  float A2[8], h[8];
  #pragma unroll
  for (int j = 0; j < 8; j++){
    A2[j] = A2b[((size_t)i2 * 128 + ch) * 16 + nb + j];
    h[j] = 0.f;
  }
  float Dv = Db[(size_t)i2 * 128 + ch];
  size_t so = (size_t)gd * MT * 128 + (size_t)seq * 576 * 128;
  size_t bo = (size_t)gd * MT * 16  + (size_t)seq * 576 * 16;
  __shared__ __align__(16) float sd[2][PT * 128];
  __shared__ __align__(16) float su[2][PT * 128];
  __shared__ __align__(16) float sb[2][PT * 16];
  __shared__ __align__(16) float sc[2][PT * 16];
  __shared__ __align__(16) float sy[PT * 128];
  float4 rd0, rd1, ru0, ru1; float rb, rc;
  {
    const float4* d4 = (const float4*)(delta + so);
    const float4* u4 = (const float4*)(xhs + so);
    rd0 = d4[2 * tid]; rd1 = d4[2 * tid + 1];
    ru0 = u4[2 * tid]; ru1 = u4[2 * tid + 1];
    rb = (Bm + bo)[tid]; rc = (Cm + bo)[tid];
  }
  const int NT = 576 / PT;
  for (int tile = 0; tile < NT; tile++){
    int bs = tile & 1;
    __syncthreads();
    ((float4*)sd[bs])[2 * tid] = rd0; ((float4*)sd[bs])[2 * tid + 1] = rd1;
    ((float4*)su[bs])[2 * tid] = ru0; ((float4*)su[bs])[2 * tid + 1] = ru1;
    sb[bs][tid] = rb; sc[bs][tid] = rc;
    __syncthreads();
    if (tile + 1 < NT){
      const float4* d4 = (const float4*)(delta + so + (size_t)(tile + 1) * PT * 128);
      const float4* u4 = (const float4*)(xhs + so + (size_t)(tile + 1) * PT * 128);
      rd0 = d4[2 * tid]; rd1 = d4[2 * tid + 1];
      ru0 = u4[2 * tid]; ru1 = u4[2 * tid + 1];
      rb = (Bm + bo + (size_t)(tile + 1) * PT * 16)[tid];
      rc = (Cm + bo + (size_t)(tile + 1) * PT * 16)[tid];
    }
    #pragma unroll
    for (int t = 0; t < PT; t++){
      float dt = sd[bs][t * 128 + ch];
      float u  = su[bs][t * 128 + ch];
      float du = dt * u;
      float acc = 0.f;
      #pragma unroll
      for (int j = 0; j < 8; j++){
        float e = exp2f(dt * A2[j]);
        h[j] = h[j] * e + du * sb[bs][t * 16 + nb + j];
        acc += h[j] * sc[bs][t * 16 + nb + j];
      }
      acc += __shfl_xor(acc, 1);
      if (!(tid & 1)) sy[t * 128 + ch] = acc + u * Dv;
    }
    __syncthreads();
    {
      const float4* z4 = (const float4*)(zz + so + (size_t)tile * PT * 128);
      float4* y4 = (float4*)(ys + so + (size_t)tile * PT * 128);
      #pragma unroll
      for (int i = 0; i < 2; i++){
        int f = 2 * tid + i;
        float4 yv = ((float4*)sy)[f];
        float4 zv = z4[f];
        yv.x *= siluf(zv.x); yv.y *= siluf(zv.y); yv.z *= siluf(zv.z); yv.w *= siluf(zv.w);
        y4[f] = yv;
      }
    }
  }
}

// window p1: per-chunk (prod a, carry b); one block per (chunk, gd); 6 tiles of 16
__global__ __launch_bounds__(256) void k_scan_win_p1(const float* __restrict__ delta, const float* __restrict__ xhs,
                                                     const float* __restrict__ Bm, const float* __restrict__ A2b,
                                                     float* __restrict__ Acar, float* __restrict__ Bcar, int s){
  int gd = blockIdx.y, g = gd >> 1, dir = gd & 1;
  int i2 = (g * 2 + s) * 2 + dir;
  int chunk = blockIdx.x;
  int tid = threadIdx.x, ch = tid >> 1, nb = (tid & 1) * 8;
  float A2[8], ap[8], bc[8];
  #pragma unroll
  for (int j = 0; j < 8; j++){
    A2[j] = A2b[((size_t)i2 * 128 + ch) * 16 + nb + j];
    ap[j] = 1.f; bc[j] = 0.f;
  }
  size_t so = (size_t)gd * MT * 128 + (size_t)chunk * WCL * 128;
  size_t bo = (size_t)gd * MT * 16  + (size_t)chunk * WCL * 16;
  __shared__ __align__(16) float sd[2][PT * 128];
  __shared__ __align__(16) float su[2][PT * 128];
  __shared__ __align__(16) float sb[2][PT * 16];
  float4 rd0, rd1, ru0, ru1; float rb;
  {
    const float4* d4 = (const float4*)(delta + so);
    const float4* u4 = (const float4*)(xhs + so);
    rd0 = d4[2 * tid]; rd1 = d4[2 * tid + 1];
    ru0 = u4[2 * tid]; ru1 = u4[2 * tid + 1];
    rb = (Bm + bo)[tid];
  }
  const int NT = WCL / PT;
  for (int tile = 0; tile < NT; tile++){
    int bs = tile & 1;
    __syncthreads();
    ((float4*)sd[bs])[2 * tid] = rd0; ((float4*)sd[bs])[2 * tid + 1] = rd1;
    ((float4*)su[bs])[2 * tid] = ru0; ((float4*)su[bs])[2 * tid + 1] = ru1;
    sb[bs][tid] = rb;
    __syncthreads();
    if (tile + 1 < NT){
      const float4* d4 = (const float4*)(delta + so + (size_t)(tile + 1) * PT * 128);
      const float4* u4 = (const float4*)(xhs + so + (size_t)(tile + 1) * PT * 128);
      rd0 = d4[2 * tid]; rd1 = d4[2 * tid + 1];
      ru0 = u4[2 * tid]; ru1 = u4[2 * tid + 1];
      rb = (Bm + bo + (size_t)(tile + 1) * PT * 16)[tid];
    }
    #pragma unroll
    for (int t = 0; t < PT; t++){
      float dt = sd[bs][t * 128 + ch];
      float u  = su[bs][t * 128 + ch];
      float du = dt * u;
      #pragma unroll
      for (int j = 0; j < 8; j++){
        float e = exp2f(dt * A2[j]);
        bc[j] = bc[j] * e + du * sb[bs][t * 16 + nb + j];
        ap[j] *= e;
      }
    }
  }
  size_t o = ((size_t)gd * WNC + chunk) * 2048 + (size_t)ch * 16 + nb;
  float4* A4 = (float4*)(Acar + o);
  float4* B4 = (float4*)(Bcar + o);
  A4[0] = make_float4(ap[0], ap[1], ap[2], ap[3]);
  A4[1] = make_float4(ap[4], ap[5], ap[6], ap[7]);
  B4[0] = make_float4(bc[0], bc[1], bc[2], bc[3]);
  B4[1] = make_float4(bc[4], bc[5], bc[6], bc[7]);
}

__global__ __launch_bounds__(256) void k_scan_win_p2(const float* __restrict__ Acar, const float* __restrict__ Bcar,
                                                     float* __restrict__ Hin){
  int flat = blockIdx.x * 256 + threadIdx.x;  // 8192 total
  int cs = flat & 2047, gd = flat >> 11;
  float h = 0.f;
  for (int c = 0; c < WNC; c++){
    size_t o = ((size_t)gd * WNC + c) * 2048 + cs;
    Hin[o] = h;
    h = Acar[o] * h + Bcar[o];
  }
}

__global__ __launch_bounds__(256) void k_scan_win_p3(const float* __restrict__ delta, const float* __restrict__ xhs,
                                                     const float* __restrict__ Bm, const float* __restrict__ Cm,
                                                     const float* __restrict__ zz, const float* __restrict__ A2b,
                                                     const float* __restrict__ Db, const float* __restrict__ Hin,
                                                     float* __restrict__ ys, int s){
  int gd = blockIdx.y, g = gd >> 1, dir = gd & 1;
  int i2 = (g * 2 + s) * 2 + dir;
  int chunk = blockIdx.x;
  int tid = threadIdx.x, ch = tid >> 1, nb = (tid & 1) * 8;
  float A2[8], h[8];
  size_t ho = ((size_t)gd * WNC + chunk) * 2048 + (size_t)ch * 16 + nb;
  {
    const float4* H4 = (const float4*)(Hin + ho);
    float4 h0 = H4[0], h1 = H4[1];
    h[0]=h0.x; h[1]=h0.y; h[2]=h0.z; h[3]=h0.w;
    h[4]=h1.x; h[5]=h1.y; h[6]=h1.z; h[7]=h1.w;
  }
  #pragma unroll
  for (int j = 0; j < 8; j++) A2[j] = A2b[((size_t)i2 * 128 + ch) * 16 + nb + j];
  float Dv = Db[(size_t)i2 * 128 + ch];
  size_t so = (size_t)gd * MT * 128 + (size_t)chunk * WCL * 128;
  size_t bo = (size_t)gd * MT * 16  + (size_t)chunk * WCL * 16;
  __shared__ __align__(16) float sd[2][PT * 128];
  __shared__ __align__(16) float su[2][PT * 128];
  __shared__ __align__(16) float sb[2][PT * 16];
  __shared__ __align__(16) float sc[2][PT * 16];
  __shared__ __align__(16) float sy[PT * 128];
  float4 rd0, rd1, ru0, ru1; float rb, rc;
  {
    const float4* d4 = (const float4*)(delta + so);
    const float4* u4 = (const float4*)(xhs + so);
    rd0 = d4[2 * tid]; rd1 = d4[2 * tid + 1];
    ru0 = u4[2 * tid]; ru1 = u4[2 * tid + 1];
    rb = (Bm + bo)[tid]; rc = (Cm + bo)[tid];
  }
  const int NT = WCL / PT;
  for (int tile = 0; tile < NT; tile++){
    int bs = tile & 1;
    __syncthreads();
    ((float4*)sd[bs])[2 * tid] = rd0; ((float4*)sd[bs])[2 * tid + 1] = rd1;
    ((float4*)su[bs])[2 * tid] = ru0; ((float4*)su[bs])[2 * tid + 1] = ru1;
    sb[bs][tid] = rb; sc[bs][tid] = rc;
    __syncthreads();
    if (tile + 1 < NT){
      const float4* d4 = (const float4*)(delta + so + (size_t)(tile + 1) * PT * 128);
      const float4* u4 = (const float4*)(xhs + so + (size_t)(tile + 1) * PT * 128);
      rd0 = d4[2 * tid]; rd1 = d4[2 * tid + 1];
      ru0 = u4[2 * tid]; ru1 = u4[2 * tid + 1];
      rb = (Bm + bo + (size_t)(tile + 1) * PT * 16)[tid];
      rc = (Cm + bo + (size_t)(tile + 1) * PT * 16)[tid];
    }
    #pragma unroll
    for (int t = 0; t < PT; t++){
      float dt = sd[bs][t * 128 + ch];
      float u  = su[bs][t * 128 + ch];
      float du = dt * u;
      float acc = 0.f;
      #pragma unroll
      for (int j = 0; j < 8; j++){
        float e = exp2f(dt * A2[j]);
        h[j] = h[j] * e + du * sb[bs][t * 16 + nb + j];
        acc += h[j] * sc[bs][t * 16 + nb + j];
      }
      acc += __shfl_xor(acc, 1);
      if (!(tid & 1)) sy[t * 128 + ch] = acc + u * Dv;
    }
    __syncthreads();
    {
      const float4* z4 = (const float4*)(zz + so + (size_t)tile * PT * 128);
      float4* y4 = (float4*)(ys + so + (size_t)tile * PT * 128);
      #pragma unroll
      for (int i = 0; i < 2; i++){
        int f = 2 * tid + i;
        float4 yv = ((float4*)sy)[f];
        float4 zv = z4[f];
        yv.x *= siluf(zv.x); yv.y *= siluf(zv.y); yv.z *= siluf(zv.z); yv.w *= siluf(zv.w);
        y4[f] = yv;
      }
    }
  }
}

// ---------------- out-projection + residual ----------------
__global__ __launch_bounds__(256) void k_outproj_pixel(const float* __restrict__ ys, const float* __restrict__ owb,
                                                       const float* __restrict__ imgA, float* __restrict__ imgB, int s){
  int idx = blockIdx.x * 256 + threadIdx.x;
  int c = idx & 63, q = idx >> 6;
  int t = q % MT, g = q / MT;
  int i2 = g * 2 + s;
  const float4* ow = (const float4*)(owb + (size_t)(i2 * 64 + c) * 128);
  int b = t / 576, l = t % 576;
  int rt = b * 576 + 575 - l;
  const float4* yf = (const float4*)(ys + (size_t)(g * 2 + 0) * MT * 128 + (size_t)t * 128);
  const float4* yb = (const float4*)(ys + (size_t)(g * 2 + 1) * MT * 128 + (size_t)rt * 128);
  float acc = 0.f;
  #pragma unroll 8
  for (int k = 0; k < 32; k++){
    float4 a = yf[k], bb = yb[k], w = ow[k];
    acc += (a.x + bb.x) * w.x + (a.y + bb.y) * w.y + (a.z + bb.z) * w.z + (a.w + bb.w) * w.w;
  }
  int ph = b / 5, pw = b % 5, nh = l / 24, nw = l % 24;
  size_t io = (size_t)g * 64 * MT + (size_t)c * MT + (nh * 5 + ph) * 120 + (nw * 5 + pw);
  imgB[io] = imgA[io] + acc;
}

__global__ __launch_bounds__(256) void k_outproj_win(const float* __restrict__ ys, const float* __restrict__ owb,
                                                     const float* __restrict__ obwb, float* __restrict__ imgA,
                                                     float* __restrict__ imgB, float* __restrict__ xM,
                                                     float* __restrict__ yM, int s, int writeM){
  int idx = blockIdx.x * 256 + threadIdx.x;
  int c = idx & 63, q = idx >> 6;
  int l = q % MT, g = q / MT;
  int i2 = g * 2 + s;
  const float4* ow  = (const float4*)(owb  + (size_t)(i2 * 64 + c) * 128);
  const float4* obw = (const float4*)(obwb + (size_t)(i2 * 64 + c) * 128);
  const float4* yf  = (const float4*)(ys + (size_t)(g * 2 + 0) * MT * 128 + (size_t)l * 128);
  const float4* ybr = (const float4*)(ys + (size_t)(g * 2 + 1) * MT * 128 + (size_t)(MT - 1 - l) * 128);
  const float4* ybd = (const float4*)(ys + (size_t)(g * 2 + 1) * MT * 128 + (size_t)l * 128);
  float accC = 0.f, accF = 0.f, accB = 0.f;
  #pragma unroll 4
  for (int k = 0; k < 32; k++){
    float4 a = yf[k], br = ybr[k], w = ow[k];
    accC += (a.x + br.x) * w.x + (a.y + br.y) * w.y + (a.z + br.z) * w.z + (a.w + br.w) * w.w;
    accF += a.x * w.x + a.y * w.y + a.z * w.z + a.w * w.w;
    float4 bd = ybd[k], wb = obw[k];
    accB += bd.x * wb.x + bd.y * wb.y + bd.z * wb.z + bd.w * wb.w;
  }
  size_t io = (size_t)g * 64 * MT + (size_t)c * MT + l;
  float nb = imgB[io] + accC;
  imgB[io] = nb;
  imgA[io] += nb;
  if (writeM){
    xM[(size_t)g * MT * 64 + (size_t)l * 64 + c] = accF;
    yM[(size_t)g * MT * 64 + (size_t)l * 64 + c] = accB;
  }
}

// ---------------- GCN (hub graph -> closed form) ----------------
__global__ __launch_bounds__(256) void k_gcn1(const float* __restrict__ xM, const float* __restrict__ yM,
                                              const float* __restrict__ W1, float* __restrict__ t1){
  __shared__ __align__(16) float nf[2][256];
  int l0 = blockIdx.x * 2;
  int tid = threadIdx.x;
  for (int idx = tid; idx < 512; idx += 256){
    int ll = idx >> 8, k = idx & 255;
    int l = l0 + ll;
    int which = k >> 6, cc = k & 63;
    const float* srcp = (which == 0) ? xM : (which == 1) ? yM
                       : (which == 2) ? (xM + (size_t)MT * 64) : (yM + (size_t)MT * 64);
    nf[ll][k] = srcp[(size_t)l * 64 + cc];
  }
  __syncthreads();
  int f = tid & 127, ll = tid >> 7;
  const float4* w4 = (const float4*)(W1 + (size_t)f * 256);
  const float4* a4 = (const float4*)nf[ll];
  float acc = 0.f;
  #pragma unroll 8
  for (int k = 0; k < 64; k++){
    float4 a = a4[k], w = w4[k];
    acc += a.x * w.x + a.y * w.y + a.z * w.z + a.w * w.w;
  }
  t1[(size_t)(l0 + ll) * 128 + f] = acc;
}

__global__ __launch_bounds__(128) void k_hub1(const float* __restrict__ t1, float* __restrict__ hubm){
  int f = threadIdx.x;
  float sum = 0.f;
  for (int hb = 0; hb < 450; hb++) sum += t1[(size_t)(hb * 32) * 128 + f];
  hubm[f] = sum * (1.f / 450.f);
}

__global__ __launch_bounds__(128) void k_gcn2(const float* __restrict__ t1, const float* __restrict__ hubm,
                                              const float* __restrict__ b1, const float* __restrict__ W2,
                                              float* __restrict__ t2){
  __shared__ __align__(16) float hbuf[2][128];
  int l0 = blockIdx.x * 2;
  int tid = threadIdx.x;
  for (int idx = tid; idx < 256; idx += 128){
    int ll = idx >> 7, k = idx & 127;
    int l = l0 + ll;
    float raw = ((l & 31) == 0) ? hubm[k] : t1[(size_t)l * 128 + k];
    hbuf[ll][k] = fmaxf(raw + b1[k], 0.f);
  }
  __syncthreads();
  int c = tid & 63, ll = tid >> 6;
  const float4* w4 = (const float4*)(W2 + (size_t)c * 128);
  const float4* a4 = (const float4*)hbuf[ll];
  float acc = 0.f;
  #pragma unroll 8
  for (int k = 0; k < 32; k++){
    float4 a = a4[k], w = w4[k];
    acc += a.x * w.x + a.y * w.y + a.z * w.z + a.w * w.w;
  }
  t2[(size_t)(l0 + ll) * 64 + c] = acc;
}

__global__ __launch_bounds__(64) void k_hub2(const float* __restrict__ t2, float* __restrict__ hubm2){
  int c = threadIdx.x;
  float sum = 0.f;
  for (int hb = 0; hb < 450; hb++) sum += t2[(size_t)(hb * 32) * 64 + c];
  hubm2[c] = sum * (1.f / 450.f);
}

__global__ __launch_bounds__(256) void k_final(const void* __restrict__ x, const float* __restrict__ t2,
                                               const float* __restrict__ hubm2, const float* __restrict__ b2,
                                               const float* __restrict__ imgA, void* __restrict__ out,
                                               const int* __restrict__ flag){
  int idx = blockIdx.x * 256 + threadIdx.x;  // c*MT + l
  int l = idx % MT, c = idx / MT;
  int fp32 = *flag;
  float gval = (((l & 31) == 0) ? hubm2[c] : t2[(size_t)l * 64 + c]) + b2[c];
  float a0 = imgA[idx];
  float a1 = imgA[(size_t)64 * MT + (size_t)c * MT + (l % 120) * 120 + l / 120];
  float xv = fp32 ? ((const float*)x)[idx] : b2f(((const u16*)x)[idx]);
  float val = gval + xv + a0 + a1;
  if (fp32) ((float*)out)[idx] = val;
  else      ((u16*)out)[idx] = f2b(val);
}

extern "C" void kernel_launch(void* const* d_in, const int* in_sizes, int n_in,
                              void* d_out, int out_size, void* d_ws, size_t ws_size,
                              hipStream_t stream){
  int I_X=0,I_PIW=1,I_PCW=2,I_PCB=3,I_PXP=4,I_PDTW=5,I_PDTB=6,I_PAL=7,I_PD=8,I_PLG=9,I_PLB=10,
      I_WIW=11,I_WCW=12,I_WCB=13,I_WXP=14,I_WDTW=15,I_WDTB=16,I_WAL=17,I_WD=18,I_WLG=19,I_WLB=20,
      I_POW=21,I_WOW=22,I_WOBW=23,I_G1=24,I_GB1=25,I_G2=26,I_GB2=27;
  if (n_in >= 28 && in_sizes[9] == 131072){
    I_WIW=9;I_WCW=10;I_WCB=11;I_WXP=12;I_WDTW=13;I_WDTB=14;I_WAL=15;I_WD=16;
    I_PLG=17;I_PLB=18;I_WLG=19;I_WLB=20;
  }
  if (n_in < 28 || in_sizes[I_PIW] != 131072 || out_size != 921600) return;

  float* Wp = (float*)d_ws;
  size_t off = 0;
  auto alloc = [&](size_t n){ size_t r = off; off += (n + 63) & ~(size_t)63; return r; };
  size_t oFlag=alloc(64);
  size_t oPIW=alloc(131072), oPCW=alloc(4096), oPCB=alloc(1024), oPXP=alloc(36864),
         oPDTW=alloc(4096), oPDTB=alloc(1024), oPA=alloc(16384), oPD=alloc(1024),
         oPLG=alloc(256), oPLB=alloc(256);
  size_t oWIW=alloc(131072), oWCW=alloc(4096), oWCB=alloc(1024), oWXP=alloc(36864),
         oWDTW=alloc(4096), oWDTB=alloc(1024), oWA=alloc(16384), oWD=alloc(1024),
         oWLG=alloc(256), oWLB=alloc(256);
  size_t oPOW=alloc(32768), oWOW=alloc(32768), oWOBW=alloc(32768),
         oG1=alloc(32768), oGB1=alloc(128), oG2=alloc(8192), oGB2=alloc(64);
  size_t oImgA=alloc(2UL*64*MT), oImgB=alloc(2UL*64*MT), oXn=alloc(2UL*MT*64);
  size_t oRaw=alloc(4UL*MT*128);             // xh_raw; aliased as ys after conv
  size_t oZ=alloc(4UL*MT*128), oXhs=alloc(4UL*MT*128), oDelta=alloc(4UL*MT*128);
  size_t oBm=alloc(4UL*MT*16), oCm=alloc(4UL*MT*16);
  size_t oAc=alloc(4UL*WNC*2048), oBc=alloc(4UL*WNC*2048), oHin=alloc(4UL*WNC*2048);
  size_t oXM=alloc(2UL*MT*64), oYM=alloc(2UL*MT*64);
  size_t oT1=alloc((size_t)MT*128), oHub1=alloc(128), oT2=alloc((size_t)MT*64), oHub2=alloc(64);
  if (ws_size < off * sizeof(float)) return;

  int* flag = (int*)(Wp + oFlag);
  k_detect<<<dim3(1), dim3(256), 0, stream>>>((const u16*)d_in[I_PAL], 16384, flag);

  PTab tb;
  int ti = 0;
  auto add = [&](int inIdx, size_t o, int n, int neg){
    tb.src[ti] = d_in[inIdx]; tb.dst[ti] = Wp + o; tb.n[ti] = n; tb.neg[ti] = neg; ti++;
  };
  add(I_PIW,oPIW,131072,0); add(I_PCW,oPCW,4096,0); add(I_PCB,oPCB,1024,0); add(I_PXP,oPXP,36864,0);
  add(I_PDTW,oPDTW,4096,0); add(I_PDTB,oPDTB,1024,0); add(I_PAL,oPA,16384,1); add(I_PD,oPD,1024,0);
  add(I_PLG,oPLG,256,0); add(I_PLB,oPLB,256,0);
  add(I_WIW,oWIW,131072,0); add(I_WCW,oWCW,4096,0); add(I_WCB,oWCB,1024,0); add(I_WXP,oWXP,36864,0);
  add(I_WDTW,oWDTW,4096,0); add(I_WDTB,oWDTB,1024,0); add(I_WAL,oWA,16384,1); add(I_WD,oWD,1024,0);
  add(I_WLG,oWLG,256,0); add(I_WLB,oWLB,256,0);
  add(I_POW,oPOW,32768,0); add(I_WOW,oWOW,32768,0); add(I_WOBW,oWOBW,32768,0);
  add(I_G1,oG1,32768,0); add(I_GB1,oGB1,128,0); add(I_G2,oG2,8192,0); add(I_GB2,oGB2,64,0);

  k_cvt<<<dim3(128, 27), dim3(256), 0, stream>>>(tb, flag);
  k_cvt_x<<<dim3(3600), dim3(256), 0, stream>>>(d_in[I_X], Wp + oImgA, flag);

  float *imgA = Wp+oImgA, *imgB = Wp+oImgB, *xn = Wp+oXn, *raw = Wp+oRaw, *ys = Wp+oRaw,
        *zz = Wp+oZ, *xhs = Wp+oXhs, *delta = Wp+oDelta, *Bm = Wp+oBm, *Cm = Wp+oCm,
        *Ac = Wp+oAc, *Bc = Wp+oBc, *Hin = Wp+oHin, *xM = Wp+oXM, *yM = Wp+oYM;

  for (int s = 0; s < 2; s++){
    k_prep_xn<<<dim3(7200), dim3(256), 0, stream>>>(imgA, Wp+oPLG, Wp+oPLB, xn, s, 1);
    k_inproj <<<dim3(900, 4), dim3(256), 0, stream>>>(xn, Wp+oPIW, raw, zz, s, 1);
    k_conv   <<<dim3(7200, 4), dim3(256), 0, stream>>>(raw, Wp+oPCW, Wp+oPCB, xhs, s, 1);
    k_xproj  <<<dim3(1800, 4), dim3(256), 0, stream>>>(xhs, Wp+oPXP, Wp+oPDTW, Wp+oPDTB, delta, Bm, Cm, s);
    k_scan_pixel<<<dim3(25, 4), dim3(256), 0, stream>>>(delta, xhs, Bm, Cm, zz, Wp+oPA, Wp+oPD, ys, s);
    k_outproj_pixel<<<dim3(7200), dim3(256), 0, stream>>>(ys, Wp+oPOW, imgA, imgB, s);

    k_prep_xn<<<dim3(7200), dim3(256), 0, stream>>>(imgB, Wp+oWLG, Wp+oWLB, xn, s, 0);
    k_inproj <<<dim3(900, 4), dim3(256), 0, stream>>>(xn, Wp+oWIW, raw, zz, s, 0);
    k_conv   <<<dim3(7200, 4), dim3(256), 0, stream>>>(raw, Wp+oWCW, Wp+oWCB, xhs, s, 0);
    k_xproj  <<<dim3(1800, 4), dim3(256), 0, stream>>>(xhs, Wp+oWXP, Wp+oWDTW, Wp+oWDTB, delta, Bm, Cm, s);
    k_scan_win_p1<<<dim3(WNC, 4), dim3(256), 0, stream>>>(delta, xhs, Bm, Wp+oWA, Ac, Bc, s);
    k_scan_win_p2<<<dim3(32), dim3(256), 0, stream>>>(Ac, Bc, Hin);
    k_scan_win_p3<<<dim3(WNC, 4), dim3(256), 0, stream>>>(delta, xhs, Bm, Cm, zz, Wp+oWA, Wp+oWD, Hin, ys, s);
    k_outproj_win<<<dim3(7200), dim3(256), 0, stream>>>(ys, Wp+oWOW, Wp+oWOBW, imgA, imgB, xM, yM, s, (s == 1) ? 1 : 0);
  }

  k_gcn1<<<dim3(7200), dim3(256), 0, stream>>>(xM, yM, Wp+oG1, Wp+oT1);
  k_hub1<<<dim3(1), dim3(128), 0, stream>>>(Wp+oT1, Wp+oHub1);
  k_gcn2<<<dim3(7200), dim3(128), 0, stream>>>(Wp+oT1, Wp+oHub1, Wp+oGB1, Wp+oG2, Wp+oT2);
  k_hub2<<<dim3(1), dim3(64), 0, stream>>>(Wp+oT2, Wp+oHub2);
  k_final<<<dim3(3600), dim3(256), 0, stream>>>(d_in[I_X], Wp+oT2, Wp+oHub2, Wp+oGB2, imgA, d_out, flag);
}

// Round 4
// 2813.047 us; speedup vs baseline: 1.9387x; 1.6033x over previous
//
#include <hip/hip_runtime.h>
#include <hip/hip_bf16.h>

#define MT 14400
#define WNC 150     // window scan chunks
#define WCL 96      // window chunk length (WNC*WCL = MT)
#define PT 16       // LDS tile (timesteps) for all scans

typedef unsigned short u16;

__device__ __forceinline__ float b2f(u16 u){
  union { unsigned int i; float f; } v; v.i = ((unsigned int)u) << 16; return v.f;
}
__device__ __forceinline__ u16 f2b(float f){
  union { unsigned int i; float f; } v; v.f = f;
  unsigned int x = v.i;
  return (u16)((x + 0x7fffu + ((x >> 16) & 1u)) >> 16);
}
__device__ __forceinline__ float siluf(float x){ return x / (1.f + expf(-x)); }
__device__ __forceinline__ float softplusf(float x){ return (x > 20.f) ? x : log1pf(expf(x)); }

// ---------------- dtype detection ----------------
__global__ __launch_bounds__(256) void k_detect(const u16* __restrict__ a, int n, int* __restrict__ flag){
  __shared__ int found;
  if (threadIdx.x == 0) found = 0;
  __syncthreads();
  int f = 0;
  for (int i = threadIdx.x; i < n; i += 256){
    float v = b2f(a[i]);
    if (!(fabsf(v) <= 1e9f)) f = 1;
  }
  if (f) atomicOr(&found, 1);
  __syncthreads();
  if (threadIdx.x == 0) *flag = found;
}

// ---------------- param conversion ----------------
struct PTab {
  const void* src[27];
  float* dst[27];
  int n[27];
  int neg[27];   // 1 -> store -exp(v)*log2(e)  (A_log -> A2 for exp2f scans)
};

__global__ __launch_bounds__(256) void k_cvt(PTab tb, const int* __restrict__ flag){
  int id = blockIdx.y;
  int n = tb.n[id];
  int fp32 = *flag;
  float* d = tb.dst[id];
  int ng = tb.neg[id];
  for (int i = blockIdx.x * 256 + threadIdx.x; i < n; i += gridDim.x * 256){
    float v = fp32 ? ((const float*)tb.src[id])[i] : b2f(((const u16*)tb.src[id])[i]);
    if (ng) v = -expf(v) * 1.4426950408889634f;
    d[i] = v;
  }
}

// transpose in_w: W[mat][256][64] -> WT[mat][64][256]  (mat = 16: 8 pix + 8 win)
__global__ __launch_bounds__(256) void k_wtrans(const float* __restrict__ Wpix, const float* __restrict__ Wwin,
                                                float* __restrict__ WTpix, float* __restrict__ WTwin){
  int mat = blockIdx.y;
  const float* src = (mat < 8) ? (Wpix + (size_t)mat * 16384) : (Wwin + (size_t)(mat - 8) * 16384);
  float* dst = (mat < 8) ? (WTpix + (size_t)mat * 16384) : (WTwin + (size_t)(mat - 8) * 16384);
  int idx = blockIdx.x * 256 + threadIdx.x;  // e*64 + k
  int e = idx >> 6, k = idx & 63;
  dst[k * 256 + e] = src[idx];
}

__global__ __launch_bounds__(256) void k_cvt_x(const void* __restrict__ x, float* __restrict__ imgA,
                                               const int* __restrict__ flag){
  int idx = blockIdx.x * 256 + threadIdx.x;  // c*MT + l
  int l = idx % MT, c = idx / MT;
  float v = (*flag) ? ((const float*)x)[idx] : b2f(((const u16*)x)[idx]);
  imgA[idx] = v;
  imgA[(size_t)64 * MT + (size_t)c * MT + (l % 120) * 120 + l / 120] = v;
}

// ---------------- layernorm + token-order gather ----------------
__global__ __launch_bounds__(256) void k_prep_xn(const float* __restrict__ img, const float* __restrict__ lng,
                                                 const float* __restrict__ lnb, float* __restrict__ xn,
                                                 int s, int pixelMode){
  int tid = threadIdx.x;
  int q = blockIdx.x * 4 + (tid >> 6);
  int c = tid & 63;
  int g = q / MT, t = q % MT;
  int hw;
  if (pixelMode){
    int b = t / 576, l = t % 576;
    int ph = b / 5, pw = b % 5, nh = l / 24, nw = l % 24;
    hw = (nh * 5 + ph) * 120 + (nw * 5 + pw);
  } else hw = t;
  float v = img[(size_t)g * 64 * MT + (size_t)c * MT + hw];
  float sm = v;
  #pragma unroll
  for (int m = 32; m >= 1; m >>= 1) sm += __shfl_xor(sm, m);
  float mean = sm * (1.f / 64.f);
  float dv = v - mean;
  float s2 = dv * dv;
  #pragma unroll
  for (int m = 32; m >= 1; m >>= 1) s2 += __shfl_xor(s2, m);
  float var = s2 * (1.f / 64.f);
  int i2 = g * 2 + s;
  float o = dv * rsqrtf(var + 1e-5f) * lng[i2 * 64 + c] + lnb[i2 * 64 + c];
  xn[(size_t)g * MT * 64 + (size_t)t * 64 + c] = o;
}

// ---------------- in-projection: register-tiled GEMM ----------------
// block: 64 tokens x 128 outputs, K=64 staged in LDS; threads 16x16, acc[4][8]
// grid.x = 450: ttile = x>>1 (225 tiles of 64 tokens), ntile = x&1 (xh / z half)
__global__ __launch_bounds__(256) void k_inproj(const float* __restrict__ xn, const float* __restrict__ WT,
                                                float* __restrict__ xh, float* __restrict__ z,
                                                int s, int pixelMode){
  int gd = blockIdx.y, g = gd >> 1, dir = gd & 1;
  int i2 = (g * 2 + s) * 2 + dir;
  int ttile = blockIdx.x >> 1, ntile = blockIdx.x & 1;
  int t0 = ttile * 64;
  const float* WTm = WT + (size_t)i2 * 16384 + ntile * 128;

  __shared__ __align__(16) float sA[64 * 68];
  __shared__ __align__(16) float sB[64 * 128];
  int tid = threadIdx.x;

  // stage A (64 tokens x 64 k), with dir-reversal gather
  {
    int k0 = (tid & 15) * 4;
    #pragma unroll
    for (int it = 0; it < 4; it++){
      int t = (tid >> 4) + it * 16;
      int tq = t0 + t, src = tq;
      if (dir){
        if (pixelMode){ int b = tq / 576, l = tq % 576; src = b * 576 + 575 - l; }
        else src = MT - 1 - tq;
      }
      float4 v = *(const float4*)&xn[(size_t)g * MT * 64 + (size_t)src * 64 + k0];
      *(float4*)&sA[t * 68 + k0] = v;
    }
  }
  // stage B (64 k x 128 outputs) from pre-transposed weights
  {
    #pragma unroll
    for (int it = 0; it < 8; it++){
      int idx = it * 256 + tid;
      int k = idx >> 5, e4 = (idx & 31) * 4;
      float4 v = *(const float4*)&WTm[(size_t)k * 256 + e4];
      *(float4*)&sB[k * 128 + e4] = v;
    }
  }
  __syncthreads();

  int tr = tid >> 4, tc = tid & 15;
  float acc[4][8];
  #pragma unroll
  for (int i = 0; i < 4; i++)
    #pragma unroll
    for (int j = 0; j < 8; j++) acc[i][j] = 0.f;

  for (int k0 = 0; k0 < 64; k0 += 4){
    float4 a4[4];
    #pragma unroll
    for (int i = 0; i < 4; i++) a4[i] = *(const float4*)&sA[(tr * 4 + i) * 68 + k0];
    #pragma unroll
    for (int kk = 0; kk < 4; kk++){
      float4 b0 = *(const float4*)&sB[(k0 + kk) * 128 + tc * 8];
      float4 b1 = *(const float4*)&sB[(k0 + kk) * 128 + tc * 8 + 4];
      float bv[8] = {b0.x, b0.y, b0.z, b0.w, b1.x, b1.y, b1.z, b1.w};
      #pragma unroll
      for (int i = 0; i < 4; i++){
        const float* ap = (const float*)&a4[i];
        float av = ap[kk];
        #pragma unroll
        for (int j = 0; j < 8; j++) acc[i][j] += av * bv[j];
      }
    }
  }

  float* dst = ntile ? z : xh;
  #pragma unroll
  for (int i = 0; i < 4; i++){
    int t_out = t0 + tr * 4 + i;
    size_t base = (size_t)gd * MT * 128 + (size_t)t_out * 128 + tc * 8;
    *(float4*)&dst[base]     = make_float4(acc[i][0], acc[i][1], acc[i][2], acc[i][3]);
    *(float4*)&dst[base + 4] = make_float4(acc[i][4], acc[i][5], acc[i][6], acc[i][7]);
  }
}

// ---------------- causal depthwise conv (K=4) + SiLU ----------------
__global__ __launch_bounds__(256) void k_conv(const float* __restrict__ raw, const float* __restrict__ cw,
                                              const float* __restrict__ cb, float* __restrict__ xhs,
                                              int s, int pixelMode){
  int gd = blockIdx.y, g = gd >> 1, dir = gd & 1;
  int i2 = (g * 2 + s) * 2 + dir;
  int idx = blockIdx.x * 256 + threadIdx.x;  // t*128+ch
  int t = idx >> 7, ch = idx & 127;
  int SL = pixelMode ? 576 : MT;
  int pos = t % SL;
  const float* src = raw + (size_t)gd * MT * 128;
  const float* wrow = cw + (size_t)(i2 * 128 + ch) * 4;
  float acc = cb[i2 * 128 + ch];
  #pragma unroll
  for (int i = 0; i < 4; i++){
    int d = 3 - i;
    if (pos >= d) acc += src[(size_t)(t - d) * 128 + ch] * wrow[i];
  }
  xhs[(size_t)gd * MT * 128 + idx] = siluf(acc);
}

// ---------------- x-projection -> delta(softplus), B, C ----------------
__global__ __launch_bounds__(256) void k_xproj(const float* __restrict__ xhs, const float* __restrict__ xpb,
                                               const float* __restrict__ dtw, const float* __restrict__ dtb,
                                               float* __restrict__ delta, float* __restrict__ Bm,
                                               float* __restrict__ Cm, int s){
  int gd = blockIdx.y, g = gd >> 1, dir = gd & 1;
  int i2 = (g * 2 + s) * 2 + dir;
  const float* XP = xpb + (size_t)i2 * 36 * 128;
  const float* DW = dtw + (size_t)i2 * 128 * 4;
  const float* DB = dtb + (size_t)i2 * 128;
  int t0 = blockIdx.x * 8;
  __shared__ __align__(16) float xv[8][128];
  __shared__ float dbl[8][36];
  int tid = threadIdx.x;
  const float* src = xhs + (size_t)gd * MT * 128 + (size_t)t0 * 128;
  for (int idx = tid; idx < 8 * 128; idx += 256) xv[idx >> 7][idx & 127] = src[idx];
  __syncthreads();
  for (int o = tid; o < 8 * 36; o += 256){
    int tok = o / 36, e = o - tok * 36;
    const float4* a4 = (const float4*)xv[tok];
    const float4* w4 = (const float4*)(XP + (size_t)e * 128);
    float acc = 0.f;
    #pragma unroll 8
    for (int k = 0; k < 32; k++){
      float4 a = a4[k], w = w4[k];
      acc += a.x*w.x + a.y*w.y + a.z*w.z + a.w*w.w;
    }
    dbl[tok][e] = acc;
  }
  __syncthreads();
  for (int o = tid; o < 8 * 128; o += 256){
    int tok = o >> 7, d = o & 127;
    float v = DB[d];
    #pragma unroll
    for (int r = 0; r < 4; r++) v += dbl[tok][r] * DW[d * 4 + r];
    delta[(size_t)gd * MT * 128 + (size_t)(t0 + tok) * 128 + d] = softplusf(v);
  }
  for (int o = tid; o < 8 * 32; o += 256){
    int tok = o >> 5, n = o & 31;
    int t = t0 + tok;
    if (n < 16) Bm[(size_t)gd * MT * 16 + (size_t)t * 16 + n] = dbl[tok][4 + n];
    else        Cm[(size_t)gd * MT * 16 + (size_t)t * 16 + (n - 16)] = dbl[tok][20 + (n - 16)];
  }
}

// ---------------- selective scan, LDS-staged ----------------
__global__ __launch_bounds__(256) void k_scan_pixel(const float* __restrict__ delta, const float* __restrict__ xhs,
                                                    const float* __restrict__ Bm, const float* __restrict__ Cm,
                                                    const float* __restrict__ zz, const float* __restrict__ A2b,
                                                    const float* __restrict__ Db, float* __restrict__ ys, int s){
  int gd = blockIdx.y, g = gd >> 1, dir = gd & 1;
  int i2 = (g * 2 + s) * 2 + dir;
  int seq = blockIdx.x;
  int tid = threadIdx.x, ch = tid >> 1, nb = (tid & 1) * 8;
  float A2[8], h[8];
  #pragma unroll
  for (int j = 0; j < 8; j++){
    A2[j] = A2b[((size_t)i2 * 128 + ch) * 16 + nb + j];
    h[j] = 0.f;
  }
  float Dv = Db[(size_t)i2 * 128 + ch];
  size_t so = (size_t)gd * MT * 128 + (size_t)seq * 576 * 128;
  size_t bo = (size_t)gd * MT * 16  + (size_t)seq * 576 * 16;
  __shared__ __align__(16) float sd[2][PT * 128];
  __shared__ __align__(16) float su[2][PT * 128];
  __shared__ __align__(16) float sb[2][PT * 16];
  __shared__ __align__(16) float sc[2][PT * 16];
  __shared__ __align__(16) float sy[PT * 128];
  float4 rd0, rd1, ru0, ru1; float rb, rc;
  {
    const float4* d4 = (const float4*)(delta + so);
    const float4* u4 = (const float4*)(xhs + so);
    rd0 = d4[2 * tid]; rd1 = d4[2 * tid + 1];
    ru0 = u4[2 * tid]; ru1 = u4[2 * tid + 1];
    rb = (Bm + bo)[tid]; rc = (Cm + bo)[tid];
  }
  const int NT = 576 / PT;
  for (int tile = 0; tile < NT; tile++){
    int bs = tile & 1;
    __syncthreads();
    ((float4*)sd[bs])[2 * tid] = rd0; ((float4*)sd[bs])[2 * tid + 1] = rd1;
    ((float4*)su[bs])[2 * tid] = ru0; ((float4*)su[bs])[2 * tid + 1] = ru1;
    sb[bs][tid] = rb; sc[bs][tid] = rc;
    __syncthreads();
    if (tile + 1 < NT){
      const float4* d4 = (const float4*)(delta + so + (size_t)(tile + 1) * PT * 128);
      const float4* u4 = (const float4*)(xhs + so + (size_t)(tile + 1) * PT * 128);
      rd0 = d4[2 * tid]; rd1 = d4[2 * tid + 1];
      ru0 = u4[2 * tid]; ru1 = u4[2 * tid + 1];
      rb = (Bm + bo + (size_t)(tile + 1) * PT * 16)[tid];
      rc = (Cm + bo + (size_t)(tile + 1) * PT * 16)[tid];
    }
    #pragma unroll
    for (int t = 0; t < PT; t++){
      float dt = sd[bs][t * 128 + ch];
      float u  = su[bs][t * 128 + ch];
      float du = dt * u;
      float acc = 0.f;
      #pragma unroll
      for (int j = 0; j < 8; j++){
        float e = exp2f(dt * A2[j]);
        h[j] = h[j] * e + du * sb[bs][t * 16 + nb + j];
        acc += h[j] * sc[bs][t * 16 + nb + j];
      }
      acc += __shfl_xor(acc, 1);
      if (!(tid & 1)) sy[t * 128 + ch] = acc + u * Dv;
    }
    __syncthreads();
    {
      const float4* z4 = (const float4*)(zz + so + (size_t)tile * PT * 128);
      float4* y4 = (float4*)(ys + so + (size_t)tile * PT * 128);
      #pragma unroll
      for (int i = 0; i < 2; i++){
        int f = 2 * tid + i;
        float4 yv = ((float4*)sy)[f];
        float4 zv = z4[f];
        yv.x *= siluf(zv.x); yv.y *= siluf(zv.y); yv.z *= siluf(zv.z); yv.w *= siluf(zv.w);
        y4[f] = yv;
      }
    }
  }
}

__global__ __launch_bounds__(256) void k_scan_win_p1(const float* __restrict__ delta, const float* __restrict__ xhs,
                                                     const float* __restrict__ Bm, const float* __restrict__ A2b,
                                                     float* __restrict__ Acar, float* __restrict__ Bcar, int s){
  int gd = blockIdx.y, g = gd >> 1, dir = gd & 1;
  int i2 = (g * 2 + s) * 2 + dir;
  int chunk = blockIdx.x;
  int tid = threadIdx.x, ch = tid >> 1, nb = (tid & 1) * 8;
  float A2[8], ap[8], bc[8];
  #pragma unroll
  for (int j = 0; j < 8; j++){
    A2[j] = A2b[((size_t)i2 * 128 + ch) * 16 + nb + j];
    ap[j] = 1.f; bc[j] = 0.f;
  }
  size_t so = (size_t)gd * MT * 128 + (size_t)chunk * WCL * 128;
  size_t bo = (size_t)gd * MT * 16  + (size_t)chunk * WCL * 16;
  __shared__ __align__(16) float sd[2][PT * 128];
  __shared__ __align__(16) float su[2][PT * 128];
  __shared__ __align__(16) float sb[2][PT * 16];
  float4 rd0, rd1, ru0, ru1; float rb;
  {
    const float4* d4 = (const float4*)(delta + so);
    const float4* u4 = (const float4*)(xhs + so);
    rd0 = d4[2 * tid]; rd1 = d4[2 * tid + 1];
    ru0 = u4[2 * tid]; ru1 = u4[2 * tid + 1];
    rb = (Bm + bo)[tid];
  }
  const int NT = WCL / PT;
  for (int tile = 0; tile < NT; tile++){
    int bs = tile & 1;
    __syncthreads();
    ((float4*)sd[bs])[2 * tid] = rd0; ((float4*)sd[bs])[2 * tid + 1] = rd1;
    ((float4*)su[bs])[2 * tid] = ru0; ((float4*)su[bs])[2 * tid + 1] = ru1;
    sb[bs][tid] = rb;
    __syncthreads();
    if (tile + 1 < NT){
      const float4* d4 = (const float4*)(delta + so + (size_t)(tile + 1) * PT * 128);
      const float4* u4 = (const float4*)(xhs + so + (size_t)(tile + 1) * PT * 128);
      rd0 = d4[2 * tid]; rd1 = d4[2 * tid + 1];
      ru0 = u4[2 * tid]; ru1 = u4[2 * tid + 1];
      rb = (Bm + bo + (size_t)(tile + 1) * PT * 16)[tid];
    }
    #pragma unroll
    for (int t = 0; t < PT; t++){
      float dt = sd[bs][t * 128 + ch];
      float u  = su[bs][t * 128 + ch];
      float du = dt * u;
      #pragma unroll
      for (int j = 0; j < 8; j++){
        float e = exp2f(dt * A2[j]);
        bc[j] = bc[j] * e + du * sb[bs][t * 16 + nb + j];
        ap[j] *= e;
      }
    }
  }
  size_t o = ((size_t)gd * WNC + chunk) * 2048 + (size_t)ch * 16 + nb;
  float4* A4 = (float4*)(Acar + o);
  float4* B4 = (float4*)(Bcar + o);
  A4[0] = make_float4(ap[0], ap[1], ap[2], ap[3]);
  A4[1] = make_float4(ap[4], ap[5], ap[6], ap[7]);
  B4[0] = make_float4(bc[0], bc[1], bc[2], bc[3]);
  B4[1] = make_float4(bc[4], bc[5], bc[6], bc[7]);
}

__global__ __launch_bounds__(256) void k_scan_win_p2(const float* __restrict__ Acar, const float* __restrict__ Bcar,
                                                     float* __restrict__ Hin){
  int flat = blockIdx.x * 256 + threadIdx.x;  // 8192 total
  int cs = flat & 2047, gd = flat >> 11;
  float h = 0.f;
  for (int c = 0; c < WNC; c++){
    size_t o = ((size_t)gd * WNC + c) * 2048 + cs;
    Hin[o] = h;
    h = Acar[o] * h + Bcar[o];
  }
}

__global__ __launch_bounds__(256) void k_scan_win_p3(const float* __restrict__ delta, const float* __restrict__ xhs,
                                                     const float* __restrict__ Bm, const float* __restrict__ Cm,
                                                     const float* __restrict__ zz, const float* __restrict__ A2b,
                                                     const float* __restrict__ Db, const float* __restrict__ Hin,
                                                     float* __restrict__ ys, int s){
  int gd = blockIdx.y, g = gd >> 1, dir = gd & 1;
  int i2 = (g * 2 + s) * 2 + dir;
  int chunk = blockIdx.x;
  int tid = threadIdx.x, ch = tid >> 1, nb = (tid & 1) * 8;
  float A2[8], h[8];
  size_t ho = ((size_t)gd * WNC + chunk) * 2048 + (size_t)ch * 16 + nb;
  {
    const float4* H4 = (const float4*)(Hin + ho);
    float4 h0 = H4[0], h1 = H4[1];
    h[0]=h0.x; h[1]=h0.y; h[2]=h0.z; h[3]=h0.w;
    h[4]=h1.x; h[5]=h1.y; h[6]=h1.z; h[7]=h1.w;
  }
  #pragma unroll
  for (int j = 0; j < 8; j++) A2[j] = A2b[((size_t)i2 * 128 + ch) * 16 + nb + j];
  float Dv = Db[(size_t)i2 * 128 + ch];
  size_t so = (size_t)gd * MT * 128 + (size_t)chunk * WCL * 128;
  size_t bo = (size_t)gd * MT * 16  + (size_t)chunk * WCL * 16;
  __shared__ __align__(16) float sd[2][PT * 128];
  __shared__ __align__(16) float su[2][PT * 128];
  __shared__ __align__(16) float sb[2][PT * 16];
  __shared__ __align__(16) float sc[2][PT * 16];
  __shared__ __align__(16) float sy[PT * 128];
  float4 rd0, rd1, ru0, ru1; float rb, rc;
  {
    const float4* d4 = (const float4*)(delta + so);
    const float4* u4 = (const float4*)(xhs + so);
    rd0 = d4[2 * tid]; rd1 = d4[2 * tid + 1];
    ru0 = u4[2 * tid]; ru1 = u4[2 * tid + 1];
    rb = (Bm + bo)[tid]; rc = (Cm + bo)[tid];
  }
  const int NT = WCL / PT;
  for (int tile = 0; tile < NT; tile++){
    int bs = tile & 1;
    __syncthreads();
    ((float4*)sd[bs])[2 * tid] = rd0; ((float4*)sd[bs])[2 * tid + 1] = rd1;
    ((float4*)su[bs])[2 * tid] = ru0; ((float4*)su[bs])[2 * tid + 1] = ru1;
    sb[bs][tid] = rb; sc[bs][tid] = rc;
    __syncthreads();
    if (tile + 1 < NT){
      const float4* d4 = (const float4*)(delta + so + (size_t)(tile + 1) * PT * 128);
      const float4* u4 = (const float4*)(xhs + so + (size_t)(tile + 1) * PT * 128);
      rd0 = d4[2 * tid]; rd1 = d4[2 * tid + 1];
      ru0 = u4[2 * tid]; ru1 = u4[2 * tid + 1];
      rb = (Bm + bo + (size_t)(tile + 1) * PT * 16)[tid];
      rc = (Cm + bo + (size_t)(tile + 1) * PT * 16)[tid];
    }
    #pragma unroll
    for (int t = 0; t < PT; t++){
      float dt = sd[bs][t * 128 + ch];
      float u  = su[bs][t * 128 + ch];
      float du = dt * u;
      float acc = 0.f;
      #pragma unroll
      for (int j = 0; j < 8; j++){
        float e = exp2f(dt * A2[j]);
        h[j] = h[j] * e + du * sb[bs][t * 16 + nb + j];
        acc += h[j] * sc[bs][t * 16 + nb + j];
      }
      acc += __shfl_xor(acc, 1);
      if (!(tid & 1)) sy[t * 128 + ch] = acc + u * Dv;
    }
    __syncthreads();
    {
      const float4* z4 = (const float4*)(zz + so + (size_t)tile * PT * 128);
      float4* y4 = (float4*)(ys + so + (size_t)tile * PT * 128);
      #pragma unroll
      for (int i = 0; i < 2; i++){
        int f = 2 * tid + i;
        float4 yv = ((float4*)sy)[f];
        float4 zv = z4[f];
        yv.x *= siluf(zv.x); yv.y *= siluf(zv.y); yv.z *= siluf(zv.z); yv.w *= siluf(zv.w);
        y4[f] = yv;
      }
    }
  }
}

// ---------------- out-projection + residual ----------------
__global__ __launch_bounds__(256) void k_outproj_pixel(const float* __restrict__ ys, const float* __restrict__ owb,
                                                       const float* __restrict__ imgA, float* __restrict__ imgB, int s){
  int idx = blockIdx.x * 256 + threadIdx.x;
  int c = idx & 63, q = idx >> 6;
  int t = q % MT, g = q / MT;
  int i2 = g * 2 + s;
  const float4* ow = (const float4*)(owb + (size_t)(i2 * 64 + c) * 128);
  int b = t / 576, l = t % 576;
  int rt = b * 576 + 575 - l;
  const float4* yf = (const float4*)(ys + (size_t)(g * 2 + 0) * MT * 128 + (size_t)t * 128);
  const float4* yb = (const float4*)(ys + (size_t)(g * 2 + 1) * MT * 128 + (size_t)rt * 128);
  float acc = 0.f;
  #pragma unroll 8
  for (int k = 0; k < 32; k++){
    float4 a = yf[k], bb = yb[k], w = ow[k];
    acc += (a.x + bb.x) * w.x + (a.y + bb.y) * w.y + (a.z + bb.z) * w.z + (a.w + bb.w) * w.w;
  }
  int ph = b / 5, pw = b % 5, nh = l / 24, nw = l % 24;
  size_t io = (size_t)g * 64 * MT + (size_t)c * MT + (nh * 5 + ph) * 120 + (nw * 5 + pw);
  imgB[io] = imgA[io] + acc;
}

__global__ __launch_bounds__(256) void k_outproj_win(const float* __restrict__ ys, const float* __restrict__ owb,
                                                     const float* __restrict__ obwb, float* __restrict__ imgA,
                                                     float* __restrict__ imgB, float* __restrict__ xM,
                                                     float* __restrict__ yM, int s, int writeM){
  int idx = blockIdx.x * 256 + threadIdx.x;
  int c = idx & 63, q = idx >> 6;
  int l = q % MT, g = q / MT;
  int i2 = g * 2 + s;
  const float4* ow  = (const float4*)(owb  + (size_t)(i2 * 64 + c) * 128);
  const float4* obw = (const float4*)(obwb + (size_t)(i2 * 64 + c) * 128);
  const float4* yf  = (const float4*)(ys + (size_t)(g * 2 + 0) * MT * 128 + (size_t)l * 128);
  const float4* ybr = (const float4*)(ys + (size_t)(g * 2 + 1) * MT * 128 + (size_t)(MT - 1 - l) * 128);
  const float4* ybd = (const float4*)(ys + (size_t)(g * 2 + 1) * MT * 128 + (size_t)l * 128);
  float accC = 0.f, accF = 0.f, accB = 0.f;
  #pragma unroll 4
  for (int k = 0; k < 32; k++){
    float4 a = yf[k], br = ybr[k], w = ow[k];
    accC += (a.x + br.x) * w.x + (a.y + br.y) * w.y + (a.z + br.z) * w.z + (a.w + br.w) * w.w;
    accF += a.x * w.x + a.y * w.y + a.z * w.z + a.w * w.w;
    float4 bd = ybd[k], wb = obw[k];
    accB += bd.x * wb.x + bd.y * wb.y + bd.z * wb.z + bd.w * wb.w;
  }
  size_t io = (size_t)g * 64 * MT + (size_t)c * MT + l;
  float nb = imgB[io] + accC;
  imgB[io] = nb;
  imgA[io] += nb;
  if (writeM){
    xM[(size_t)g * MT * 64 + (size_t)l * 64 + c] = accF;
    yM[(size_t)g * MT * 64 + (size_t)l * 64 + c] = accB;
  }
}

// ---------------- GCN (hub graph -> closed form) ----------------
__global__ __launch_bounds__(256) void k_gcn1(const float* __restrict__ xM, const float* __restrict__ yM,
                                              const float* __restrict__ W1, float* __restrict__ t1){
  __shared__ __align__(16) float nf[2][256];
  int l0 = blockIdx.x * 2;
  int tid = threadIdx.x;
  for (int idx = tid; idx < 512; idx += 256){
    int ll = idx >> 8, k = idx & 255;
    int l = l0 + ll;
    int which = k >> 6, cc = k & 63;
    const float* srcp = (which == 0) ? xM : (which == 1) ? yM
                       : (which == 2) ? (xM + (size_t)MT * 64) : (yM + (size_t)MT * 64);
    nf[ll][k] = srcp[(size_t)l * 64 + cc];
  }
  __syncthreads();
  int f = tid & 127, ll = tid >> 7;
  const float4* w4 = (const float4*)(W1 + (size_t)f * 256);
  const float4* a4 = (const float4*)nf[ll];
  float acc = 0.f;
  #pragma unroll 8
  for (int k = 0; k < 64; k++){
    float4 a = a4[k], w = w4[k];
    acc += a.x * w.x + a.y * w.y + a.z * w.z + a.w * w.w;
  }
  t1[(size_t)(l0 + ll) * 128 + f] = acc;
}

__global__ __launch_bounds__(128) void k_hub1(const float* __restrict__ t1, float* __restrict__ hubm){
  int f = threadIdx.x;
  float sum = 0.f;
  for (int hb = 0; hb < 450; hb++) sum += t1[(size_t)(hb * 32) * 128 + f];
  hubm[f] = sum * (1.f / 450.f);
}

__global__ __launch_bounds__(128) void k_gcn2(const float* __restrict__ t1, const float* __restrict__ hubm,
                                              const float* __restrict__ b1, const float* __restrict__ W2,
                                              float* __restrict__ t2){
  __shared__ __align__(16) float hbuf[2][128];
  int l0 = blockIdx.x * 2;
  int tid = threadIdx.x;
  for (int idx = tid; idx < 256; idx += 128){
    int ll = idx >> 7, k = idx & 127;
    int l = l0 + ll;
    float raw = ((l & 31) == 0) ? hubm[k] : t1[(size_t)l * 128 + k];
    hbuf[ll][k] = fmaxf(raw + b1[k], 0.f);
  }
  __syncthreads();
  int c = tid & 63, ll = tid >> 6;
  const float4* w4 = (const float4*)(W2 + (size_t)c * 128);
  const float4* a4 = (const float4*)hbuf[ll];
  float acc = 0.f;
  #pragma unroll 8
  for (int k = 0; k < 32; k++){
    float4 a = a4[k], w = w4[k];
    acc += a.x * w.x + a.y * w.y + a.z * w.z + a.w * w.w;
  }
  t2[(size_t)(l0 + ll) * 64 + c] = acc;
}

__global__ __launch_bounds__(64) void k_hub2(const float* __restrict__ t2, float* __restrict__ hubm2){
  int c = threadIdx.x;
  float sum = 0.f;
  for (int hb = 0; hb < 450; hb++) sum += t2[(size_t)(hb * 32) * 64 + c];
  hubm2[c] = sum * (1.f / 450.f);
}

__global__ __launch_bounds__(256) void k_final(const void* __restrict__ x, const float* __restrict__ t2,
                                               const float* __restrict__ hubm2, const float* __restrict__ b2,
                                               const float* __restrict__ imgA, void* __restrict__ out,
                                               const int* __restrict__ flag){
  int idx = blockIdx.x * 256 + threadIdx.x;  // c*MT + l
  int l = idx % MT, c = idx / MT;
  int fp32 = *flag;
  float gval = (((l & 31) == 0) ? hubm2[c] : t2[(size_t)l * 64 + c]) + b2[c];
  float a0 = imgA[idx];
  float a1 = imgA[(size_t)64 * MT + (size_t)c * MT + (l % 120) * 120 + l / 120];
  float xv = fp32 ? ((const float*)x)[idx] : b2f(((const u16*)x)[idx]);
  float val = gval + xv + a0 + a1;
  if (fp32) ((float*)out)[idx] = val;
  else      ((u16*)out)[idx] = f2b(val);
}

extern "C" void kernel_launch(void* const* d_in, const int* in_sizes, int n_in,
                              void* d_out, int out_size, void* d_ws, size_t ws_size,
                              hipStream_t stream){
  int I_X=0,I_PIW=1,I_PCW=2,I_PCB=3,I_PXP=4,I_PDTW=5,I_PDTB=6,I_PAL=7,I_PD=8,I_PLG=9,I_PLB=10,
      I_WIW=11,I_WCW=12,I_WCB=13,I_WXP=14,I_WDTW=15,I_WDTB=16,I_WAL=17,I_WD=18,I_WLG=19,I_WLB=20,
      I_POW=21,I_WOW=22,I_WOBW=23,I_G1=24,I_GB1=25,I_G2=26,I_GB2=27;
  if (n_in >= 28 && in_sizes[9] == 131072){
    I_WIW=9;I_WCW=10;I_WCB=11;I_WXP=12;I_WDTW=13;I_WDTB=14;I_WAL=15;I_WD=16;
    I_PLG=17;I_PLB=18;I_WLG=19;I_WLB=20;
  }
  if (n_in < 28 || in_sizes[I_PIW] != 131072 || out_size != 921600) return;

  float* Wp = (float*)d_ws;
  size_t off = 0;
  auto alloc = [&](size_t n){ size_t r = off; off += (n + 63) & ~(size_t)63; return r; };
  size_t oFlag=alloc(64);
  size_t oPIW=alloc(131072), oPCW=alloc(4096), oPCB=alloc(1024), oPXP=alloc(36864),
         oPDTW=alloc(4096), oPDTB=alloc(1024), oPA=alloc(16384), oPD=alloc(1024),
         oPLG=alloc(256), oPLB=alloc(256);
  size_t oWIW=alloc(131072), oWCW=alloc(4096), oWCB=alloc(1024), oWXP=alloc(36864),
         oWDTW=alloc(4096), oWDTB=alloc(1024), oWA=alloc(16384), oWD=alloc(1024),
         oWLG=alloc(256), oWLB=alloc(256);
  size_t oPOW=alloc(32768), oWOW=alloc(32768), oWOBW=alloc(32768),
         oG1=alloc(32768), oGB1=alloc(128), oG2=alloc(8192), oGB2=alloc(64);
  size_t oPIWT=alloc(131072), oWIWT=alloc(131072);
  size_t oImgA=alloc(2UL*64*MT), oImgB=alloc(2UL*64*MT), oXn=alloc(2UL*MT*64);
  size_t oRaw=alloc(4UL*MT*128);             // xh_raw; aliased as ys after conv
  size_t oZ=alloc(4UL*MT*128), oXhs=alloc(4UL*MT*128), oDelta=alloc(4UL*MT*128);
  size_t oBm=alloc(4UL*MT*16), oCm=alloc(4UL*MT*16);
  size_t oAc=alloc(4UL*WNC*2048), oBc=alloc(4UL*WNC*2048), oHin=alloc(4UL*WNC*2048);
  size_t oXM=alloc(2UL*MT*64), oYM=alloc(2UL*MT*64);
  size_t oT1=alloc((size_t)MT*128), oHub1=alloc(128), oT2=alloc((size_t)MT*64), oHub2=alloc(64);
  if (ws_size < off * sizeof(float)) return;

  int* flag = (int*)(Wp + oFlag);
  k_detect<<<dim3(1), dim3(256), 0, stream>>>((const u16*)d_in[I_PAL], 16384, flag);

  PTab tb;
  int ti = 0;
  auto add = [&](int inIdx, size_t o, int n, int neg){
    tb.src[ti] = d_in[inIdx]; tb.dst[ti] = Wp + o; tb.n[ti] = n; tb.neg[ti] = neg; ti++;
  };
  add(I_PIW,oPIW,131072,0); add(I_PCW,oPCW,4096,0); add(I_PCB,oPCB,1024,0); add(I_PXP,oPXP,36864,0);
  add(I_PDTW,oPDTW,4096,0); add(I_PDTB,oPDTB,1024,0); add(I_PAL,oPA,16384,1); add(I_PD,oPD,1024,0);
  add(I_PLG,oPLG,256,0); add(I_PLB,oPLB,256,0);
  add(I_WIW,oWIW,131072,0); add(I_WCW,oWCW,4096,0); add(I_WCB,oWCB,1024,0); add(I_WXP,oWXP,36864,0);
  add(I_WDTW,oWDTW,4096,0); add(I_WDTB,oWDTB,1024,0); add(I_WAL,oWA,16384,1); add(I_WD,oWD,1024,0);
  add(I_WLG,oWLG,256,0); add(I_WLB,oWLB,256,0);
  add(I_POW,oPOW,32768,0); add(I_WOW,oWOW,32768,0); add(I_WOBW,oWOBW,32768,0);
  add(I_G1,oG1,32768,0); add(I_GB1,oGB1,128,0); add(I_G2,oG2,8192,0); add(I_GB2,oGB2,64,0);

  k_cvt<<<dim3(128, 27), dim3(256), 0, stream>>>(tb, flag);
  k_wtrans<<<dim3(64, 16), dim3(256), 0, stream>>>(Wp+oPIW, Wp+oWIW, Wp+oPIWT, Wp+oWIWT);
  k_cvt_x<<<dim3(3600), dim3(256), 0, stream>>>(d_in[I_X], Wp + oImgA, flag);

  float *imgA = Wp+oImgA, *imgB = Wp+oImgB, *xn = Wp+oXn, *raw = Wp+oRaw, *ys = Wp+oRaw,
        *zz = Wp+oZ, *xhs = Wp+oXhs, *delta = Wp+oDelta, *Bm = Wp+oBm, *Cm = Wp+oCm,
        *Ac = Wp+oAc, *Bc = Wp+oBc, *Hin = Wp+oHin, *xM = Wp+oXM, *yM = Wp+oYM;

  for (int s = 0; s < 2; s++){
    k_prep_xn<<<dim3(7200), dim3(256), 0, stream>>>(imgA, Wp+oPLG, Wp+oPLB, xn, s, 1);
    k_inproj <<<dim3(450, 4), dim3(256), 0, stream>>>(xn, Wp+oPIWT, raw, zz, s, 1);
    k_conv   <<<dim3(7200, 4), dim3(256), 0, stream>>>(raw, Wp+oPCW, Wp+oPCB, xhs, s, 1);
    k_xproj  <<<dim3(1800, 4), dim3(256), 0, stream>>>(xhs, Wp+oPXP, Wp+oPDTW, Wp+oPDTB, delta, Bm, Cm, s);
    k_scan_pixel<<<dim3(25, 4), dim3(256), 0, stream>>>(delta, xhs, Bm, Cm, zz, Wp+oPA, Wp+oPD, ys, s);
    k_outproj_pixel<<<dim3(7200), dim3(256), 0, stream>>>(ys, Wp+oPOW, imgA, imgB, s);

    k_prep_xn<<<dim3(7200), dim3(256), 0, stream>>>(imgB, Wp+oWLG, Wp+oWLB, xn, s, 0);
    k_inproj <<<dim3(450, 4), dim3(256), 0, stream>>>(xn, Wp+oWIWT, raw, zz, s, 0);
    k_conv   <<<dim3(7200, 4), dim3(256), 0, stream>>>(raw, Wp+oWCW, Wp+oWCB, xhs, s, 0);
    k_xproj  <<<dim3(1800, 4), dim3(256), 0, stream>>>(xhs, Wp+oWXP, Wp+oWDTW, Wp+oWDTB, delta, Bm, Cm, s);
    k_scan_win_p1<<<dim3(WNC, 4), dim3(256), 0, stream>>>(delta, xhs, Bm, Wp+oWA, Ac, Bc, s);
    k_scan_win_p2<<<dim3(32), dim3(256), 0, stream>>>(Ac, Bc, Hin);
    k_scan_win_p3<<<dim3(WNC, 4), dim3(256), 0, stream>>>(delta, xhs, Bm, Cm, zz, Wp+oWA, Wp+oWD, Hin, ys, s);
    k_outproj_win<<<dim3(7200), dim3(256), 0, stream>>>(ys, Wp+oWOW, Wp+oWOBW, imgA, imgB, xM, yM, s, (s == 1) ? 1 : 0);
  }

  k_gcn1<<<dim3(7200), dim3(256), 0, stream>>>(xM, yM, Wp+oG1, Wp+oT1);
  k_hub1<<<dim3(1), dim3(128), 0, stream>>>(Wp+oT1, Wp+oHub1);
  k_gcn2<<<dim3(7200), dim3(128), 0, stream>>>(Wp+oT1, Wp+oHub1, Wp+oGB1, Wp+oG2, Wp+oT2);
  k_hub2<<<dim3(1), dim3(64), 0, stream>>>(Wp+oT2, Wp+oHub2);
  k_final<<<dim3(3600), dim3(256), 0, stream>>>(d_in[I_X], Wp+oT2, Wp+oHub2, Wp+oGB2, imgA, d_out, flag);
}

// Round 5
// 1785.495 us; speedup vs baseline: 3.0544x; 1.5755x over previous
//
#include <hip/hip_runtime.h>
#include <hip/hip_bf16.h>

#define MT 14400
#define WNC 150     // window scan chunks
#define WCL 96      // window chunk length (WNC*WCL = MT)
#define PT 16       // LDS tile (timesteps) for all scans

typedef unsigned short u16;

__device__ __forceinline__ float b2f(u16 u){
  union { unsigned int i; float f; } v; v.i = ((unsigned int)u) << 16; return v.f;
}
__device__ __forceinline__ u16 f2b(float f){
  union { unsigned int i; float f; } v; v.f = f;
  unsigned int x = v.i;
  return (u16)((x + 0x7fffu + ((x >> 16) & 1u)) >> 16);
}
__device__ __forceinline__ float siluf(float x){ return x / (1.f + expf(-x)); }
__device__ __forceinline__ float softplusf(float x){ return (x > 20.f) ? x : log1pf(expf(x)); }

// ---------------- dtype detection ----------------
__global__ __launch_bounds__(256) void k_detect(const u16* __restrict__ a, int n, int* __restrict__ flag){
  __shared__ int found;
  if (threadIdx.x == 0) found = 0;
  __syncthreads();
  int f = 0;
  for (int i = threadIdx.x; i < n; i += 256){
    float v = b2f(a[i]);
    if (!(fabsf(v) <= 1e9f)) f = 1;
  }
  if (f) atomicOr(&found, 1);
  __syncthreads();
  if (threadIdx.x == 0) *flag = found;
}

// ---------------- param conversion ----------------
struct PTab {
  const void* src[27];
  float* dst[27];
  int n[27];
  int neg[27];
};

__global__ __launch_bounds__(256) void k_cvt(PTab tb, const int* __restrict__ flag){
  int id = blockIdx.y;
  int n = tb.n[id];
  int fp32 = *flag;
  float* d = tb.dst[id];
  int ng = tb.neg[id];
  for (int i = blockIdx.x * 256 + threadIdx.x; i < n; i += gridDim.x * 256){
    float v = fp32 ? ((const float*)tb.src[id])[i] : b2f(((const u16*)tb.src[id])[i]);
    if (ng) v = -expf(v) * 1.4426950408889634f;
    d[i] = v;
  }
}

// transpose in_w: W[mat][256][64] -> WT[mat][64][256]
__global__ __launch_bounds__(256) void k_wtrans(const float* __restrict__ Wpix, const float* __restrict__ Wwin,
                                                float* __restrict__ WTpix, float* __restrict__ WTwin){
  int mat = blockIdx.y;
  const float* src = (mat < 8) ? (Wpix + (size_t)mat * 16384) : (Wwin + (size_t)(mat - 8) * 16384);
  float* dst = (mat < 8) ? (WTpix + (size_t)mat * 16384) : (WTwin + (size_t)(mat - 8) * 16384);
  int idx = blockIdx.x * 256 + threadIdx.x;
  int e = idx >> 6, k = idx & 63;
  dst[k * 256 + e] = src[idx];
}

// combined GCN-1 weights: W1c[str][k][f] = sum_c w_str[c][k] * W1[f][str*64+c]
// str: 0 -> (g0, ow) ; 1 -> (g0, obw) ; 2 -> (g1, ow) ; 3 -> (g1, obw);  i2 = g*2+1
__global__ __launch_bounds__(256) void k_gcn1w(const float* __restrict__ ow, const float* __restrict__ obw,
                                               const float* __restrict__ G1, float* __restrict__ W1c){
  int str = blockIdx.y;
  int g = str >> 1, d = str & 1;
  int i2 = g * 2 + 1;
  const float* W = (d ? obw : ow) + (size_t)(i2 * 64) * 128;
  int idx = blockIdx.x * 256 + threadIdx.x;   // kk*128 + f
  int kk = idx >> 7, f = idx & 127;
  float acc = 0.f;
  #pragma unroll 8
  for (int c = 0; c < 64; c++)
    acc += W[(size_t)c * 128 + kk] * G1[(size_t)f * 256 + str * 64 + c];
  W1c[((size_t)str * 128 + kk) * 128 + f] = acc;
}

__global__ __launch_bounds__(256) void k_cvt_x(const void* __restrict__ x, float* __restrict__ imgA,
                                               const int* __restrict__ flag){
  int idx = blockIdx.x * 256 + threadIdx.x;
  int l = idx % MT, c = idx / MT;
  float v = (*flag) ? ((const float*)x)[idx] : b2f(((const u16*)x)[idx]);
  imgA[idx] = v;
  imgA[(size_t)64 * MT + (size_t)c * MT + (l % 120) * 120 + l / 120] = v;
}

// ---------------- layernorm + token-order gather ----------------
__global__ __launch_bounds__(256) void k_prep_xn(const float* __restrict__ img, const float* __restrict__ lng,
                                                 const float* __restrict__ lnb, float* __restrict__ xn,
                                                 int s, int pixelMode){
  int tid = threadIdx.x;
  int q = blockIdx.x * 4 + (tid >> 6);
  int c = tid & 63;
  int g = q / MT, t = q % MT;
  int hw;
  if (pixelMode){
    int b = t / 576, l = t % 576;
    int ph = b / 5, pw = b % 5, nh = l / 24, nw = l % 24;
    hw = (nh * 5 + ph) * 120 + (nw * 5 + pw);
  } else hw = t;
  float v = img[(size_t)g * 64 * MT + (size_t)c * MT + hw];
  float sm = v;
  #pragma unroll
  for (int m = 32; m >= 1; m >>= 1) sm += __shfl_xor(sm, m);
  float mean = sm * (1.f / 64.f);
  float dv = v - mean;
  float s2 = dv * dv;
  #pragma unroll
  for (int m = 32; m >= 1; m >>= 1) s2 += __shfl_xor(s2, m);
  float var = s2 * (1.f / 64.f);
  int i2 = g * 2 + s;
  float o = dv * rsqrtf(var + 1e-5f) * lng[i2 * 64 + c] + lnb[i2 * 64 + c];
  xn[(size_t)g * MT * 64 + (size_t)t * 64 + c] = o;
}

// ---------------- in-projection: register-tiled GEMM ----------------
__global__ __launch_bounds__(256) void k_inproj(const float* __restrict__ xn, const float* __restrict__ WT,
                                                float* __restrict__ xh, float* __restrict__ z,
                                                int s, int pixelMode){
  int gd = blockIdx.y, g = gd >> 1, dir = gd & 1;
  int i2 = (g * 2 + s) * 2 + dir;
  int ttile = blockIdx.x >> 1, ntile = blockIdx.x & 1;
  int t0 = ttile * 64;
  const float* WTm = WT + (size_t)i2 * 16384 + ntile * 128;

  __shared__ __align__(16) float sA[64 * 68];
  __shared__ __align__(16) float sB[64 * 128];
  int tid = threadIdx.x;

  {
    int k0 = (tid & 15) * 4;
    #pragma unroll
    for (int it = 0; it < 4; it++){
      int t = (tid >> 4) + it * 16;
      int tq = t0 + t, src = tq;
      if (dir){
        if (pixelMode){ int b = tq / 576, l = tq % 576; src = b * 576 + 575 - l; }
        else src = MT - 1 - tq;
      }
      float4 v = *(const float4*)&xn[(size_t)g * MT * 64 + (size_t)src * 64 + k0];
      *(float4*)&sA[t * 68 + k0] = v;
    }
  }
  {
    #pragma unroll
    for (int it = 0; it < 8; it++){
      int idx = it * 256 + tid;
      int k = idx >> 5, e4 = (idx & 31) * 4;
      float4 v = *(const float4*)&WTm[(size_t)k * 256 + e4];
      *(float4*)&sB[k * 128 + e4] = v;
    }
  }
  __syncthreads();

  int tr = tid >> 4, tc = tid & 15;
  float acc[4][8];
  #pragma unroll
  for (int i = 0; i < 4; i++)
    #pragma unroll
    for (int j = 0; j < 8; j++) acc[i][j] = 0.f;

  for (int k0 = 0; k0 < 64; k0 += 4){
    float4 a4[4];
    #pragma unroll
    for (int i = 0; i < 4; i++) a4[i] = *(const float4*)&sA[(tr * 4 + i) * 68 + k0];
    #pragma unroll
    for (int kk = 0; kk < 4; kk++){
      float4 b0 = *(const float4*)&sB[(k0 + kk) * 128 + tc * 8];
      float4 b1 = *(const float4*)&sB[(k0 + kk) * 128 + tc * 8 + 4];
      float bv[8] = {b0.x, b0.y, b0.z, b0.w, b1.x, b1.y, b1.z, b1.w};
      #pragma unroll
      for (int i = 0; i < 4; i++){
        const float* ap = (const float*)&a4[i];
        float av = ap[kk];
        #pragma unroll
        for (int j = 0; j < 8; j++) acc[i][j] += av * bv[j];
      }
    }
  }

  float* dst = ntile ? z : xh;
  #pragma unroll
  for (int i = 0; i < 4; i++){
    int t_out = t0 + tr * 4 + i;
    size_t base = (size_t)gd * MT * 128 + (size_t)t_out * 128 + tc * 8;
    *(float4*)&dst[base]     = make_float4(acc[i][0], acc[i][1], acc[i][2], acc[i][3]);
    *(float4*)&dst[base + 4] = make_float4(acc[i][4], acc[i][5], acc[i][6], acc[i][7]);
  }
}

// ---------------- causal depthwise conv (K=4) + SiLU ----------------
__global__ __launch_bounds__(256) void k_conv(const float* __restrict__ raw, const float* __restrict__ cw,
                                              const float* __restrict__ cb, float* __restrict__ xhs,
                                              int s, int pixelMode){
  int gd = blockIdx.y, g = gd >> 1, dir = gd & 1;
  int i2 = (g * 2 + s) * 2 + dir;
  int idx = blockIdx.x * 256 + threadIdx.x;
  int t = idx >> 7, ch = idx & 127;
  int SL = pixelMode ? 576 : MT;
  int pos = t % SL;
  const float* src = raw + (size_t)gd * MT * 128;
  const float* wrow = cw + (size_t)(i2 * 128 + ch) * 4;
  float acc = cb[i2 * 128 + ch];
  #pragma unroll
  for (int i = 0; i < 4; i++){
    int d = 3 - i;
    if (pos >= d) acc += src[(size_t)(t - d) * 128 + ch] * wrow[i];
  }
  xhs[(size_t)gd * MT * 128 + idx] = siluf(acc);
}

// ---------------- x-projection -> delta(softplus), B, C ----------------
__global__ __launch_bounds__(256) void k_xproj(const float* __restrict__ xhs, const float* __restrict__ xpb,
                                               const float* __restrict__ dtw, const float* __restrict__ dtb,
                                               float* __restrict__ delta, float* __restrict__ Bm,
                                               float* __restrict__ Cm, int s){
  int gd = blockIdx.y, g = gd >> 1, dir = gd & 1;
  int i2 = (g * 2 + s) * 2 + dir;
  const float* XP = xpb + (size_t)i2 * 36 * 128;
  const float* DW = dtw + (size_t)i2 * 128 * 4;
  const float* DB = dtb + (size_t)i2 * 128;
  int t0 = blockIdx.x * 8;
  __shared__ __align__(16) float xv[8][128];
  __shared__ float dbl[8][36];
  int tid = threadIdx.x;
  const float* src = xhs + (size_t)gd * MT * 128 + (size_t)t0 * 128;
  for (int idx = tid; idx < 8 * 128; idx += 256) xv[idx >> 7][idx & 127] = src[idx];
  __syncthreads();
  for (int o = tid; o < 8 * 36; o += 256){
    int tok = o / 36, e = o - tok * 36;
    const float4* a4 = (const float4*)xv[tok];
    const float4* w4 = (const float4*)(XP + (size_t)e * 128);
    float acc = 0.f;
    #pragma unroll 8
    for (int k = 0; k < 32; k++){
      float4 a = a4[k], w = w4[k];
      acc += a.x*w.x + a.y*w.y + a.z*w.z + a.w*w.w;
    }
    dbl[tok][e] = acc;
  }
  __syncthreads();
  for (int o = tid; o < 8 * 128; o += 256){
    int tok = o >> 7, d = o & 127;
    float v = DB[d];
    #pragma unroll
    for (int r = 0; r < 4; r++) v += dbl[tok][r] * DW[d * 4 + r];
    delta[(size_t)gd * MT * 128 + (size_t)(t0 + tok) * 128 + d] = softplusf(v);
  }
  for (int o = tid; o < 8 * 32; o += 256){
    int tok = o >> 5, n = o & 31;
    int t = t0 + tok;
    if (n < 16) Bm[(size_t)gd * MT * 16 + (size_t)t * 16 + n] = dbl[tok][4 + n];
    else        Cm[(size_t)gd * MT * 16 + (size_t)t * 16 + (n - 16)] = dbl[tok][20 + (n - 16)];
  }
}

// ---------------- selective scan, LDS-staged ----------------
__global__ __launch_bounds__(256) void k_scan_pixel(const float* __restrict__ delta, const float* __restrict__ xhs,
                                                    const float* __restrict__ Bm, const float* __restrict__ Cm,
                                                    const float* __restrict__ zz, const float* __restrict__ A2b,
                                                    const float* __restrict__ Db, float* __restrict__ ys, int s){
  int gd = blockIdx.y, g = gd >> 1, dir = gd & 1;
  int i2 = (g * 2 + s) * 2 + dir;
  int seq = blockIdx.x;
  int tid = threadIdx.x, ch = tid >> 1, nb = (tid & 1) * 8;
  float A2[8], h[8];
  #pragma unroll
  for (int j = 0; j < 8; j++){
    A2[j] = A2b[((size_t)i2 * 128 + ch) * 16 + nb + j];
    h[j] = 0.f;
  }
  float Dv = Db[(size_t)i2 * 128 + ch];
  size_t so = (size_t)gd * MT * 128 + (size_t)seq * 576 * 128;
  size_t bo = (size_t)gd * MT * 16  + (size_t)seq * 576 * 16;
  __shared__ __align__(16) float sd[2][PT * 128];
  __shared__ __align__(16) float su[2][PT * 128];
  __shared__ __align__(16) float sb[2][PT * 16];
  __shared__ __align__(16) float sc[2][PT * 16];
  __shared__ __align__(16) float sy[PT * 128];
  float4 rd0, rd1, ru0, ru1; float rb, rc;
  {
    const float4* d4 = (const float4*)(delta + so);
    const float4* u4 = (const float4*)(xhs + so);
    rd0 = d4[2 * tid]; rd1 = d4[2 * tid + 1];
    ru0 = u4[2 * tid]; ru1 = u4[2 * tid + 1];
    rb = (Bm + bo)[tid]; rc = (Cm + bo)[tid];
  }
  const int NT = 576 / PT;
  for (int tile = 0; tile < NT; tile++){
    int bs = tile & 1;
    __syncthreads();
    ((float4*)sd[bs])[2 * tid] = rd0; ((float4*)sd[bs])[2 * tid + 1] = rd1;
    ((float4*)su[bs])[2 * tid] = ru0; ((float4*)su[bs])[2 * tid + 1] = ru1;
    sb[bs][tid] = rb; sc[bs][tid] = rc;
    __syncthreads();
    if (tile + 1 < NT){
      const float4* d4 = (const float4*)(delta + so + (size_t)(tile + 1) * PT * 128);
      const float4* u4 = (const float4*)(xhs + so + (size_t)(tile + 1) * PT * 128);
      rd0 = d4[2 * tid]; rd1 = d4[2 * tid + 1];
      ru0 = u4[2 * tid]; ru1 = u4[2 * tid + 1];
      rb = (Bm + bo + (size_t)(tile + 1) * PT * 16)[tid];
      rc = (Cm + bo + (size_t)(tile + 1) * PT * 16)[tid];
    }
    #pragma unroll
    for (int t = 0; t < PT; t++){
      float dt = sd[bs][t * 128 + ch];
      float u  = su[bs][t * 128 + ch];
      float du = dt * u;
      float acc = 0.f;
      #pragma unroll
      for (int j = 0; j < 8; j++){
        float e = exp2f(dt * A2[j]);
        h[j] = h[j] * e + du * sb[bs][t * 16 + nb + j];
        acc += h[j] * sc[bs][t * 16 + nb + j];
      }
      acc += __shfl_xor(acc, 1);
      if (!(tid & 1)) sy[t * 128 + ch] = acc + u * Dv;
    }
    __syncthreads();
    {
      const float4* z4 = (const float4*)(zz + so + (size_t)tile * PT * 128);
      float4* y4 = (float4*)(ys + so + (size_t)tile * PT * 128);
      #pragma unroll
      for (int i = 0; i < 2; i++){
        int f = 2 * tid + i;
        float4 yv = ((float4*)sy)[f];
        float4 zv = z4[f];
        yv.x *= siluf(zv.x); yv.y *= siluf(zv.y); yv.z *= siluf(zv.z); yv.w *= siluf(zv.w);
        y4[f] = yv;
      }
    }
  }
}

__global__ __launch_bounds__(256) void k_scan_win_p1(const float* __restrict__ delta, const float* __restrict__ xhs,
                                                     const float* __restrict__ Bm, const float* __restrict__ A2b,
                                                     float* __restrict__ Acar, float* __restrict__ Bcar, int s){
  int gd = blockIdx.y, g = gd >> 1, dir = gd & 1;
  int i2 = (g * 2 + s) * 2 + dir;
  int chunk = blockIdx.x;
  int tid = threadIdx.x, ch = tid >> 1, nb = (tid & 1) * 8;
  float A2[8], ap[8], bc[8];
  #pragma unroll
  for (int j = 0; j < 8; j++){
    A2[j] = A2b[((size_t)i2 * 128 + ch) * 16 + nb + j];
    ap[j] = 1.f; bc[j] = 0.f;
  }
  size_t so = (size_t)gd * MT * 128 + (size_t)chunk * WCL * 128;
  size_t bo = (size_t)gd * MT * 16  + (size_t)chunk * WCL * 16;
  __shared__ __align__(16) float sd[2][PT * 128];
  __shared__ __align__(16) float su[2][PT * 128];
  __shared__ __align__(16) float sb[2][PT * 16];
  float4 rd0, rd1, ru0, ru1; float rb;
  {
    const float4* d4 = (const float4*)(delta + so);
    const float4* u4 = (const float4*)(xhs + so);
    rd0 = d4[2 * tid]; rd1 = d4[2 * tid + 1];
    ru0 = u4[2 * tid]; ru1 = u4[2 * tid + 1];
    rb = (Bm + bo)[tid];
  }
  const int NT = WCL / PT;
  for (int tile = 0; tile < NT; tile++){
    int bs = tile & 1;
    __syncthreads();
    ((float4*)sd[bs])[2 * tid] = rd0; ((float4*)sd[bs])[2 * tid + 1] = rd1;
    ((float4*)su[bs])[2 * tid] = ru0; ((float4*)su[bs])[2 * tid + 1] = ru1;
    sb[bs][tid] = rb;
    __syncthreads();
    if (tile + 1 < NT){
      const float4* d4 = (const float4*)(delta + so + (size_t)(tile + 1) * PT * 128);
      const float4* u4 = (const float4*)(xhs + so + (size_t)(tile + 1) * PT * 128);
      rd0 = d4[2 * tid]; rd1 = d4[2 * tid + 1];
      ru0 = u4[2 * tid]; ru1 = u4[2 * tid + 1];
      rb = (Bm + bo + (size_t)(tile + 1) * PT * 16)[tid];
    }
    #pragma unroll
    for (int t = 0; t < PT; t++){
      float dt = sd[bs][t * 128 + ch];
      float u  = su[bs][t * 128 + ch];
      float du = dt * u;
      #pragma unroll
      for (int j = 0; j < 8; j++){
        float e = exp2f(dt * A2[j]);
        bc[j] = bc[j] * e + du * sb[bs][t * 16 + nb + j];
        ap[j] *= e;
      }
    }
  }
  size_t o = ((size_t)gd * WNC + chunk) * 2048 + (size_t)ch * 16 + nb;
  float4* A4 = (float4*)(Acar + o);
  float4* B4 = (float4*)(Bcar + o);
  A4[0] = make_float4(ap[0], ap[1], ap[2], ap[3]);
  A4[1] = make_float4(ap[4], ap[5], ap[6], ap[7]);
  B4[0] = make_float4(bc[0], bc[1], bc[2], bc[3]);
  B4[1] = make_float4(bc[4], bc[5], bc[6], bc[7]);
}

__global__ __launch_bounds__(256) void k_scan_win_p2(const float* __restrict__ Acar, const float* __restrict__ Bcar,
                                                     float* __restrict__ Hin){
  int flat = blockIdx.x * 256 + threadIdx.x;
  int cs = flat & 2047, gd = flat >> 11;
  float h = 0.f;
  for (int c = 0; c < WNC; c++){
    size_t o = ((size_t)gd * WNC + c) * 2048 + cs;
    Hin[o] = h;
    h = Acar[o] * h + Bcar[o];
  }
}

__global__ __launch_bounds__(256) void k_scan_win_p3(const float* __restrict__ delta, const float* __restrict__ xhs,
                                                     const float* __restrict__ Bm, const float* __restrict__ Cm,
                                                     const float* __restrict__ zz, const float* __restrict__ A2b,
                                                     const float* __restrict__ Db, const float* __restrict__ Hin,
                                                     float* __restrict__ ys, int s){
  int gd = blockIdx.y, g = gd >> 1, dir = gd & 1;
  int i2 = (g * 2 + s) * 2 + dir;
  int chunk = blockIdx.x;
  int tid = threadIdx.x, ch = tid >> 1, nb = (tid & 1) * 8;
  float A2[8], h[8];
  size_t ho = ((size_t)gd * WNC + chunk) * 2048 + (size_t)ch * 16 + nb;
  {
    const float4* H4 = (const float4*)(Hin + ho);
    float4 h0 = H4[0], h1 = H4[1];
    h[0]=h0.x; h[1]=h0.y; h[2]=h0.z; h[3]=h0.w;
    h[4]=h1.x; h[5]=h1.y; h[6]=h1.z; h[7]=h1.w;
  }
  #pragma unroll
  for (int j = 0; j < 8; j++) A2[j] = A2b[((size_t)i2 * 128 + ch) * 16 + nb + j];
  float Dv = Db[(size_t)i2 * 128 + ch];
  size_t so = (size_t)gd * MT * 128 + (size_t)chunk * WCL * 128;
  size_t bo = (size_t)gd * MT * 16  + (size_t)chunk * WCL * 16;
  __shared__ __align__(16) float sd[2][PT * 128];
  __shared__ __align__(16) float su[2][PT * 128];
  __shared__ __align__(16) float sb[2][PT * 16];
  __shared__ __align__(16) float sc[2][PT * 16];
  __shared__ __align__(16) float sy[PT * 128];
  float4 rd0, rd1, ru0, ru1; float rb, rc;
  {
    const float4* d4 = (const float4*)(delta + so);
    const float4* u4 = (const float4*)(xhs + so);
    rd0 = d4[2 * tid]; rd1 = d4[2 * tid + 1];
    ru0 = u4[2 * tid]; ru1 = u4[2 * tid + 1];
    rb = (Bm + bo)[tid]; rc = (Cm + bo)[tid];
  }
  const int NT = WCL / PT;
  for (int tile = 0; tile < NT; tile++){
    int bs = tile & 1;
    __syncthreads();
    ((float4*)sd[bs])[2 * tid] = rd0; ((float4*)sd[bs])[2 * tid + 1] = rd1;
    ((float4*)su[bs])[2 * tid] = ru0; ((float4*)su[bs])[2 * tid + 1] = ru1;
    sb[bs][tid] = rb; sc[bs][tid] = rc;
    __syncthreads();
    if (tile + 1 < NT){
      const float4* d4 = (const float4*)(delta + so + (size_t)(tile + 1) * PT * 128);
      const float4* u4 = (const float4*)(xhs + so + (size_t)(tile + 1) * PT * 128);
      rd0 = d4[2 * tid]; rd1 = d4[2 * tid + 1];
      ru0 = u4[2 * tid]; ru1 = u4[2 * tid + 1];
      rb = (Bm + bo + (size_t)(tile + 1) * PT * 16)[tid];
      rc = (Cm + bo + (size_t)(tile + 1) * PT * 16)[tid];
    }
    #pragma unroll
    for (int t = 0; t < PT; t++){
      float dt = sd[bs][t * 128 + ch];
      float u  = su[bs][t * 128 + ch];
      float du = dt * u;
      float acc = 0.f;
      #pragma unroll
      for (int j = 0; j < 8; j++){
        float e = exp2f(dt * A2[j]);
        h[j] = h[j] * e + du * sb[bs][t * 16 + nb + j];
        acc += h[j] * sc[bs][t * 16 + nb + j];
      }
      acc += __shfl_xor(acc, 1);
      if (!(tid & 1)) sy[t * 128 + ch] = acc + u * Dv;
    }
    __syncthreads();
    {
      const float4* z4 = (const float4*)(zz + so + (size_t)tile * PT * 128);
      float4* y4 = (float4*)(ys + so + (size_t)tile * PT * 128);
      #pragma unroll
      for (int i = 0; i < 2; i++){
        int f = 2 * tid + i;
        float4 yv = ((float4*)sy)[f];
        float4 zv = z4[f];
        yv.x *= siluf(zv.x); yv.y *= siluf(zv.y); yv.z *= siluf(zv.z); yv.w *= siluf(zv.w);
        y4[f] = yv;
      }
    }
  }
}

// ---------------- out-projection (tiled GEMM) + residual ----------------
// pixel: imgB[io] = imgA[io] + (yf[t]+yb[rt]) . ow[c]
__global__ __launch_bounds__(256) void k_outproj_pixel(const float* __restrict__ ys, const float* __restrict__ owb,
                                                       const float* __restrict__ imgA, float* __restrict__ imgB, int s){
  int g = blockIdx.y;
  int i2 = g * 2 + s;
  int tile = blockIdx.x;
  int t0 = tile * 64;
  int b = tile / 9, l0 = (tile % 9) * 64;
  const float* W = owb + (size_t)(i2 * 64) * 128;
  const float* Yf = ys + (size_t)(g * 2 + 0) * MT * 128;
  const float* Yb = ys + (size_t)(g * 2 + 1) * MT * 128;
  __shared__ __align__(16) float sA[64 * 36];
  __shared__ __align__(16) float sW[32 * 68];
  __shared__ __align__(16) float sO[64 * 68];
  int tid = threadIdx.x;
  int tr = tid >> 4, tc = tid & 15;
  float acc[4][4];
  #pragma unroll
  for (int i = 0; i < 4; i++){ acc[i][0]=0.f; acc[i][1]=0.f; acc[i][2]=0.f; acc[i][3]=0.f; }

  for (int kt = 0; kt < 4; kt++){
    int k0 = kt * 32;
    {
      int t = tid >> 2, f8 = (tid & 3) * 8;
      int rt = b * 576 + 575 - (l0 + t);
      const float4* pf = (const float4*)&Yf[(size_t)(t0 + t) * 128 + k0 + f8];
      const float4* pb = (const float4*)&Yb[(size_t)rt * 128 + k0 + f8];
      float4 v0 = pf[0], v1 = pf[1], w0 = pb[0], w1 = pb[1];
      v0.x += w0.x; v0.y += w0.y; v0.z += w0.z; v0.w += w0.w;
      v1.x += w1.x; v1.y += w1.y; v1.z += w1.z; v1.w += w1.w;
      *(float4*)&sA[t * 36 + f8] = v0; *(float4*)&sA[t * 36 + f8 + 4] = v1;
    }
    {
      int c = tid >> 2, f8 = (tid & 3) * 8;
      const float* wr = &W[(size_t)c * 128 + k0 + f8];
      #pragma unroll
      for (int j = 0; j < 8; j++) sW[(f8 + j) * 68 + c] = wr[j];
    }
    __syncthreads();
    #pragma unroll
    for (int k4 = 0; k4 < 32; k4 += 4){
      float4 a[4];
      #pragma unroll
      for (int i = 0; i < 4; i++) a[i] = *(const float4*)&sA[(tr * 4 + i) * 36 + k4];
      #pragma unroll
      for (int kk = 0; kk < 4; kk++){
        float4 bv = *(const float4*)&sW[(k4 + kk) * 68 + tc * 4];
        #pragma unroll
        for (int i = 0; i < 4; i++){
          float av = ((const float*)&a[i])[kk];
          acc[i][0] += av * bv.x; acc[i][1] += av * bv.y;
          acc[i][2] += av * bv.z; acc[i][3] += av * bv.w;
        }
      }
    }
    __syncthreads();
  }
  #pragma unroll
  for (int j = 0; j < 4; j++)
    *(float4*)&sO[(tc * 4 + j) * 68 + tr * 4] = make_float4(acc[0][j], acc[1][j], acc[2][j], acc[3][j]);
  __syncthreads();
  {
    int c = tid >> 2, q = tid & 3;
    int ph = b / 5, pw = b % 5;
    size_t base = (size_t)g * 64 * MT + (size_t)c * MT;
    #pragma unroll
    for (int v = 0; v < 16; v++){
      int l = l0 + q * 16 + v;
      int nh = l / 24, nw = l % 24;
      size_t io = base + (nh * 5 + ph) * 120 + (nw * 5 + pw);
      imgB[io] = imgA[io] + sO[c * 68 + q * 16 + v];
    }
  }
}

// window: nb = imgB + (yf[l]+ybr[MT-1-l]).ow[c]; imgB = nb; imgA += nb  (no xM/yM)
__global__ __launch_bounds__(256) void k_outproj_win(const float* __restrict__ ys, const float* __restrict__ owb,
                                                     float* __restrict__ imgA, float* __restrict__ imgB, int s){
  int g = blockIdx.y;
  int i2 = g * 2 + s;
  int t0 = blockIdx.x * 64;
  const float* W = owb + (size_t)(i2 * 64) * 128;
  const float* Yf = ys + (size_t)(g * 2 + 0) * MT * 128;
  const float* Yb = ys + (size_t)(g * 2 + 1) * MT * 128;
  __shared__ __align__(16) float sA[64 * 36];
  __shared__ __align__(16) float sW[32 * 68];
  __shared__ __align__(16) float sO[64 * 68];
  int tid = threadIdx.x;
  int tr = tid >> 4, tc = tid & 15;
  float acc[4][4];
  #pragma unroll
  for (int i = 0; i < 4; i++){ acc[i][0]=0.f; acc[i][1]=0.f; acc[i][2]=0.f; acc[i][3]=0.f; }

  for (int kt = 0; kt < 4; kt++){
    int k0 = kt * 32;
    {
      int t = tid >> 2, f8 = (tid & 3) * 8;
      int l = t0 + t;
      const float4* pf = (const float4*)&Yf[(size_t)l * 128 + k0 + f8];
      const float4* pb = (const float4*)&Yb[(size_t)(MT - 1 - l) * 128 + k0 + f8];
      float4 v0 = pf[0], v1 = pf[1], w0 = pb[0], w1 = pb[1];
      v0.x += w0.x; v0.y += w0.y; v0.z += w0.z; v0.w += w0.w;
      v1.x += w1.x; v1.y += w1.y; v1.z += w1.z; v1.w += w1.w;
      *(float4*)&sA[t * 36 + f8] = v0; *(float4*)&sA[t * 36 + f8 + 4] = v1;
    }
    {
      int c = tid >> 2, f8 = (tid & 3) * 8;
      const float* wr = &W[(size_t)c * 128 + k0 + f8];
      #pragma unroll
      for (int j = 0; j < 8; j++) sW[(f8 + j) * 68 + c] = wr[j];
    }
    __syncthreads();
    #pragma unroll
    for (int k4 = 0; k4 < 32; k4 += 4){
      float4 a[4];
      #pragma unroll
      for (int i = 0; i < 4; i++) a[i] = *(const float4*)&sA[(tr * 4 + i) * 36 + k4];
      #pragma unroll
      for (int kk = 0; kk < 4; kk++){
        float4 bv = *(const float4*)&sW[(k4 + kk) * 68 + tc * 4];
        #pragma unroll
        for (int i = 0; i < 4; i++){
          float av = ((const float*)&a[i])[kk];
          acc[i][0] += av * bv.x; acc[i][1] += av * bv.y;
          acc[i][2] += av * bv.z; acc[i][3] += av * bv.w;
        }
      }
    }
    __syncthreads();
  }
  #pragma unroll
  for (int j = 0; j < 4; j++)
    *(float4*)&sO[(tc * 4 + j) * 68 + tr * 4] = make_float4(acc[0][j], acc[1][j], acc[2][j], acc[3][j]);
  __syncthreads();
  {
    int c = tid >> 2, q = tid & 3;
    size_t base = (size_t)g * 64 * MT + (size_t)c * MT + t0 + q * 16;
    float* pB = &imgB[base];
    float* pA = &imgA[base];
    const float* pS = &sO[c * 68 + q * 16];
    #pragma unroll
    for (int v = 0; v < 4; v++){
      float4 d = *(const float4*)&pS[v * 4];
      float4 bb = *(const float4*)&pB[v * 4];
      bb.x += d.x; bb.y += d.y; bb.z += d.z; bb.w += d.w;
      *(float4*)&pB[v * 4] = bb;
      float4 aa = *(const float4*)&pA[v * 4];
      aa.x += bb.x; aa.y += bb.y; aa.z += bb.z; aa.w += bb.w;
      *(float4*)&pA[v * 4] = aa;
    }
  }
}

// ---------------- GCN layer 1: t1 = sum_str ys_str . W1c[str]   (K=512 GEMM) ----------------
__global__ __launch_bounds__(256) void k_gcn1(const float* __restrict__ ys, const float* __restrict__ W1c,
                                              float* __restrict__ t1){
  int t0 = blockIdx.x * 64;
  __shared__ __align__(16) float sA[64 * 36];
  __shared__ __align__(16) float sB[32 * 132];
  int tid = threadIdx.x, tr = tid >> 4, tc = tid & 15;
  float acc[4][8];
  #pragma unroll
  for (int i = 0; i < 4; i++)
    #pragma unroll
    for (int j = 0; j < 8; j++) acc[i][j] = 0.f;

  for (int kt = 0; kt < 16; kt++){
    int str = kt >> 2, k0 = (kt & 3) * 32;
    const float* Y = ys + (size_t)str * MT * 128;
    {
      int t = tid >> 2, f8 = (tid & 3) * 8;
      const float4* p = (const float4*)&Y[(size_t)(t0 + t) * 128 + k0 + f8];
      *(float4*)&sA[t * 36 + f8] = p[0]; *(float4*)&sA[t * 36 + f8 + 4] = p[1];
    }
    {
      const float* Wc = W1c + ((size_t)str * 128 + k0) * 128;
      int kk = tid >> 3, f16 = (tid & 7) * 16;
      #pragma unroll
      for (int v = 0; v < 4; v++)
        *(float4*)&sB[kk * 132 + f16 + v * 4] = *(const float4*)&Wc[(size_t)kk * 128 + f16 + v * 4];
    }
    __syncthreads();
    #pragma unroll
    for (int k4 = 0; k4 < 32; k4 += 4){
      float4 a[4];
      #pragma unroll
      for (int i = 0; i < 4; i++) a[i] = *(const float4*)&sA[(tr * 4 + i) * 36 + k4];
      #pragma unroll
      for (int kk = 0; kk < 4; kk++){
        float4 b0 = *(const float4*)&sB[(k4 + kk) * 132 + tc * 8];
        float4 b1 = *(const float4*)&sB[(k4 + kk) * 132 + tc * 8 + 4];
        float bv[8] = {b0.x, b0.y, b0.z, b0.w, b1.x, b1.y, b1.z, b1.w};
        #pragma unroll
        for (int i = 0; i < 4; i++){
          float av = ((const float*)&a[i])[kk];
          #pragma unroll
          for (int j = 0; j < 8; j++) acc[i][j] += av * bv[j];
        }
      }
    }
    __syncthreads();
  }
  #pragma unroll
  for (int i = 0; i < 4; i++){
    size_t base = (size_t)(t0 + tr * 4 + i) * 128 + tc * 8;
    *(float4*)&t1[base]     = make_float4(acc[i][0], acc[i][1], acc[i][2], acc[i][3]);
    *(float4*)&t1[base + 4] = make_float4(acc[i][4], acc[i][5], acc[i][6], acc[i][7]);
  }
}

__global__ __launch_bounds__(128) void k_hub1(const float* __restrict__ t1, float* __restrict__ hubm){
  int f = threadIdx.x;
  float sum = 0.f;
  for (int hb = 0; hb < 450; hb++) sum += t1[(size_t)(hb * 32) * 128 + f];
  hubm[f] = sum * (1.f / 450.f);
}

// ---------------- GCN layer 2 (tiled): t2 = relu(t1/hub + b1) . W2^T ----------------
__global__ __launch_bounds__(256) void k_gcn2(const float* __restrict__ t1, const float* __restrict__ hubm,
                                              const float* __restrict__ b1, const float* __restrict__ W2,
                                              float* __restrict__ t2){
  int t0 = blockIdx.x * 64;
  __shared__ __align__(16) float sA[64 * 36];
  __shared__ __align__(16) float sW[32 * 68];
  int tid = threadIdx.x, tr = tid >> 4, tc = tid & 15;
  float acc[4][4];
  #pragma unroll
  for (int i = 0; i < 4; i++){ acc[i][0]=0.f; acc[i][1]=0.f; acc[i][2]=0.f; acc[i][3]=0.f; }

  for (int kt = 0; kt < 4; kt++){
    int k0 = kt * 32;
    {
      int t = tid >> 2, f8 = (tid & 3) * 8;
      int l = t0 + t;
      const float* src = ((l & 31) == 0) ? &hubm[k0 + f8] : &t1[(size_t)l * 128 + k0 + f8];
      #pragma unroll
      for (int j = 0; j < 8; j++)
        sA[t * 36 + f8 + j] = fmaxf(src[j] + b1[k0 + f8 + j], 0.f);
    }
    {
      int c = tid >> 2, f8 = (tid & 3) * 8;
      const float* wr = &W2[(size_t)c * 128 + k0 + f8];
      #pragma unroll
      for (int j = 0; j < 8; j++) sW[(f8 + j) * 68 + c] = wr[j];
    }
    __syncthreads();
    #pragma unroll
    for (int k4 = 0; k4 < 32; k4 += 4){
      float4 a[4];
      #pragma unroll
      for (int i = 0; i < 4; i++) a[i] = *(const float4*)&sA[(tr * 4 + i) * 36 + k4];
      #pragma unroll
      for (int kk = 0; kk < 4; kk++){
        float4 bv = *(const float4*)&sW[(k4 + kk) * 68 + tc * 4];
        #pragma unroll
        for (int i = 0; i < 4; i++){
          float av = ((const float*)&a[i])[kk];
          acc[i][0] += av * bv.x; acc[i][1] += av * bv.y;
          acc[i][2] += av * bv.z; acc[i][3] += av * bv.w;
        }
      }
    }
    __syncthreads();
  }
  #pragma unroll
  for (int i = 0; i < 4; i++)
    *(float4*)&t2[(size_t)(t0 + tr * 4 + i) * 64 + tc * 4] = make_float4(acc[i][0], acc[i][1], acc[i][2], acc[i][3]);
}

__global__ __launch_bounds__(64) void k_hub2(const float* __restrict__ t2, float* __restrict__ hubm2){
  int c = threadIdx.x;
  float sum = 0.f;
  for (int hb = 0; hb < 450; hb++) sum += t2[(size_t)(hb * 32) * 64 + c];
  hubm2[c] = sum * (1.f / 450.f);
}

__global__ __launch_bounds__(256) void k_final(const void* __restrict__ x, const float* __restrict__ t2,
                                               const float* __restrict__ hubm2, const float* __restrict__ b2,
                                               const float* __restrict__ imgA, void* __restrict__ out,
                                               const int* __restrict__ flag){
  int idx = blockIdx.x * 256 + threadIdx.x;
  int l = idx % MT, c = idx / MT;
  int fp32 = *flag;
  float gval = (((l & 31) == 0) ? hubm2[c] : t2[(size_t)l * 64 + c]) + b2[c];
  float a0 = imgA[idx];
  float a1 = imgA[(size_t)64 * MT + (size_t)c * MT + (l % 120) * 120 + l / 120];
  float xv = fp32 ? ((const float*)x)[idx] : b2f(((const u16*)x)[idx]);
  float val = gval + xv + a0 + a1;
  if (fp32) ((float*)out)[idx] = val;
  else      ((u16*)out)[idx] = f2b(val);
}

extern "C" void kernel_launch(void* const* d_in, const int* in_sizes, int n_in,
                              void* d_out, int out_size, void* d_ws, size_t ws_size,
                              hipStream_t stream){
  int I_X=0,I_PIW=1,I_PCW=2,I_PCB=3,I_PXP=4,I_PDTW=5,I_PDTB=6,I_PAL=7,I_PD=8,I_PLG=9,I_PLB=10,
      I_WIW=11,I_WCW=12,I_WCB=13,I_WXP=14,I_WDTW=15,I_WDTB=16,I_WAL=17,I_WD=18,I_WLG=19,I_WLB=20,
      I_POW=21,I_WOW=22,I_WOBW=23,I_G1=24,I_GB1=25,I_G2=26,I_GB2=27;
  if (n_in >= 28 && in_sizes[9] == 131072){
    I_WIW=9;I_WCW=10;I_WCB=11;I_WXP=12;I_WDTW=13;I_WDTB=14;I_WAL=15;I_WD=16;
    I_PLG=17;I_PLB=18;I_WLG=19;I_WLB=20;
  }
  if (n_in < 28 || in_sizes[I_PIW] != 131072 || out_size != 921600) return;

  float* Wp = (float*)d_ws;
  size_t off = 0;
  auto alloc = [&](size_t n){ size_t r = off; off += (n + 63) & ~(size_t)63; return r; };
  size_t oFlag=alloc(64);
  size_t oPIW=alloc(131072), oPCW=alloc(4096), oPCB=alloc(1024), oPXP=alloc(36864),
         oPDTW=alloc(4096), oPDTB=alloc(1024), oPA=alloc(16384), oPD=alloc(1024),
         oPLG=alloc(256), oPLB=alloc(256);
  size_t oWIW=alloc(131072), oWCW=alloc(4096), oWCB=alloc(1024), oWXP=alloc(36864),
         oWDTW=alloc(4096), oWDTB=alloc(1024), oWA=alloc(16384), oWD=alloc(1024),
         oWLG=alloc(256), oWLB=alloc(256);
  size_t oPOW=alloc(32768), oWOW=alloc(32768), oWOBW=alloc(32768),
         oG1=alloc(32768), oGB1=alloc(128), oG2=alloc(8192), oGB2=alloc(64);
  size_t oPIWT=alloc(131072), oWIWT=alloc(131072), oW1C=alloc(65536);
  size_t oImgA=alloc(2UL*64*MT), oImgB=alloc(2UL*64*MT), oXn=alloc(2UL*MT*64);
  size_t oRaw=alloc(4UL*MT*128);             // xh_raw; aliased as ys after conv
  size_t oZ=alloc(4UL*MT*128), oXhs=alloc(4UL*MT*128), oDelta=alloc(4UL*MT*128);
  size_t oBm=alloc(4UL*MT*16), oCm=alloc(4UL*MT*16);
  size_t oAc=alloc(4UL*WNC*2048), oBc=alloc(4UL*WNC*2048), oHin=alloc(4UL*WNC*2048);
  size_t oT1=alloc((size_t)MT*128), oHub1=alloc(128), oT2=alloc((size_t)MT*64), oHub2=alloc(64);
  if (ws_size < off * sizeof(float)) return;

  int* flag = (int*)(Wp + oFlag);
  k_detect<<<dim3(1), dim3(256), 0, stream>>>((const u16*)d_in[I_PAL], 16384, flag);

  PTab tb;
  int ti = 0;
  auto add = [&](int inIdx, size_t o, int n, int neg){
    tb.src[ti] = d_in[inIdx]; tb.dst[ti] = Wp + o; tb.n[ti] = n; tb.neg[ti] = neg; ti++;
  };
  add(I_PIW,oPIW,131072,0); add(I_PCW,oPCW,4096,0); add(I_PCB,oPCB,1024,0); add(I_PXP,oPXP,36864,0);
  add(I_PDTW,oPDTW,4096,0); add(I_PDTB,oPDTB,1024,0); add(I_PAL,oPA,16384,1); add(I_PD,oPD,1024,0);
  add(I_PLG,oPLG,256,0); add(I_PLB,oPLB,256,0);
  add(I_WIW,oWIW,131072,0); add(I_WCW,oWCW,4096,0); add(I_WCB,oWCB,1024,0); add(I_WXP,oWXP,36864,0);
  add(I_WDTW,oWDTW,4096,0); add(I_WDTB,oWDTB,1024,0); add(I_WAL,oWA,16384,1); add(I_WD,oWD,1024,0);
  add(I_WLG,oWLG,256,0); add(I_WLB,oWLB,256,0);
  add(I_POW,oPOW,32768,0); add(I_WOW,oWOW,32768,0); add(I_WOBW,oWOBW,32768,0);
  add(I_G1,oG1,32768,0); add(I_GB1,oGB1,128,0); add(I_G2,oG2,8192,0); add(I_GB2,oGB2,64,0);

  k_cvt<<<dim3(128, 27), dim3(256), 0, stream>>>(tb, flag);
  k_wtrans<<<dim3(64, 16), dim3(256), 0, stream>>>(Wp+oPIW, Wp+oWIW, Wp+oPIWT, Wp+oWIWT);
  k_gcn1w<<<dim3(64, 4), dim3(256), 0, stream>>>(Wp+oWOW, Wp+oWOBW, Wp+oG1, Wp+oW1C);
  k_cvt_x<<<dim3(3600), dim3(256), 0, stream>>>(d_in[I_X], Wp + oImgA, flag);

  float *imgA = Wp+oImgA, *imgB = Wp+oImgB, *xn = Wp+oXn, *raw = Wp+oRaw, *ys = Wp+oRaw,
        *zz = Wp+oZ, *xhs = Wp+oXhs, *delta = Wp+oDelta, *Bm = Wp+oBm, *Cm = Wp+oCm,
        *Ac = Wp+oAc, *Bc = Wp+oBc, *Hin = Wp+oHin;

  for (int s = 0; s < 2; s++){
    k_prep_xn<<<dim3(7200), dim3(256), 0, stream>>>(imgA, Wp+oPLG, Wp+oPLB, xn, s, 1);
    k_inproj <<<dim3(450, 4), dim3(256), 0, stream>>>(xn, Wp+oPIWT, raw, zz, s, 1);
    k_conv   <<<dim3(7200, 4), dim3(256), 0, stream>>>(raw, Wp+oPCW, Wp+oPCB, xhs, s, 1);
    k_xproj  <<<dim3(1800, 4), dim3(256), 0, stream>>>(xhs, Wp+oPXP, Wp+oPDTW, Wp+oPDTB, delta, Bm, Cm, s);
    k_scan_pixel<<<dim3(25, 4), dim3(256), 0, stream>>>(delta, xhs, Bm, Cm, zz, Wp+oPA, Wp+oPD, ys, s);
    k_outproj_pixel<<<dim3(225, 2), dim3(256), 0, stream>>>(ys, Wp+oPOW, imgA, imgB, s);

    k_prep_xn<<<dim3(7200), dim3(256), 0, stream>>>(imgB, Wp+oWLG, Wp+oWLB, xn, s, 0);
    k_inproj <<<dim3(450, 4), dim3(256), 0, stream>>>(xn, Wp+oWIWT, raw, zz, s, 0);
    k_conv   <<<dim3(7200, 4), dim3(256), 0, stream>>>(raw, Wp+oWCW, Wp+oWCB, xhs, s, 0);
    k_xproj  <<<dim3(1800, 4), dim3(256), 0, stream>>>(xhs, Wp+oWXP, Wp+oWDTW, Wp+oWDTB, delta, Bm, Cm, s);
    k_scan_win_p1<<<dim3(WNC, 4), dim3(256), 0, stream>>>(delta, xhs, Bm, Wp+oWA, Ac, Bc, s);
    k_scan_win_p2<<<dim3(32), dim3(256), 0, stream>>>(Ac, Bc, Hin);
    k_scan_win_p3<<<dim3(WNC, 4), dim3(256), 0, stream>>>(delta, xhs, Bm, Cm, zz, Wp+oWA, Wp+oWD, Hin, ys, s);
    k_outproj_win<<<dim3(225, 2), dim3(256), 0, stream>>>(ys, Wp+oWOW, imgA, imgB, s);
  }

  // GCN directly from ys (last window stage, s==1): t1 = sum_str ys_str . W1c[str]
  k_gcn1<<<dim3(225), dim3(256), 0, stream>>>(ys, Wp+oW1C, Wp+oT1);
  k_hub1<<<dim3(1), dim3(128), 0, stream>>>(Wp+oT1, Wp+oHub1);
  k_gcn2<<<dim3(225), dim3(256), 0, stream>>>(Wp+oT1, Wp+oHub1, Wp+oGB1, Wp+oG2, Wp+oT2);
  k_hub2<<<dim3(1), dim3(64), 0, stream>>>(Wp+oT2, Wp+oHub2);
  k_final<<<dim3(3600), dim3(256), 0, stream>>>(d_in[I_X], Wp+oT2, Wp+oHub2, Wp+oGB2, imgA, d_out, flag);
}

// Round 6
// 1641.636 us; speedup vs baseline: 3.3220x; 1.0876x over previous
//
#include <hip/hip_runtime.h>
#include <hip/hip_bf16.h>

#define MT 14400
#define WNC 150     // scan chunks per (gd)
#define WCL 96      // chunk length (WNC*WCL = MT; 576 = 6*96 so pixel seqs align)
#define PT 16       // LDS tile (timesteps)

typedef unsigned short u16;

__device__ __forceinline__ float b2f(u16 u){
  union { unsigned int i; float f; } v; v.i = ((unsigned int)u) << 16; return v.f;
}
__device__ __forceinline__ u16 f2b(float f){
  union { unsigned int i; float f; } v; v.f = f;
  unsigned int x = v.i;
  return (u16)((x + 0x7fffu + ((x >> 16) & 1u)) >> 16);
}
__device__ __forceinline__ float siluf(float x){ return x / (1.f + expf(-x)); }
__device__ __forceinline__ float softplusf(float x){ return (x > 20.f) ? x : log1pf(expf(x)); }

// ---------------- dtype detection ----------------
__global__ __launch_bounds__(256) void k_detect(const u16* __restrict__ a, int n, int* __restrict__ flag){
  __shared__ int found;
  if (threadIdx.x == 0) found = 0;
  __syncthreads();
  int f = 0;
  for (int i = threadIdx.x; i < n; i += 256){
    float v = b2f(a[i]);
    if (!(fabsf(v) <= 1e9f)) f = 1;
  }
  if (f) atomicOr(&found, 1);
  __syncthreads();
  if (threadIdx.x == 0) *flag = found;
}

// ---------------- param conversion ----------------
struct PTab {
  const void* src[27];
  float* dst[27];
  int n[27];
  int neg[27];
};

__global__ __launch_bounds__(256) void k_cvt(PTab tb, const int* __restrict__ flag){
  int id = blockIdx.y;
  int n = tb.n[id];
  int fp32 = *flag;
  float* d = tb.dst[id];
  int ng = tb.neg[id];
  for (int i = blockIdx.x * 256 + threadIdx.x; i < n; i += gridDim.x * 256){
    float v = fp32 ? ((const float*)tb.src[id])[i] : b2f(((const u16*)tb.src[id])[i]);
    if (ng) v = -expf(v) * 1.4426950408889634f;
    d[i] = v;
  }
}

// transpose in_w: W[mat][256][64] -> WT[mat][64][256]
__global__ __launch_bounds__(256) void k_wtrans(const float* __restrict__ Wpix, const float* __restrict__ Wwin,
                                                float* __restrict__ WTpix, float* __restrict__ WTwin){
  int mat = blockIdx.y;
  const float* src = (mat < 8) ? (Wpix + (size_t)mat * 16384) : (Wwin + (size_t)(mat - 8) * 16384);
  float* dst = (mat < 8) ? (WTpix + (size_t)mat * 16384) : (WTwin + (size_t)(mat - 8) * 16384);
  int idx = blockIdx.x * 256 + threadIdx.x;
  int e = idx >> 6, k = idx & 63;
  dst[k * 256 + e] = src[idx];
}

// combined GCN-1 weights
__global__ __launch_bounds__(256) void k_gcn1w(const float* __restrict__ ow, const float* __restrict__ obw,
                                               const float* __restrict__ G1, float* __restrict__ W1c){
  int str = blockIdx.y;
  int g = str >> 1, d = str & 1;
  int i2 = g * 2 + 1;
  const float* W = (d ? obw : ow) + (size_t)(i2 * 64) * 128;
  int idx = blockIdx.x * 256 + threadIdx.x;
  int kk = idx >> 7, f = idx & 127;
  float acc = 0.f;
  #pragma unroll 8
  for (int c = 0; c < 64; c++)
    acc += W[(size_t)c * 128 + kk] * G1[(size_t)f * 256 + str * 64 + c];
  W1c[((size_t)str * 128 + kk) * 128 + f] = acc;
}

__global__ __launch_bounds__(256) void k_cvt_x(const void* __restrict__ x, float* __restrict__ imgA,
                                               const int* __restrict__ flag){
  int idx = blockIdx.x * 256 + threadIdx.x;
  int l = idx % MT, c = idx / MT;
  float v = (*flag) ? ((const float*)x)[idx] : b2f(((const u16*)x)[idx]);
  imgA[idx] = v;
  imgA[(size_t)64 * MT + (size_t)c * MT + (l % 120) * 120 + l / 120] = v;
}

// ---------------- layernorm + token-order gather ----------------
__global__ __launch_bounds__(256) void k_prep_xn(const float* __restrict__ img, const float* __restrict__ lng,
                                                 const float* __restrict__ lnb, float* __restrict__ xn,
                                                 int s, int pixelMode){
  int tid = threadIdx.x;
  int q = blockIdx.x * 4 + (tid >> 6);
  int c = tid & 63;
  int g = q / MT, t = q % MT;
  int hw;
  if (pixelMode){
    int b = t / 576, l = t % 576;
    int ph = b / 5, pw = b % 5, nh = l / 24, nw = l % 24;
    hw = (nh * 5 + ph) * 120 + (nw * 5 + pw);
  } else hw = t;
  float v = img[(size_t)g * 64 * MT + (size_t)c * MT + hw];
  float sm = v;
  #pragma unroll
  for (int m = 32; m >= 1; m >>= 1) sm += __shfl_xor(sm, m);
  float mean = sm * (1.f / 64.f);
  float dv = v - mean;
  float s2 = dv * dv;
  #pragma unroll
  for (int m = 32; m >= 1; m >>= 1) s2 += __shfl_xor(s2, m);
  float var = s2 * (1.f / 64.f);
  int i2 = g * 2 + s;
  float o = dv * rsqrtf(var + 1e-5f) * lng[i2 * 64 + c] + lnb[i2 * 64 + c];
  xn[(size_t)g * MT * 64 + (size_t)t * 64 + c] = o;
}

// ---------------- in-projection: register-tiled GEMM ----------------
__global__ __launch_bounds__(256) void k_inproj(const float* __restrict__ xn, const float* __restrict__ WT,
                                                float* __restrict__ xh, float* __restrict__ z,
                                                int s, int pixelMode){
  int gd = blockIdx.y, g = gd >> 1, dir = gd & 1;
  int i2 = (g * 2 + s) * 2 + dir;
  int ttile = blockIdx.x >> 1, ntile = blockIdx.x & 1;
  int t0 = ttile * 64;
  const float* WTm = WT + (size_t)i2 * 16384 + ntile * 128;

  __shared__ __align__(16) float sA[64 * 68];
  __shared__ __align__(16) float sB[64 * 128];
  int tid = threadIdx.x;

  {
    int k0 = (tid & 15) * 4;
    #pragma unroll
    for (int it = 0; it < 4; it++){
      int t = (tid >> 4) + it * 16;
      int tq = t0 + t, src = tq;
      if (dir){
        if (pixelMode){ int b = tq / 576, l = tq % 576; src = b * 576 + 575 - l; }
        else src = MT - 1 - tq;
      }
      float4 v = *(const float4*)&xn[(size_t)g * MT * 64 + (size_t)src * 64 + k0];
      *(float4*)&sA[t * 68 + k0] = v;
    }
  }
  {
    #pragma unroll
    for (int it = 0; it < 8; it++){
      int idx = it * 256 + tid;
      int k = idx >> 5, e4 = (idx & 31) * 4;
      float4 v = *(const float4*)&WTm[(size_t)k * 256 + e4];
      *(float4*)&sB[k * 128 + e4] = v;
    }
  }
  __syncthreads();

  int tr = tid >> 4, tc = tid & 15;
  float acc[4][8];
  #pragma unroll
  for (int i = 0; i < 4; i++)
    #pragma unroll
    for (int j = 0; j < 8; j++) acc[i][j] = 0.f;

  for (int k0 = 0; k0 < 64; k0 += 4){
    float4 a4[4];
    #pragma unroll
    for (int i = 0; i < 4; i++) a4[i] = *(const float4*)&sA[(tr * 4 + i) * 68 + k0];
    #pragma unroll
    for (int kk = 0; kk < 4; kk++){
      float4 b0 = *(const float4*)&sB[(k0 + kk) * 128 + tc * 8];
      float4 b1 = *(const float4*)&sB[(k0 + kk) * 128 + tc * 8 + 4];
      float bv[8] = {b0.x, b0.y, b0.z, b0.w, b1.x, b1.y, b1.z, b1.w};
      #pragma unroll
      for (int i = 0; i < 4; i++){
        const float* ap = (const float*)&a4[i];
        float av = ap[kk];
        #pragma unroll
        for (int j = 0; j < 8; j++) acc[i][j] += av * bv[j];
      }
    }
  }

  float* dst = ntile ? z : xh;
  #pragma unroll
  for (int i = 0; i < 4; i++){
    int t_out = t0 + tr * 4 + i;
    size_t base = (size_t)gd * MT * 128 + (size_t)t_out * 128 + tc * 8;
    *(float4*)&dst[base]     = make_float4(acc[i][0], acc[i][1], acc[i][2], acc[i][3]);
    *(float4*)&dst[base + 4] = make_float4(acc[i][4], acc[i][5], acc[i][6], acc[i][7]);
  }
}

// ---------------- causal depthwise conv (K=4) + SiLU ----------------
__global__ __launch_bounds__(256) void k_conv(const float* __restrict__ raw, const float* __restrict__ cw,
                                              const float* __restrict__ cb, float* __restrict__ xhs,
                                              int s, int pixelMode){
  int gd = blockIdx.y, g = gd >> 1, dir = gd & 1;
  int i2 = (g * 2 + s) * 2 + dir;
  int idx = blockIdx.x * 256 + threadIdx.x;
  int t = idx >> 7, ch = idx & 127;
  int SL = pixelMode ? 576 : MT;
  int pos = t % SL;
  const float* src = raw + (size_t)gd * MT * 128;
  const float* wrow = cw + (size_t)(i2 * 128 + ch) * 4;
  float acc = cb[i2 * 128 + ch];
  #pragma unroll
  for (int i = 0; i < 4; i++){
    int d = 3 - i;
    if (pos >= d) acc += src[(size_t)(t - d) * 128 + ch] * wrow[i];
  }
  xhs[(size_t)gd * MT * 128 + idx] = siluf(acc);
}

// ---------------- x-projection -> delta(softplus), B, C ----------------
__global__ __launch_bounds__(256) void k_xproj(const float* __restrict__ xhs, const float* __restrict__ xpb,
                                               const float* __restrict__ dtw, const float* __restrict__ dtb,
                                               float* __restrict__ delta, float* __restrict__ Bm,
                                               float* __restrict__ Cm, int s){
  int gd = blockIdx.y, g = gd >> 1, dir = gd & 1;
  int i2 = (g * 2 + s) * 2 + dir;
  const float* XP = xpb + (size_t)i2 * 36 * 128;
  const float* DW = dtw + (size_t)i2 * 128 * 4;
  const float* DB = dtb + (size_t)i2 * 128;
  int t0 = blockIdx.x * 8;
  __shared__ __align__(16) float xv[8][128];
  __shared__ float dbl[8][36];
  int tid = threadIdx.x;
  const float* src = xhs + (size_t)gd * MT * 128 + (size_t)t0 * 128;
  for (int idx = tid; idx < 8 * 128; idx += 256) xv[idx >> 7][idx & 127] = src[idx];
  __syncthreads();
  for (int o = tid; o < 8 * 36; o += 256){
    int tok = o / 36, e = o - tok * 36;
    const float4* a4 = (const float4*)xv[tok];
    const float4* w4 = (const float4*)(XP + (size_t)e * 128);
    float acc = 0.f;
    #pragma unroll 8
    for (int k = 0; k < 32; k++){
      float4 a = a4[k], w = w4[k];
      acc += a.x*w.x + a.y*w.y + a.z*w.z + a.w*w.w;
    }
    dbl[tok][e] = acc;
  }
  __syncthreads();
  for (int o = tid; o < 8 * 128; o += 256){
    int tok = o >> 7, d = o & 127;
    float v = DB[d];
    #pragma unroll
    for (int r = 0; r < 4; r++) v += dbl[tok][r] * DW[d * 4 + r];
    delta[(size_t)gd * MT * 128 + (size_t)(t0 + tok) * 128 + d] = softplusf(v);
  }
  for (int o = tid; o < 8 * 32; o += 256){
    int tok = o >> 5, n = o & 31;
    int t = t0 + tok;
    if (n < 16) Bm[(size_t)gd * MT * 16 + (size_t)t * 16 + n] = dbl[tok][4 + n];
    else        Cm[(size_t)gd * MT * 16 + (size_t)t * 16 + (n - 16)] = dbl[tok][20 + (n - 16)];
  }
}

// ---------------- unified 3-phase chunked scan (pixel & window) ----------------
// p1: per-chunk (prod a, carry b). grid (WNC, 4). single-buffer LDS + reg prefetch.
__global__ __launch_bounds__(256) void k_scan_p1(const float* __restrict__ delta, const float* __restrict__ xhs,
                                                 const float* __restrict__ Bm, const float* __restrict__ A2b,
                                                 float* __restrict__ Acar, float* __restrict__ Bcar, int s){
  int gd = blockIdx.y, g = gd >> 1, dir = gd & 1;
  int i2 = (g * 2 + s) * 2 + dir;
  int chunk = blockIdx.x;
  int tid = threadIdx.x, ch = tid >> 1, nb = (tid & 1) * 8;
  float A2[8], ap[8], bc[8];
  #pragma unroll
  for (int j = 0; j < 8; j++){
    A2[j] = A2b[((size_t)i2 * 128 + ch) * 16 + nb + j];
    ap[j] = 1.f; bc[j] = 0.f;
  }
  size_t so = (size_t)gd * MT * 128 + (size_t)chunk * WCL * 128;
  size_t bo = (size_t)gd * MT * 16  + (size_t)chunk * WCL * 16;
  __shared__ __align__(16) float sd[PT * 128];
  __shared__ __align__(16) float su[PT * 128];
  __shared__ __align__(16) float sb[PT * 16];
  float4 rd0, rd1, ru0, ru1; float rb;
  {
    const float4* d4 = (const float4*)(delta + so);
    const float4* u4 = (const float4*)(xhs + so);
    rd0 = d4[2 * tid]; rd1 = d4[2 * tid + 1];
    ru0 = u4[2 * tid]; ru1 = u4[2 * tid + 1];
    rb = (Bm + bo)[tid];
  }
  const int NT = WCL / PT;
  for (int tile = 0; tile < NT; tile++){
    __syncthreads();
    ((float4*)sd)[2 * tid] = rd0; ((float4*)sd)[2 * tid + 1] = rd1;
    ((float4*)su)[2 * tid] = ru0; ((float4*)su)[2 * tid + 1] = ru1;
    sb[tid] = rb;
    __syncthreads();
    if (tile + 1 < NT){
      const float4* d4 = (const float4*)(delta + so + (size_t)(tile + 1) * PT * 128);
      const float4* u4 = (const float4*)(xhs + so + (size_t)(tile + 1) * PT * 128);
      rd0 = d4[2 * tid]; rd1 = d4[2 * tid + 1];
      ru0 = u4[2 * tid]; ru1 = u4[2 * tid + 1];
      rb = (Bm + bo + (size_t)(tile + 1) * PT * 16)[tid];
    }
    #pragma unroll
    for (int t = 0; t < PT; t++){
      float dt = sd[t * 128 + ch];
      float u  = su[t * 128 + ch];
      float du = dt * u;
      #pragma unroll
      for (int j = 0; j < 8; j++){
        float e = exp2f(dt * A2[j]);
        bc[j] = bc[j] * e + du * sb[t * 16 + nb + j];
        ap[j] *= e;
      }
    }
  }
  size_t o = ((size_t)gd * WNC + chunk) * 2048 + (size_t)ch * 16 + nb;
  float4* A4 = (float4*)(Acar + o);
  float4* B4 = (float4*)(Bcar + o);
  A4[0] = make_float4(ap[0], ap[1], ap[2], ap[3]);
  A4[1] = make_float4(ap[4], ap[5], ap[6], ap[7]);
  B4[0] = make_float4(bc[0], bc[1], bc[2], bc[3]);
  B4[1] = make_float4(bc[4], bc[5], bc[6], bc[7]);
}

// p2: compose carries serially; carry resets every resetPeriod chunks (6=pixel seqs, 150=window)
__global__ __launch_bounds__(256) void k_scan_p2(const float* __restrict__ Acar, const float* __restrict__ Bcar,
                                                 float* __restrict__ Hin, int resetPeriod){
  int flat = blockIdx.x * 256 + threadIdx.x;
  int cs = flat & 2047, gd = flat >> 11;
  float h = 0.f;
  int cnt = 0;
  for (int c = 0; c < WNC; c++){
    if (cnt == resetPeriod) { h = 0.f; cnt = 0; }
    cnt++;
    size_t o = ((size_t)gd * WNC + c) * 2048 + cs;
    Hin[o] = h;
    h = Acar[o] * h + Bcar[o];
  }
}

// p3: replay with correct h_in; fused C-contraction, D, silu(z) gating
__global__ __launch_bounds__(256) void k_scan_p3(const float* __restrict__ delta, const float* __restrict__ xhs,
                                                 const float* __restrict__ Bm, const float* __restrict__ Cm,
                                                 const float* __restrict__ zz, const float* __restrict__ A2b,
                                                 const float* __restrict__ Db, const float* __restrict__ Hin,
                                                 float* __restrict__ ys, int s){
  int gd = blockIdx.y, g = gd >> 1, dir = gd & 1;
  int i2 = (g * 2 + s) * 2 + dir;
  int chunk = blockIdx.x;
  int tid = threadIdx.x, ch = tid >> 1, nb = (tid & 1) * 8;
  float A2[8], h[8];
  size_t ho = ((size_t)gd * WNC + chunk) * 2048 + (size_t)ch * 16 + nb;
  {
    const float4* H4 = (const float4*)(Hin + ho);
    float4 h0 = H4[0], h1 = H4[1];
    h[0]=h0.x; h[1]=h0.y; h[2]=h0.z; h[3]=h0.w;
    h[4]=h1.x; h[5]=h1.y; h[6]=h1.z; h[7]=h1.w;
  }
  #pragma unroll
  for (int j = 0; j < 8; j++) A2[j] = A2b[((size_t)i2 * 128 + ch) * 16 + nb + j];
  float Dv = Db[(size_t)i2 * 128 + ch];
  size_t so = (size_t)gd * MT * 128 + (size_t)chunk * WCL * 128;
  size_t bo = (size_t)gd * MT * 16  + (size_t)chunk * WCL * 16;
  __shared__ __align__(16) float sd[PT * 128];
  __shared__ __align__(16) float su[PT * 128];
  __shared__ __align__(16) float sb[PT * 16];
  __shared__ __align__(16) float sc[PT * 16];
  __shared__ __align__(16) float sy[PT * 128];
  float4 rd0, rd1, ru0, ru1; float rb, rc;
  {
    const float4* d4 = (const float4*)(delta + so);
    const float4* u4 = (const float4*)(xhs + so);
    rd0 = d4[2 * tid]; rd1 = d4[2 * tid + 1];
    ru0 = u4[2 * tid]; ru1 = u4[2 * tid + 1];
    rb = (Bm + bo)[tid]; rc = (Cm + bo)[tid];
  }
  const int NT = WCL / PT;
  for (int tile = 0; tile < NT; tile++){
    __syncthreads();
    ((float4*)sd)[2 * tid] = rd0; ((float4*)sd)[2 * tid + 1] = rd1;
    ((float4*)su)[2 * tid] = ru0; ((float4*)su)[2 * tid + 1] = ru1;
    sb[tid] = rb; sc[tid] = rc;
    __syncthreads();
    if (tile + 1 < NT){
      const float4* d4 = (const float4*)(delta + so + (size_t)(tile + 1) * PT * 128);
      const float4* u4 = (const float4*)(xhs + so + (size_t)(tile + 1) * PT * 128);
      rd0 = d4[2 * tid]; rd1 = d4[2 * tid + 1];
      ru0 = u4[2 * tid]; ru1 = u4[2 * tid + 1];
      rb = (Bm + bo + (size_t)(tile + 1) * PT * 16)[tid];
      rc = (Cm + bo + (size_t)(tile + 1) * PT * 16)[tid];
    }
    #pragma unroll
    for (int t = 0; t < PT; t++){
      float dt = sd[t * 128 + ch];
      float u  = su[t * 128 + ch];
      float du = dt * u;
      float acc = 0.f;
      #pragma unroll
      for (int j = 0; j < 8; j++){
        float e = exp2f(dt * A2[j]);
        h[j] = h[j] * e + du * sb[t * 16 + nb + j];
        acc += h[j] * sc[t * 16 + nb + j];
      }
      acc += __shfl_xor(acc, 1);
      if (!(tid & 1)) sy[t * 128 + ch] = acc + u * Dv;
    }
    __syncthreads();
    {
      const float4* z4 = (const float4*)(zz + so + (size_t)tile * PT * 128);
      float4* y4 = (float4*)(ys + so + (size_t)tile * PT * 128);
      #pragma unroll
      for (int i = 0; i < 2; i++){
        int f = 2 * tid + i;
        float4 yv = ((float4*)sy)[f];
        float4 zv = z4[f];
        yv.x *= siluf(zv.x); yv.y *= siluf(zv.y); yv.z *= siluf(zv.z); yv.w *= siluf(zv.w);
        y4[f] = yv;
      }
    }
    __syncthreads();
  }
}

// ---------------- out-projection (tiled GEMM) + residual ----------------
__global__ __launch_bounds__(256) void k_outproj_pixel(const float* __restrict__ ys, const float* __restrict__ owb,
                                                       const float* __restrict__ imgA, float* __restrict__ imgB, int s){
  int g = blockIdx.y;
  int i2 = g * 2 + s;
  int tile = blockIdx.x;
  int t0 = tile * 64;
  int b = tile / 9, l0 = (tile % 9) * 64;
  const float* W = owb + (size_t)(i2 * 64) * 128;
  const float* Yf = ys + (size_t)(g * 2 + 0) * MT * 128;
  const float* Yb = ys + (size_t)(g * 2 + 1) * MT * 128;
  __shared__ __align__(16) float sA[64 * 36];
  __shared__ __align__(16) float sW[32 * 68];
  __shared__ __align__(16) float sO[64 * 68];
  int tid = threadIdx.x;
  int tr = tid >> 4, tc = tid & 15;
  float acc[4][4];
  #pragma unroll
  for (int i = 0; i < 4; i++){ acc[i][0]=0.f; acc[i][1]=0.f; acc[i][2]=0.f; acc[i][3]=0.f; }

  for (int kt = 0; kt < 4; kt++){
    int k0 = kt * 32;
    {
      int t = tid >> 2, f8 = (tid & 3) * 8;
      int rt = b * 576 + 575 - (l0 + t);
      const float4* pf = (const float4*)&Yf[(size_t)(t0 + t) * 128 + k0 + f8];
      const float4* pb = (const float4*)&Yb[(size_t)rt * 128 + k0 + f8];
      float4 v0 = pf[0], v1 = pf[1], w0 = pb[0], w1 = pb[1];
      v0.x += w0.x; v0.y += w0.y; v0.z += w0.z; v0.w += w0.w;
      v1.x += w1.x; v1.y += w1.y; v1.z += w1.z; v1.w += w1.w;
      *(float4*)&sA[t * 36 + f8] = v0; *(float4*)&sA[t * 36 + f8 + 4] = v1;
    }
    {
      int c = tid >> 2, f8 = (tid & 3) * 8;
      const float* wr = &W[(size_t)c * 128 + k0 + f8];
      #pragma unroll
      for (int j = 0; j < 8; j++) sW[(f8 + j) * 68 + c] = wr[j];
    }
    __syncthreads();
    #pragma unroll
    for (int k4 = 0; k4 < 32; k4 += 4){
      float4 a[4];
      #pragma unroll
      for (int i = 0; i < 4; i++) a[i] = *(const float4*)&sA[(tr * 4 + i) * 36 + k4];
      #pragma unroll
      for (int kk = 0; kk < 4; kk++){
        float4 bv = *(const float4*)&sW[(k4 + kk) * 68 + tc * 4];
        #pragma unroll
        for (int i = 0; i < 4; i++){
          float av = ((const float*)&a[i])[kk];
          acc[i][0] += av * bv.x; acc[i][1] += av * bv.y;
          acc[i][2] += av * bv.z; acc[i][3] += av * bv.w;
        }
      }
    }
    __syncthreads();
  }
  #pragma unroll
  for (int j = 0; j < 4; j++)
    *(float4*)&sO[(tc * 4 + j) * 68 + tr * 4] = make_float4(acc[0][j], acc[1][j], acc[2][j], acc[3][j]);
  __syncthreads();
  {
    int c = tid >> 2, q = tid & 3;
    int ph = b / 5, pw = b % 5;
    size_t base = (size_t)g * 64 * MT + (size_t)c * MT;
    #pragma unroll
    for (int v = 0; v < 16; v++){
      int l = l0 + q * 16 + v;
      int nh = l / 24, nw = l % 24;
      size_t io = base + (nh * 5 + ph) * 120 + (nw * 5 + pw);
      imgB[io] = imgA[io] + sO[c * 68 + q * 16 + v];
    }
  }
}

__global__ __launch_bounds__(256) void k_outproj_win(const float* __restrict__ ys, const float* __restrict__ owb,
                                                     float* __restrict__ imgA, float* __restrict__ imgB, int s){
  int g = blockIdx.y;
  int i2 = g * 2 + s;
  int t0 = blockIdx.x * 64;
  const float* W = owb + (size_t)(i2 * 64) * 128;
  const float* Yf = ys + (size_t)(g * 2 + 0) * MT * 128;
  const float* Yb = ys + (size_t)(g * 2 + 1) * MT * 128;
  __shared__ __align__(16) float sA[64 * 36];
  __shared__ __align__(16) float sW[32 * 68];
  __shared__ __align__(16) float sO[64 * 68];
  int tid = threadIdx.x;
  int tr = tid >> 4, tc = tid & 15;
  float acc[4][4];
  #pragma unroll
  for (int i = 0; i < 4; i++){ acc[i][0]=0.f; acc[i][1]=0.f; acc[i][2]=0.f; acc[i][3]=0.f; }

  for (int kt = 0; kt < 4; kt++){
    int k0 = kt * 32;
    {
      int t = tid >> 2, f8 = (tid & 3) * 8;
      int l = t0 + t;
      const float4* pf = (const float4*)&Yf[(size_t)l * 128 + k0 + f8];
      const float4* pb = (const float4*)&Yb[(size_t)(MT - 1 - l) * 128 + k0 + f8];
      float4 v0 = pf[0], v1 = pf[1], w0 = pb[0], w1 = pb[1];
      v0.x += w0.x; v0.y += w0.y; v0.z += w0.z; v0.w += w0.w;
      v1.x += w1.x; v1.y += w1.y; v1.z += w1.z; v1.w += w1.w;
      *(float4*)&sA[t * 36 + f8] = v0; *(float4*)&sA[t * 36 + f8 + 4] = v1;
    }
    {
      int c = tid >> 2, f8 = (tid & 3) * 8;
      const float* wr = &W[(size_t)c * 128 + k0 + f8];
      #pragma unroll
      for (int j = 0; j < 8; j++) sW[(f8 + j) * 68 + c] = wr[j];
    }
    __syncthreads();
    #pragma unroll
    for (int k4 = 0; k4 < 32; k4 += 4){
      float4 a[4];
      #pragma unroll
      for (int i = 0; i < 4; i++) a[i] = *(const float4*)&sA[(tr * 4 + i) * 36 + k4];
      #pragma unroll
      for (int kk = 0; kk < 4; kk++){
        float4 bv = *(const float4*)&sW[(k4 + kk) * 68 + tc * 4];
        #pragma unroll
        for (int i = 0; i < 4; i++){
          float av = ((const float*)&a[i])[kk];
          acc[i][0] += av * bv.x; acc[i][1] += av * bv.y;
          acc[i][2] += av * bv.z; acc[i][3] += av * bv.w;
        }
      }
    }
    __syncthreads();
  }
  #pragma unroll
  for (int j = 0; j < 4; j++)
    *(float4*)&sO[(tc * 4 + j) * 68 + tr * 4] = make_float4(acc[0][j], acc[1][j], acc[2][j], acc[3][j]);
  __syncthreads();
  {
    int c = tid >> 2, q = tid & 3;
    size_t base = (size_t)g * 64 * MT + (size_t)c * MT + t0 + q * 16;
    float* pB = &imgB[base];
    float* pA = &imgA[base];
    const float* pS = &sO[c * 68 + q * 16];
    #pragma unroll
    for (int v = 0; v < 4; v++){
      float4 d = *(const float4*)&pS[v * 4];
      float4 bb = *(const float4*)&pB[v * 4];
      bb.x += d.x; bb.y += d.y; bb.z += d.z; bb.w += d.w;
      *(float4*)&pB[v * 4] = bb;
      float4 aa = *(const float4*)&pA[v * 4];
      aa.x += bb.x; aa.y += bb.y; aa.z += bb.z; aa.w += bb.w;
      *(float4*)&pA[v * 4] = aa;
    }
  }
}

// ---------------- GCN layer 1 (K=512 GEMM over 4 ys streams) ----------------
__global__ __launch_bounds__(256) void k_gcn1(const float* __restrict__ ys, const float* __restrict__ W1c,
                                              float* __restrict__ t1){
  int t0 = blockIdx.x * 64;
  __shared__ __align__(16) float sA[64 * 36];
  __shared__ __align__(16) float sB[32 * 132];
  int tid = threadIdx.x, tr = tid >> 4, tc = tid & 15;
  float acc[4][8];
  #pragma unroll
  for (int i = 0; i < 4; i++)
    #pragma unroll
    for (int j = 0; j < 8; j++) acc[i][j] = 0.f;

  for (int kt = 0; kt < 16; kt++){
    int str = kt >> 2, k0 = (kt & 3) * 32;
    const float* Y = ys + (size_t)str * MT * 128;
    {
      int t = tid >> 2, f8 = (tid & 3) * 8;
      const float4* p = (const float4*)&Y[(size_t)(t0 + t) * 128 + k0 + f8];
      *(float4*)&sA[t * 36 + f8] = p[0]; *(float4*)&sA[t * 36 + f8 + 4] = p[1];
    }
    {
      const float* Wc = W1c + ((size_t)str * 128 + k0) * 128;
      int kk = tid >> 3, f16 = (tid & 7) * 16;
      #pragma unroll
      for (int v = 0; v < 4; v++)
        *(float4*)&sB[kk * 132 + f16 + v * 4] = *(const float4*)&Wc[(size_t)kk * 128 + f16 + v * 4];
    }
    __syncthreads();
    #pragma unroll
    for (int k4 = 0; k4 < 32; k4 += 4){
      float4 a[4];
      #pragma unroll
      for (int i = 0; i < 4; i++) a[i] = *(const float4*)&sA[(tr * 4 + i) * 36 + k4];
      #pragma unroll
      for (int kk = 0; kk < 4; kk++){
        float4 b0 = *(const float4*)&sB[(k4 + kk) * 132 + tc * 8];
        float4 b1 = *(const float4*)&sB[(k4 + kk) * 132 + tc * 8 + 4];
        float bv[8] = {b0.x, b0.y, b0.z, b0.w, b1.x, b1.y, b1.z, b1.w};
        #pragma unroll
        for (int i = 0; i < 4; i++){
          float av = ((const float*)&a[i])[kk];
          #pragma unroll
          for (int j = 0; j < 8; j++) acc[i][j] += av * bv[j];
        }
      }
    }
    __syncthreads();
  }
  #pragma unroll
  for (int i = 0; i < 4; i++){
    size_t base = (size_t)(t0 + tr * 4 + i) * 128 + tc * 8;
    *(float4*)&t1[base]     = make_float4(acc[i][0], acc[i][1], acc[i][2], acc[i][3]);
    *(float4*)&t1[base + 4] = make_float4(acc[i][4], acc[i][5], acc[i][6], acc[i][7]);
  }
}

__global__ __launch_bounds__(128) void k_hub1(const float* __restrict__ t1, float* __restrict__ hubm){
  int f = threadIdx.x;
  float sum = 0.f;
  for (int hb = 0; hb < 450; hb++) sum += t1[(size_t)(hb * 32) * 128 + f];
  hubm[f] = sum * (1.f / 450.f);
}

__global__ __launch_bounds__(256) void k_gcn2(const float* __restrict__ t1, const float* __restrict__ hubm,
                                              const float* __restrict__ b1, const float* __restrict__ W2,
                                              float* __restrict__ t2){
  int t0 = blockIdx.x * 64;
  __shared__ __align__(16) float sA[64 * 36];
  __shared__ __align__(16) float sW[32 * 68];
  int tid = threadIdx.x, tr = tid >> 4, tc = tid & 15;
  float acc[4][4];
  #pragma unroll
  for (int i = 0; i < 4; i++){ acc[i][0]=0.f; acc[i][1]=0.f; acc[i][2]=0.f; acc[i][3]=0.f; }

  for (int kt = 0; kt < 4; kt++){
    int k0 = kt * 32;
    {
      int t = tid >> 2, f8 = (tid & 3) * 8;
      int l = t0 + t;
      const float* src = ((l & 31) == 0) ? &hubm[k0 + f8] : &t1[(size_t)l * 128 + k0 + f8];
      #pragma unroll
      for (int j = 0; j < 8; j++)
        sA[t * 36 + f8 + j] = fmaxf(src[j] + b1[k0 + f8 + j], 0.f);
    }
    {
      int c = tid >> 2, f8 = (tid & 3) * 8;
      const float* wr = &W2[(size_t)c * 128 + k0 + f8];
      #pragma unroll
      for (int j = 0; j < 8; j++) sW[(f8 + j) * 68 + c] = wr[j];
    }
    __syncthreads();
    #pragma unroll
    for (int k4 = 0; k4 < 32; k4 += 4){
      float4 a[4];
      #pragma unroll
      for (int i = 0; i < 4; i++) a[i] = *(const float4*)&sA[(tr * 4 + i) * 36 + k4];
      #pragma unroll
      for (int kk = 0; kk < 4; kk++){
        float4 bv = *(const float4*)&sW[(k4 + kk) * 68 + tc * 4];
        #pragma unroll
        for (int i = 0; i < 4; i++){
          float av = ((const float*)&a[i])[kk];
          acc[i][0] += av * bv.x; acc[i][1] += av * bv.y;
          acc[i][2] += av * bv.z; acc[i][3] += av * bv.w;
        }
      }
    }
    __syncthreads();
  }
  #pragma unroll
  for (int i = 0; i < 4; i++)
    *(float4*)&t2[(size_t)(t0 + tr * 4 + i) * 64 + tc * 4] = make_float4(acc[i][0], acc[i][1], acc[i][2], acc[i][3]);
}

__global__ __launch_bounds__(64) void k_hub2(const float* __restrict__ t2, float* __restrict__ hubm2){
  int c = threadIdx.x;
  float sum = 0.f;
  for (int hb = 0; hb < 450; hb++) sum += t2[(size_t)(hb * 32) * 64 + c];
  hubm2[c] = sum * (1.f / 450.f);
}

__global__ __launch_bounds__(256) void k_final(const void* __restrict__ x, const float* __restrict__ t2,
                                               const float* __restrict__ hubm2, const float* __restrict__ b2,
                                               const float* __restrict__ imgA, void* __restrict__ out,
                                               const int* __restrict__ flag){
  int idx = blockIdx.x * 256 + threadIdx.x;
  int l = idx % MT, c = idx / MT;
  int fp32 = *flag;
  float gval = (((l & 31) == 0) ? hubm2[c] : t2[(size_t)l * 64 + c]) + b2[c];
  float a0 = imgA[idx];
  float a1 = imgA[(size_t)64 * MT + (size_t)c * MT + (l % 120) * 120 + l / 120];
  float xv = fp32 ? ((const float*)x)[idx] : b2f(((const u16*)x)[idx]);
  float val = gval + xv + a0 + a1;
  if (fp32) ((float*)out)[idx] = val;
  else      ((u16*)out)[idx] = f2b(val);
}

extern "C" void kernel_launch(void* const* d_in, const int* in_sizes, int n_in,
                              void* d_out, int out_size, void* d_ws, size_t ws_size,
                              hipStream_t stream){
  int I_X=0,I_PIW=1,I_PCW=2,I_PCB=3,I_PXP=4,I_PDTW=5,I_PDTB=6,I_PAL=7,I_PD=8,I_PLG=9,I_PLB=10,
      I_WIW=11,I_WCW=12,I_WCB=13,I_WXP=14,I_WDTW=15,I_WDTB=16,I_WAL=17,I_WD=18,I_WLG=19,I_WLB=20,
      I_POW=21,I_WOW=22,I_WOBW=23,I_G1=24,I_GB1=25,I_G2=26,I_GB2=27;
  if (n_in >= 28 && in_sizes[9] == 131072){
    I_WIW=9;I_WCW=10;I_WCB=11;I_WXP=12;I_WDTW=13;I_WDTB=14;I_WAL=15;I_WD=16;
    I_PLG=17;I_PLB=18;I_WLG=19;I_WLB=20;
  }
  if (n_in < 28 || in_sizes[I_PIW] != 131072 || out_size != 921600) return;

  float* Wp = (float*)d_ws;
  size_t off = 0;
  auto alloc = [&](size_t n){ size_t r = off; off += (n + 63) & ~(size_t)63; return r; };
  size_t oFlag=alloc(64);
  size_t oPIW=alloc(131072), oPCW=alloc(4096), oPCB=alloc(1024), oPXP=alloc(36864),
         oPDTW=alloc(4096), oPDTB=alloc(1024), oPA=alloc(16384), oPD=alloc(1024),
         oPLG=alloc(256), oPLB=alloc(256);
  size_t oWIW=alloc(131072), oWCW=alloc(4096), oWCB=alloc(1024), oWXP=alloc(36864),
         oWDTW=alloc(4096), oWDTB=alloc(1024), oWA=alloc(16384), oWD=alloc(1024),
         oWLG=alloc(256), oWLB=alloc(256);
  size_t oPOW=alloc(32768), oWOW=alloc(32768), oWOBW=alloc(32768),
         oG1=alloc(32768), oGB1=alloc(128), oG2=alloc(8192), oGB2=alloc(64);
  size_t oPIWT=alloc(131072), oWIWT=alloc(131072), oW1C=alloc(65536);
  size_t oImgA=alloc(2UL*64*MT), oImgB=alloc(2UL*64*MT), oXn=alloc(2UL*MT*64);
  size_t oRaw=alloc(4UL*MT*128);             // xh_raw; aliased as ys after conv
  size_t oZ=alloc(4UL*MT*128), oXhs=alloc(4UL*MT*128), oDelta=alloc(4UL*MT*128);
  size_t oBm=alloc(4UL*MT*16), oCm=alloc(4UL*MT*16);
  size_t oAc=alloc(4UL*WNC*2048), oBc=alloc(4UL*WNC*2048), oHin=alloc(4UL*WNC*2048);
  size_t oT1=alloc((size_t)MT*128), oHub1=alloc(128), oT2=alloc((size_t)MT*64), oHub2=alloc(64);
  if (ws_size < off * sizeof(float)) return;

  int* flag = (int*)(Wp + oFlag);
  k_detect<<<dim3(1), dim3(256), 0, stream>>>((const u16*)d_in[I_PAL], 16384, flag);

  PTab tb;
  int ti = 0;
  auto add = [&](int inIdx, size_t o, int n, int neg){
    tb.src[ti] = d_in[inIdx]; tb.dst[ti] = Wp + o; tb.n[ti] = n; tb.neg[ti] = neg; ti++;
  };
  add(I_PIW,oPIW,131072,0); add(I_PCW,oPCW,4096,0); add(I_PCB,oPCB,1024,0); add(I_PXP,oPXP,36864,0);
  add(I_PDTW,oPDTW,4096,0); add(I_PDTB,oPDTB,1024,0); add(I_PAL,oPA,16384,1); add(I_PD,oPD,1024,0);
  add(I_PLG,oPLG,256,0); add(I_PLB,oPLB,256,0);
  add(I_WIW,oWIW,131072,0); add(I_WCW,oWCW,4096,0); add(I_WCB,oWCB,1024,0); add(I_WXP,oWXP,36864,0);
  add(I_WDTW,oWDTW,4096,0); add(I_WDTB,oWDTB,1024,0); add(I_WAL,oWA,16384,1); add(I_WD,oWD,1024,0);
  add(I_WLG,oWLG,256,0); add(I_WLB,oWLB,256,0);
  add(I_POW,oPOW,32768,0); add(I_WOW,oWOW,32768,0); add(I_WOBW,oWOBW,32768,0);
  add(I_G1,oG1,32768,0); add(I_GB1,oGB1,128,0); add(I_G2,oG2,8192,0); add(I_GB2,oGB2,64,0);

  k_cvt<<<dim3(128, 27), dim3(256), 0, stream>>>(tb, flag);
  k_wtrans<<<dim3(64, 16), dim3(256), 0, stream>>>(Wp+oPIW, Wp+oWIW, Wp+oPIWT, Wp+oWIWT);
  k_gcn1w<<<dim3(64, 4), dim3(256), 0, stream>>>(Wp+oWOW, Wp+oWOBW, Wp+oG1, Wp+oW1C);
  k_cvt_x<<<dim3(3600), dim3(256), 0, stream>>>(d_in[I_X], Wp + oImgA, flag);

  float *imgA = Wp+oImgA, *imgB = Wp+oImgB, *xn = Wp+oXn, *raw = Wp+oRaw, *ys = Wp+oRaw,
        *zz = Wp+oZ, *xhs = Wp+oXhs, *delta = Wp+oDelta, *Bm = Wp+oBm, *Cm = Wp+oCm,
        *Ac = Wp+oAc, *Bc = Wp+oBc, *Hin = Wp+oHin;

  for (int s = 0; s < 2; s++){
    // ---- pixel stage ----
    k_prep_xn<<<dim3(7200), dim3(256), 0, stream>>>(imgA, Wp+oPLG, Wp+oPLB, xn, s, 1);
    k_inproj <<<dim3(450, 4), dim3(256), 0, stream>>>(xn, Wp+oPIWT, raw, zz, s, 1);
    k_conv   <<<dim3(7200, 4), dim3(256), 0, stream>>>(raw, Wp+oPCW, Wp+oPCB, xhs, s, 1);
    k_xproj  <<<dim3(1800, 4), dim3(256), 0, stream>>>(xhs, Wp+oPXP, Wp+oPDTW, Wp+oPDTB, delta, Bm, Cm, s);
    k_scan_p1<<<dim3(WNC, 4), dim3(256), 0, stream>>>(delta, xhs, Bm, Wp+oPA, Ac, Bc, s);
    k_scan_p2<<<dim3(32), dim3(256), 0, stream>>>(Ac, Bc, Hin, 6);
    k_scan_p3<<<dim3(WNC, 4), dim3(256), 0, stream>>>(delta, xhs, Bm, Cm, zz, Wp+oPA, Wp+oPD, Hin, ys, s);
    k_outproj_pixel<<<dim3(225, 2), dim3(256), 0, stream>>>(ys, Wp+oPOW, imgA, imgB, s);

    // ---- window stage ----
    k_prep_xn<<<dim3(7200), dim3(256), 0, stream>>>(imgB, Wp+oWLG, Wp+oWLB, xn, s, 0);
    k_inproj <<<dim3(450, 4), dim3(256), 0, stream>>>(xn, Wp+oWIWT, raw, zz, s, 0);
    k_conv   <<<dim3(7200, 4), dim3(256), 0, stream>>>(raw, Wp+oWCW, Wp+oWCB, xhs, s, 0);
    k_xproj  <<<dim3(1800, 4), dim3(256), 0, stream>>>(xhs, Wp+oWXP, Wp+oWDTW, Wp+oWDTB, delta, Bm, Cm, s);
    k_scan_p1<<<dim3(WNC, 4), dim3(256), 0, stream>>>(delta, xhs, Bm, Wp+oWA, Ac, Bc, s);
    k_scan_p2<<<dim3(32), dim3(256), 0, stream>>>(Ac, Bc, Hin, WNC);
    k_scan_p3<<<dim3(WNC, 4), dim3(256), 0, stream>>>(delta, xhs, Bm, Cm, zz, Wp+oWA, Wp+oWD, Hin, ys, s);
    k_outproj_win<<<dim3(225, 2), dim3(256), 0, stream>>>(ys, Wp+oWOW, imgA, imgB, s);
  }

  k_gcn1<<<dim3(225), dim3(256), 0, stream>>>(ys, Wp+oW1C, Wp+oT1);
  k_hub1<<<dim3(1), dim3(128), 0, stream>>>(Wp+oT1, Wp+oHub1);
  k_gcn2<<<dim3(225), dim3(256), 0, stream>>>(Wp+oT1, Wp+oHub1, Wp+oGB1, Wp+oG2, Wp+oT2);
  k_hub2<<<dim3(1), dim3(64), 0, stream>>>(Wp+oT2, Wp+oHub2);
  k_final<<<dim3(3600), dim3(256), 0, stream>>>(d_in[I_X], Wp+oT2, Wp+oHub2, Wp+oGB2, imgA, d_out, flag);
}

// Round 7
// 1352.995 us; speedup vs baseline: 4.0307x; 1.2133x over previous
//
#include <hip/hip_runtime.h>
#include <hip/hip_bf16.h>

#define MT 14400
#define WNC 150     // scan chunks per (gd)
#define WCL 96      // chunk length (WNC*WCL = MT; 576 = 6*96 so pixel seqs align)
#define PT 16       // LDS tile (timesteps)

typedef unsigned short u16;

__device__ __forceinline__ float b2f(u16 u){
  union { unsigned int i; float f; } v; v.i = ((unsigned int)u) << 16; return v.f;
}
__device__ __forceinline__ u16 f2b(float f){
  union { unsigned int i; float f; } v; v.f = f;
  unsigned int x = v.i;
  return (u16)((x + 0x7fffu + ((x >> 16) & 1u)) >> 16);
}
__device__ __forceinline__ float siluf(float x){ return x / (1.f + expf(-x)); }
__device__ __forceinline__ float softplusf(float x){ return (x > 20.f) ? x : log1pf(expf(x)); }

// ---------------- dtype detection ----------------
__global__ __launch_bounds__(256) void k_detect(const u16* __restrict__ a, int n, int* __restrict__ flag){
  __shared__ int found;
  if (threadIdx.x == 0) found = 0;
  __syncthreads();
  int f = 0;
  for (int i = threadIdx.x; i < n; i += 256){
    float v = b2f(a[i]);
    if (!(fabsf(v) <= 1e9f)) f = 1;
  }
  if (f) atomicOr(&found, 1);
  __syncthreads();
  if (threadIdx.x == 0) *flag = found;
}

// ---------------- param conversion ----------------
struct PTab {
  const void* src[27];
  float* dst[27];
  int n[27];
  int neg[27];
};

__global__ __launch_bounds__(256) void k_cvt(PTab tb, const int* __restrict__ flag){
  int id = blockIdx.y;
  int n = tb.n[id];
  int fp32 = *flag;
  float* d = tb.dst[id];
  int ng = tb.neg[id];
  for (int i = blockIdx.x * 256 + threadIdx.x; i < n; i += gridDim.x * 256){
    float v = fp32 ? ((const float*)tb.src[id])[i] : b2f(((const u16*)tb.src[id])[i]);
    if (ng) v = -expf(v) * 1.4426950408889634f;
    d[i] = v;
  }
}

// transpose in_w: W[mat][256][64] -> WT[mat][64][256]
__global__ __launch_bounds__(256) void k_wtrans(const float* __restrict__ Wpix, const float* __restrict__ Wwin,
                                                float* __restrict__ WTpix, float* __restrict__ WTwin){
  int mat = blockIdx.y;
  const float* src = (mat < 8) ? (Wpix + (size_t)mat * 16384) : (Wwin + (size_t)(mat - 8) * 16384);
  float* dst = (mat < 8) ? (WTpix + (size_t)mat * 16384) : (WTwin + (size_t)(mat - 8) * 16384);
  int idx = blockIdx.x * 256 + threadIdx.x;
  int e = idx >> 6, k = idx & 63;
  dst[k * 256 + e] = src[idx];
}

// combined GCN-1 weights
__global__ __launch_bounds__(256) void k_gcn1w(const float* __restrict__ ow, const float* __restrict__ obw,
                                               const float* __restrict__ G1, float* __restrict__ W1c){
  int str = blockIdx.y;
  int g = str >> 1, d = str & 1;
  int i2 = g * 2 + 1;
  const float* W = (d ? obw : ow) + (size_t)(i2 * 64) * 128;
  int idx = blockIdx.x * 256 + threadIdx.x;
  int kk = idx >> 7, f = idx & 127;
  float acc = 0.f;
  #pragma unroll 8
  for (int c = 0; c < 64; c++)
    acc += W[(size_t)c * 128 + kk] * G1[(size_t)f * 256 + str * 64 + c];
  W1c[((size_t)str * 128 + kk) * 128 + f] = acc;
}

__global__ __launch_bounds__(256) void k_cvt_x(const void* __restrict__ x, float* __restrict__ imgA,
                                               const int* __restrict__ flag){
  int idx = blockIdx.x * 256 + threadIdx.x;
  int l = idx % MT, c = idx / MT;
  float v = (*flag) ? ((const float*)x)[idx] : b2f(((const u16*)x)[idx]);
  imgA[idx] = v;
  imgA[(size_t)64 * MT + (size_t)c * MT + (l % 120) * 120 + l / 120] = v;
}

// ---------------- layernorm + token-order gather ----------------
__global__ __launch_bounds__(256) void k_prep_xn(const float* __restrict__ img, const float* __restrict__ lng,
                                                 const float* __restrict__ lnb, float* __restrict__ xn,
                                                 int s, int pixelMode){
  int tid = threadIdx.x;
  int q = blockIdx.x * 4 + (tid >> 6);
  int c = tid & 63;
  int g = q / MT, t = q % MT;
  int hw;
  if (pixelMode){
    int b = t / 576, l = t % 576;
    int ph = b / 5, pw = b % 5, nh = l / 24, nw = l % 24;
    hw = (nh * 5 + ph) * 120 + (nw * 5 + pw);
  } else hw = t;
  float v = img[(size_t)g * 64 * MT + (size_t)c * MT + hw];
  float sm = v;
  #pragma unroll
  for (int m = 32; m >= 1; m >>= 1) sm += __shfl_xor(sm, m);
  float mean = sm * (1.f / 64.f);
  float dv = v - mean;
  float s2 = dv * dv;
  #pragma unroll
  for (int m = 32; m >= 1; m >>= 1) s2 += __shfl_xor(s2, m);
  float var = s2 * (1.f / 64.f);
  int i2 = g * 2 + s;
  float o = dv * rsqrtf(var + 1e-5f) * lng[i2 * 64 + c] + lnb[i2 * 64 + c];
  xn[(size_t)g * MT * 64 + (size_t)t * 64 + c] = o;
}

// ---------------- in-projection: register-tiled GEMM ----------------
__global__ __launch_bounds__(256) void k_inproj(const float* __restrict__ xn, const float* __restrict__ WT,
                                                float* __restrict__ xh, float* __restrict__ z,
                                                int s, int pixelMode){
  int gd = blockIdx.y, g = gd >> 1, dir = gd & 1;
  int i2 = (g * 2 + s) * 2 + dir;
  int ttile = blockIdx.x >> 1, ntile = blockIdx.x & 1;
  int t0 = ttile * 64;
  const float* WTm = WT + (size_t)i2 * 16384 + ntile * 128;

  __shared__ __align__(16) float sA[64 * 68];
  __shared__ __align__(16) float sB[64 * 128];
  int tid = threadIdx.x;

  {
    int k0 = (tid & 15) * 4;
    #pragma unroll
    for (int it = 0; it < 4; it++){
      int t = (tid >> 4) + it * 16;
      int tq = t0 + t, src = tq;
      if (dir){
        if (pixelMode){ int b = tq / 576, l = tq % 576; src = b * 576 + 575 - l; }
        else src = MT - 1 - tq;
      }
      float4 v = *(const float4*)&xn[(size_t)g * MT * 64 + (size_t)src * 64 + k0];
      *(float4*)&sA[t * 68 + k0] = v;
    }
  }
  {
    #pragma unroll
    for (int it = 0; it < 8; it++){
      int idx = it * 256 + tid;
      int k = idx >> 5, e4 = (idx & 31) * 4;
      float4 v = *(const float4*)&WTm[(size_t)k * 256 + e4];
      *(float4*)&sB[k * 128 + e4] = v;
    }
  }
  __syncthreads();

  int tr = tid >> 4, tc = tid & 15;
  float acc[4][8];
  #pragma unroll
  for (int i = 0; i < 4; i++)
    #pragma unroll
    for (int j = 0; j < 8; j++) acc[i][j] = 0.f;

  for (int k0 = 0; k0 < 64; k0 += 4){
    float4 a4[4];
    #pragma unroll
    for (int i = 0; i < 4; i++) a4[i] = *(const float4*)&sA[(tr * 4 + i) * 68 + k0];
    #pragma unroll
    for (int kk = 0; kk < 4; kk++){
      float4 b0 = *(const float4*)&sB[(k0 + kk) * 128 + tc * 8];
      float4 b1 = *(const float4*)&sB[(k0 + kk) * 128 + tc * 8 + 4];
      float bv[8] = {b0.x, b0.y, b0.z, b0.w, b1.x, b1.y, b1.z, b1.w};
      #pragma unroll
      for (int i = 0; i < 4; i++){
        const float* ap = (const float*)&a4[i];
        float av = ap[kk];
        #pragma unroll
        for (int j = 0; j < 8; j++) acc[i][j] += av * bv[j];
      }
    }
  }

  float* dst = ntile ? z : xh;
  #pragma unroll
  for (int i = 0; i < 4; i++){
    int t_out = t0 + tr * 4 + i;
    size_t base = (size_t)gd * MT * 128 + (size_t)t_out * 128 + tc * 8;
    *(float4*)&dst[base]     = make_float4(acc[i][0], acc[i][1], acc[i][2], acc[i][3]);
    *(float4*)&dst[base + 4] = make_float4(acc[i][4], acc[i][5], acc[i][6], acc[i][7]);
  }
}

// ---------------- causal depthwise conv (K=4) + SiLU ----------------
__global__ __launch_bounds__(256) void k_conv(const float* __restrict__ raw, const float* __restrict__ cw,
                                              const float* __restrict__ cb, float* __restrict__ xhs,
                                              int s, int pixelMode){
  int gd = blockIdx.y, g = gd >> 1, dir = gd & 1;
  int i2 = (g * 2 + s) * 2 + dir;
  int idx = blockIdx.x * 256 + threadIdx.x;
  int t = idx >> 7, ch = idx & 127;
  int SL = pixelMode ? 576 : MT;
  int pos = t % SL;
  const float* src = raw + (size_t)gd * MT * 128;
  const float* wrow = cw + (size_t)(i2 * 128 + ch) * 4;
  float acc = cb[i2 * 128 + ch];
  #pragma unroll
  for (int i = 0; i < 4; i++){
    int d = 3 - i;
    if (pos >= d) acc += src[(size_t)(t - d) * 128 + ch] * wrow[i];
  }
  xhs[(size_t)gd * MT * 128 + idx] = siluf(acc);
}

// ---------------- x-projection: tiled GEMM (64 tok x 48 outs, K=128) + fused delta/B/C ----------------
// dbl = xhs . XP^T (XP rows are out-major already); delta = softplus(dbl[0:4].DW^T + DB)
__global__ __launch_bounds__(256) void k_xproj(const float* __restrict__ xhs, const float* __restrict__ xpb,
                                               const float* __restrict__ dtw, const float* __restrict__ dtb,
                                               float* __restrict__ delta, float* __restrict__ Bm,
                                               float* __restrict__ Cm, int s){
  int gd = blockIdx.y, g = gd >> 1, dir = gd & 1;
  int i2 = (g * 2 + s) * 2 + dir;
  const float* XP = xpb + (size_t)i2 * 36 * 128;
  const float* DW = dtw + (size_t)i2 * 128 * 4;
  const float* DB = dtb + (size_t)i2 * 128;
  int t0 = blockIdx.x * 64;
  size_t gb = (size_t)gd * MT * 128;
  size_t gb16 = (size_t)gd * MT * 16;

  __shared__ __align__(16) float sX[64 * 132];   // aliased as sDbl[64*52] after GEMM
  __shared__ __align__(16) float sW[48 * 132];
  float* sDbl = sX;
  int tid = threadIdx.x;

  // stage X: 64 tokens x 128 k
  #pragma unroll
  for (int it = 0; it < 8; it++){
    int idx = it * 256 + tid;
    int tok = idx >> 5, k4 = (idx & 31) * 4;
    *(float4*)&sX[tok * 132 + k4] = *(const float4*)&xhs[gb + (size_t)(t0 + tok) * 128 + k4];
  }
  // stage W: 48 outs (36 real, 12 zero) x 128 k
  for (int idx = tid; idx < 48 * 32; idx += 256){
    int out = idx >> 5, k4 = (idx & 31) * 4;
    float4 v = (out < 36) ? *(const float4*)&XP[(size_t)out * 128 + k4]
                          : make_float4(0.f, 0.f, 0.f, 0.f);
    *(float4*)&sW[out * 132 + k4] = v;
  }
  __syncthreads();

  int tr = tid >> 4, tc = tid & 15;   // tokG (4 tok), outG (3 outs)
  float acc[4][3];
  #pragma unroll
  for (int i = 0; i < 4; i++){ acc[i][0]=0.f; acc[i][1]=0.f; acc[i][2]=0.f; }

  for (int k0 = 0; k0 < 128; k0 += 4){
    float4 a4[4], bw[3];
    #pragma unroll
    for (int i = 0; i < 4; i++) a4[i] = *(const float4*)&sX[(tr * 4 + i) * 132 + k0];
    #pragma unroll
    for (int j = 0; j < 3; j++) bw[j] = *(const float4*)&sW[(tc * 3 + j) * 132 + k0];
    #pragma unroll
    for (int kk = 0; kk < 4; kk++){
      #pragma unroll
      for (int i = 0; i < 4; i++){
        float av = ((const float*)&a4[i])[kk];
        #pragma unroll
        for (int j = 0; j < 3; j++) acc[i][j] += av * ((const float*)&bw[j])[kk];
      }
    }
  }
  __syncthreads();   // done reading sX; reuse as sDbl

  #pragma unroll
  for (int i = 0; i < 4; i++){
    #pragma unroll
    for (int j = 0; j < 3; j++){
      int out = tc * 3 + j;
      if (out < 36) sDbl[(tr * 4 + i) * 52 + out] = acc[i][j];
    }
  }
  __syncthreads();

  // delta: each thread owns one d (tid&127), 32 tokens
  {
    int d = tid & 127, half = tid >> 7;
    float4 dw = *(const float4*)&DW[(size_t)d * 4];
    float db = DB[d];
    #pragma unroll
    for (int it = 0; it < 32; it++){
      int t = it * 2 + half;
      const float* row = &sDbl[t * 52];
      float v = db + row[0] * dw.x + row[1] * dw.y + row[2] * dw.z + row[3] * dw.w;
      delta[gb + (size_t)(t0 + t) * 128 + d] = softplusf(v);
    }
  }
  // B / C
  #pragma unroll
  for (int it = 0; it < 8; it++){
    int flat = it * 256 + tid;
    int t = flat >> 5, n = flat & 31;
    float v = sDbl[t * 52 + 4 + n];
    if (n < 16) Bm[gb16 + (size_t)(t0 + t) * 16 + n] = v;
    else        Cm[gb16 + (size_t)(t0 + t) * 16 + (n - 16)] = v;
  }
}

// ---------------- unified 3-phase chunked scan (pixel & window) ----------------
__global__ __launch_bounds__(256) void k_scan_p1(const float* __restrict__ delta, const float* __restrict__ xhs,
                                                 const float* __restrict__ Bm, const float* __restrict__ A2b,
                                                 float* __restrict__ Acar, float* __restrict__ Bcar, int s){
  int gd = blockIdx.y, g = gd >> 1, dir = gd & 1;
  int i2 = (g * 2 + s) * 2 + dir;
  int chunk = blockIdx.x;
  int tid = threadIdx.x, ch = tid >> 1, nb = (tid & 1) * 8;
  float A2[8], ap[8], bc[8];
  #pragma unroll
  for (int j = 0; j < 8; j++){
    A2[j] = A2b[((size_t)i2 * 128 + ch) * 16 + nb + j];
    ap[j] = 1.f; bc[j] = 0.f;
  }
  size_t so = (size_t)gd * MT * 128 + (size_t)chunk * WCL * 128;
  size_t bo = (size_t)gd * MT * 16  + (size_t)chunk * WCL * 16;
  __shared__ __align__(16) float sd[PT * 128];
  __shared__ __align__(16) float su[PT * 128];
  __shared__ __align__(16) float sb[PT * 16];
  float4 rd0, rd1, ru0, ru1; float rb;
  {
    const float4* d4 = (const float4*)(delta + so);
    const float4* u4 = (const float4*)(xhs + so);
    rd0 = d4[2 * tid]; rd1 = d4[2 * tid + 1];
    ru0 = u4[2 * tid]; ru1 = u4[2 * tid + 1];
    rb = (Bm + bo)[tid];
  }
  const int NT = WCL / PT;
  for (int tile = 0; tile < NT; tile++){
    __syncthreads();
    ((float4*)sd)[2 * tid] = rd0; ((float4*)sd)[2 * tid + 1] = rd1;
    ((float4*)su)[2 * tid] = ru0; ((float4*)su)[2 * tid + 1] = ru1;
    sb[tid] = rb;
    __syncthreads();
    if (tile + 1 < NT){
      const float4* d4 = (const float4*)(delta + so + (size_t)(tile + 1) * PT * 128);
      const float4* u4 = (const float4*)(xhs + so + (size_t)(tile + 1) * PT * 128);
      rd0 = d4[2 * tid]; rd1 = d4[2 * tid + 1];
      ru0 = u4[2 * tid]; ru1 = u4[2 * tid + 1];
      rb = (Bm + bo + (size_t)(tile + 1) * PT * 16)[tid];
    }
    #pragma unroll
    for (int t = 0; t < PT; t++){
      float dt = sd[t * 128 + ch];
      float u  = su[t * 128 + ch];
      float du = dt * u;
      #pragma unroll
      for (int j = 0; j < 8; j++){
        float e = exp2f(dt * A2[j]);
        bc[j] = bc[j] * e + du * sb[t * 16 + nb + j];
        ap[j] *= e;
      }
    }
  }
  size_t o = ((size_t)gd * WNC + chunk) * 2048 + (size_t)ch * 16 + nb;
  float4* A4 = (float4*)(Acar + o);
  float4* B4 = (float4*)(Bcar + o);
  A4[0] = make_float4(ap[0], ap[1], ap[2], ap[3]);
  A4[1] = make_float4(ap[4], ap[5], ap[6], ap[7]);
  B4[0] = make_float4(bc[0], bc[1], bc[2], bc[3]);
  B4[1] = make_float4(bc[4], bc[5], bc[6], bc[7]);
}

__global__ __launch_bounds__(256) void k_scan_p2(const float* __restrict__ Acar, const float* __restrict__ Bcar,
                                                 float* __restrict__ Hin, int resetPeriod){
  int flat = blockIdx.x * 256 + threadIdx.x;
  int cs = flat & 2047, gd = flat >> 11;
  float h = 0.f;
  int cnt = 0;
  for (int c = 0; c < WNC; c++){
    if (cnt == resetPeriod) { h = 0.f; cnt = 0; }
    cnt++;
    size_t o = ((size_t)gd * WNC + c) * 2048 + cs;
    Hin[o] = h;
    h = Acar[o] * h + Bcar[o];
  }
}

__global__ __launch_bounds__(256) void k_scan_p3(const float* __restrict__ delta, const float* __restrict__ xhs,
                                                 const float* __restrict__ Bm, const float* __restrict__ Cm,
                                                 const float* __restrict__ zz, const float* __restrict__ A2b,
                                                 const float* __restrict__ Db, const float* __restrict__ Hin,
                                                 float* __restrict__ ys, int s){
  int gd = blockIdx.y, g = gd >> 1, dir = gd & 1;
  int i2 = (g * 2 + s) * 2 + dir;
  int chunk = blockIdx.x;
  int tid = threadIdx.x, ch = tid >> 1, nb = (tid & 1) * 8;
  float A2[8], h[8];
  size_t ho = ((size_t)gd * WNC + chunk) * 2048 + (size_t)ch * 16 + nb;
  {
    const float4* H4 = (const float4*)(Hin + ho);
    float4 h0 = H4[0], h1 = H4[1];
    h[0]=h0.x; h[1]=h0.y; h[2]=h0.z; h[3]=h0.w;
    h[4]=h1.x; h[5]=h1.y; h[6]=h1.z; h[7]=h1.w;
  }
  #pragma unroll
  for (int j = 0; j < 8; j++) A2[j] = A2b[((size_t)i2 * 128 + ch) * 16 + nb + j];
  float Dv = Db[(size_t)i2 * 128 + ch];
  size_t so = (size_t)gd * MT * 128 + (size_t)chunk * WCL * 128;
  size_t bo = (size_t)gd * MT * 16  + (size_t)chunk * WCL * 16;
  __shared__ __align__(16) float sd[PT * 128];
  __shared__ __align__(16) float su[PT * 128];
  __shared__ __align__(16) float sb[PT * 16];
  __shared__ __align__(16) float sc[PT * 16];
  __shared__ __align__(16) float sy[PT * 128];
  float4 rd0, rd1, ru0, ru1; float rb, rc;
  {
    const float4* d4 = (const float4*)(delta + so);
    const float4* u4 = (const float4*)(xhs + so);
    rd0 = d4[2 * tid]; rd1 = d4[2 * tid + 1];
    ru0 = u4[2 * tid]; ru1 = u4[2 * tid + 1];
    rb = (Bm + bo)[tid]; rc = (Cm + bo)[tid];
  }
  const int NT = WCL / PT;
  for (int tile = 0; tile < NT; tile++){
    __syncthreads();
    ((float4*)sd)[2 * tid] = rd0; ((float4*)sd)[2 * tid + 1] = rd1;
    ((float4*)su)[2 * tid] = ru0; ((float4*)su)[2 * tid + 1] = ru1;
    sb[tid] = rb; sc[tid] = rc;
    __syncthreads();
    if (tile + 1 < NT){
      const float4* d4 = (const float4*)(delta + so + (size_t)(tile + 1) * PT * 128);
      const float4* u4 = (const float4*)(xhs + so + (size_t)(tile + 1) * PT * 128);
      rd0 = d4[2 * tid]; rd1 = d4[2 * tid + 1];
      ru0 = u4[2 * tid]; ru1 = u4[2 * tid + 1];
      rb = (Bm + bo + (size_t)(tile + 1) * PT * 16)[tid];
      rc = (Cm + bo + (size_t)(tile + 1) * PT * 16)[tid];
    }
    #pragma unroll
    for (int t = 0; t < PT; t++){
      float dt = sd[t * 128 + ch];
      float u  = su[t * 128 + ch];
      float du = dt * u;
      float acc = 0.f;
      #pragma unroll
      for (int j = 0; j < 8; j++){
        float e = exp2f(dt * A2[j]);
        h[j] = h[j] * e + du * sb[t * 16 + nb + j];
        acc += h[j] * sc[t * 16 + nb + j];
      }
      acc += __shfl_xor(acc, 1);
      if (!(tid & 1)) sy[t * 128 + ch] = acc + u * Dv;
    }
    __syncthreads();
    {
      const float4* z4 = (const float4*)(zz + so + (size_t)tile * PT * 128);
      float4* y4 = (float4*)(ys + so + (size_t)tile * PT * 128);
      #pragma unroll
      for (int i = 0; i < 2; i++){
        int f = 2 * tid + i;
        float4 yv = ((float4*)sy)[f];
        float4 zv = z4[f];
        yv.x *= siluf(zv.x); yv.y *= siluf(zv.y); yv.z *= siluf(zv.z); yv.w *= siluf(zv.w);
        y4[f] = yv;
      }
    }
    __syncthreads();
  }
}

// ---------------- out-projection (tiled GEMM) + residual ----------------
__global__ __launch_bounds__(256) void k_outproj_pixel(const float* __restrict__ ys, const float* __restrict__ owb,
                                                       const float* __restrict__ imgA, float* __restrict__ imgB, int s){
  int g = blockIdx.y;
  int i2 = g * 2 + s;
  int tile = blockIdx.x;
  int t0 = tile * 64;
  int b = tile / 9, l0 = (tile % 9) * 64;
  const float* W = owb + (size_t)(i2 * 64) * 128;
  const float* Yf = ys + (size_t)(g * 2 + 0) * MT * 128;
  const float* Yb = ys + (size_t)(g * 2 + 1) * MT * 128;
  __shared__ __align__(16) float sA[64 * 36];
  __shared__ __align__(16) float sW[32 * 68];
  __shared__ __align__(16) float sO[64 * 68];
  int tid = threadIdx.x;
  int tr = tid >> 4, tc = tid & 15;
  float acc[4][4];
  #pragma unroll
  for (int i = 0; i < 4; i++){ acc[i][0]=0.f; acc[i][1]=0.f; acc[i][2]=0.f; acc[i][3]=0.f; }

  for (int kt = 0; kt < 4; kt++){
    int k0 = kt * 32;
    {
      int t = tid >> 2, f8 = (tid & 3) * 8;
      int rt = b * 576 + 575 - (l0 + t);
      const float4* pf = (const float4*)&Yf[(size_t)(t0 + t) * 128 + k0 + f8];
      const float4* pb = (const float4*)&Yb[(size_t)rt * 128 + k0 + f8];
      float4 v0 = pf[0], v1 = pf[1], w0 = pb[0], w1 = pb[1];
      v0.x += w0.x; v0.y += w0.y; v0.z += w0.z; v0.w += w0.w;
      v1.x += w1.x; v1.y += w1.y; v1.z += w1.z; v1.w += w1.w;
      *(float4*)&sA[t * 36 + f8] = v0; *(float4*)&sA[t * 36 + f8 + 4] = v1;
    }
    {
      int c = tid >> 2, f8 = (tid & 3) * 8;
      const float* wr = &W[(size_t)c * 128 + k0 + f8];
      #pragma unroll
      for (int j = 0; j < 8; j++) sW[(f8 + j) * 68 + c] = wr[j];
    }
    __syncthreads();
    #pragma unroll
    for (int k4 = 0; k4 < 32; k4 += 4){
      float4 a[4];
      #pragma unroll
      for (int i = 0; i < 4; i++) a[i] = *(const float4*)&sA[(tr * 4 + i) * 36 + k4];
      #pragma unroll
      for (int kk = 0; kk < 4; kk++){
        float4 bv = *(const float4*)&sW[(k4 + kk) * 68 + tc * 4];
        #pragma unroll
        for (int i = 0; i < 4; i++){
          float av = ((const float*)&a[i])[kk];
          acc[i][0] += av * bv.x; acc[i][1] += av * bv.y;
          acc[i][2] += av * bv.z; acc[i][3] += av * bv.w;
        }
      }
    }
    __syncthreads();
  }
  #pragma unroll
  for (int j = 0; j < 4; j++)
    *(float4*)&sO[(tc * 4 + j) * 68 + tr * 4] = make_float4(acc[0][j], acc[1][j], acc[2][j], acc[3][j]);
  __syncthreads();
  {
    int c = tid >> 2, q = tid & 3;
    int ph = b / 5, pw = b % 5;
    size_t base = (size_t)g * 64 * MT + (size_t)c * MT;
    #pragma unroll
    for (int v = 0; v < 16; v++){
      int l = l0 + q * 16 + v;
      int nh = l / 24, nw = l % 24;
      size_t io = base + (nh * 5 + ph) * 120 + (nw * 5 + pw);
      imgB[io] = imgA[io] + sO[c * 68 + q * 16 + v];
    }
  }
}

__global__ __launch_bounds__(256) void k_outproj_win(const float* __restrict__ ys, const float* __restrict__ owb,
                                                     float* __restrict__ imgA, float* __restrict__ imgB, int s){
  int g = blockIdx.y;
  int i2 = g * 2 + s;
  int t0 = blockIdx.x * 64;
  const float* W = owb + (size_t)(i2 * 64) * 128;
  const float* Yf = ys + (size_t)(g * 2 + 0) * MT * 128;
  const float* Yb = ys + (size_t)(g * 2 + 1) * MT * 128;
  __shared__ __align__(16) float sA[64 * 36];
  __shared__ __align__(16) float sW[32 * 68];
  __shared__ __align__(16) float sO[64 * 68];
  int tid = threadIdx.x;
  int tr = tid >> 4, tc = tid & 15;
  float acc[4][4];
  #pragma unroll
  for (int i = 0; i < 4; i++){ acc[i][0]=0.f; acc[i][1]=0.f; acc[i][2]=0.f; acc[i][3]=0.f; }

  for (int kt = 0; kt < 4; kt++){
    int k0 = kt * 32;
    {
      int t = tid >> 2, f8 = (tid & 3) * 8;
      int l = t0 + t;
      const float4* pf = (const float4*)&Yf[(size_t)l * 128 + k0 + f8];
      const float4* pb = (const float4*)&Yb[(size_t)(MT - 1 - l) * 128 + k0 + f8];
      float4 v0 = pf[0], v1 = pf[1], w0 = pb[0], w1 = pb[1];
      v0.x += w0.x; v0.y += w0.y; v0.z += w0.z; v0.w += w0.w;
      v1.x += w1.x; v1.y += w1.y; v1.z += w1.z; v1.w += w1.w;
      *(float4*)&sA[t * 36 + f8] = v0; *(float4*)&sA[t * 36 + f8 + 4] = v1;
    }
    {
      int c = tid >> 2, f8 = (tid & 3) * 8;
      const float* wr = &W[(size_t)c * 128 + k0 + f8];
      #pragma unroll
      for (int j = 0; j < 8; j++) sW[(f8 + j) * 68 + c] = wr[j];
    }
    __syncthreads();
    #pragma unroll
    for (int k4 = 0; k4 < 32; k4 += 4){
      float4 a[4];
      #pragma unroll
      for (int i = 0; i < 4; i++) a[i] = *(const float4*)&sA[(tr * 4 + i) * 36 + k4];
      #pragma unroll
      for (int kk = 0; kk < 4; kk++){
        float4 bv = *(const float4*)&sW[(k4 + kk) * 68 + tc * 4];
        #pragma unroll
        for (int i = 0; i < 4; i++){
          float av = ((const float*)&a[i])[kk];
          acc[i][0] += av * bv.x; acc[i][1] += av * bv.y;
          acc[i][2] += av * bv.z; acc[i][3] += av * bv.w;
        }
      }
    }
    __syncthreads();
  }
  #pragma unroll
  for (int j = 0; j < 4; j++)
    *(float4*)&sO[(tc * 4 + j) * 68 + tr * 4] = make_float4(acc[0][j], acc[1][j], acc[2][j], acc[3][j]);
  __syncthreads();
  {
    int c = tid >> 2, q = tid & 3;
    size_t base = (size_t)g * 64 * MT + (size_t)c * MT + t0 + q * 16;
    float* pB = &imgB[base];
    float* pA = &imgA[base];
    const float* pS = &sO[c * 68 + q * 16];
    #pragma unroll
    for (int v = 0; v < 4; v++){
      float4 d = *(const float4*)&pS[v * 4];
      float4 bb = *(const float4*)&pB[v * 4];
      bb.x += d.x; bb.y += d.y; bb.z += d.z; bb.w += d.w;
      *(float4*)&pB[v * 4] = bb;
      float4 aa = *(const float4*)&pA[v * 4];
      aa.x += bb.x; aa.y += bb.y; aa.z += bb.z; aa.w += bb.w;
      *(float4*)&pA[v * 4] = aa;
    }
  }
}

// ---------------- GCN layer 1 (K=512 GEMM over 4 ys streams) ----------------
__global__ __launch_bounds__(256) void k_gcn1(const float* __restrict__ ys, const float* __restrict__ W1c,
                                              float* __restrict__ t1){
  int t0 = blockIdx.x * 64;
  __shared__ __align__(16) float sA[64 * 36];
  __shared__ __align__(16) float sB[32 * 132];
  int tid = threadIdx.x, tr = tid >> 4, tc = tid & 15;
  float acc[4][8];
  #pragma unroll
  for (int i = 0; i < 4; i++)
    #pragma unroll
    for (int j = 0; j < 8; j++) acc[i][j] = 0.f;

  for (int kt = 0; kt < 16; kt++){
    int str = kt >> 2, k0 = (kt & 3) * 32;
    const float* Y = ys + (size_t)str * MT * 128;
    {
      int t = tid >> 2, f8 = (tid & 3) * 8;
      const float4* p = (const float4*)&Y[(size_t)(t0 + t) * 128 + k0 + f8];
      *(float4*)&sA[t * 36 + f8] = p[0]; *(float4*)&sA[t * 36 + f8 + 4] = p[1];
    }
    {
      const float* Wc = W1c + ((size_t)str * 128 + k0) * 128;
      int kk = tid >> 3, f16 = (tid & 7) * 16;
      #pragma unroll
      for (int v = 0; v < 4; v++)
        *(float4*)&sB[kk * 132 + f16 + v * 4] = *(const float4*)&Wc[(size_t)kk * 128 + f16 + v * 4];
    }
    __syncthreads();
    #pragma unroll
    for (int k4 = 0; k4 < 32; k4 += 4){
      float4 a[4];
      #pragma unroll
      for (int i = 0; i < 4; i++) a[i] = *(const float4*)&sA[(tr * 4 + i) * 36 + k4];
      #pragma unroll
      for (int kk = 0; kk < 4; kk++){
        float4 b0 = *(const float4*)&sB[(k4 + kk) * 132 + tc * 8];
        float4 b1 = *(const float4*)&sB[(k4 + kk) * 132 + tc * 8 + 4];
        float bv[8] = {b0.x, b0.y, b0.z, b0.w, b1.x, b1.y, b1.z, b1.w};
        #pragma unroll
        for (int i = 0; i < 4; i++){
          float av = ((const float*)&a[i])[kk];
          #pragma unroll
          for (int j = 0; j < 8; j++) acc[i][j] += av * bv[j];
        }
      }
    }
    __syncthreads();
  }
  #pragma unroll
  for (int i = 0; i < 4; i++){
    size_t base = (size_t)(t0 + tr * 4 + i) * 128 + tc * 8;
    *(float4*)&t1[base]     = make_float4(acc[i][0], acc[i][1], acc[i][2], acc[i][3]);
    *(float4*)&t1[base + 4] = make_float4(acc[i][4], acc[i][5], acc[i][6], acc[i][7]);
  }
}

__global__ __launch_bounds__(128) void k_hub1(const float* __restrict__ t1, float* __restrict__ hubm){
  int f = threadIdx.x;
  float sum = 0.f;
  for (int hb = 0; hb < 450; hb++) sum += t1[(size_t)(hb * 32) * 128 + f];
  hubm[f] = sum * (1.f / 450.f);
}

__global__ __launch_bounds__(256) void k_gcn2(const float* __restrict__ t1, const float* __restrict__ hubm,
                                              const float* __restrict__ b1, const float* __restrict__ W2,
                                              float* __restrict__ t2){
  int t0 = blockIdx.x * 64;
  __shared__ __align__(16) float sA[64 * 36];
  __shared__ __align__(16) float sW[32 * 68];
  int tid = threadIdx.x, tr = tid >> 4, tc = tid & 15;
  float acc[4][4];
  #pragma unroll
  for (int i = 0; i < 4; i++){ acc[i][0]=0.f; acc[i][1]=0.f; acc[i][2]=0.f; acc[i][3]=0.f; }

  for (int kt = 0; kt < 4; kt++){
    int k0 = kt * 32;
    {
      int t = tid >> 2, f8 = (tid & 3) * 8;
      int l = t0 + t;
      const float* src = ((l & 31) == 0) ? &hubm[k0 + f8] : &t1[(size_t)l * 128 + k0 + f8];
      #pragma unroll
      for (int j = 0; j < 8; j++)
        sA[t * 36 + f8 + j] = fmaxf(src[j] + b1[k0 + f8 + j], 0.f);
    }
    {
      int c = tid >> 2, f8 = (tid & 3) * 8;
      const float* wr = &W2[(size_t)c * 128 + k0 + f8];
      #pragma unroll
      for (int j = 0; j < 8; j++) sW[(f8 + j) * 68 + c] = wr[j];
    }
    __syncthreads();
    #pragma unroll
    for (int k4 = 0; k4 < 32; k4 += 4){
      float4 a[4];
      #pragma unroll
      for (int i = 0; i < 4; i++) a[i] = *(const float4*)&sA[(tr * 4 + i) * 36 + k4];
      #pragma unroll
      for (int kk = 0; kk < 4; kk++){
        float4 bv = *(const float4*)&sW[(k4 + kk) * 68 + tc * 4];
        #pragma unroll
        for (int i = 0; i < 4; i++){
          float av = ((const float*)&a[i])[kk];
          acc[i][0] += av * bv.x; acc[i][1] += av * bv.y;
          acc[i][2] += av * bv.z; acc[i][3] += av * bv.w;
        }
      }
    }
    __syncthreads();
  }
  #pragma unroll
  for (int i = 0; i < 4; i++)
    *(float4*)&t2[(size_t)(t0 + tr * 4 + i) * 64 + tc * 4] = make_float4(acc[i][0], acc[i][1], acc[i][2], acc[i][3]);
}

__global__ __launch_bounds__(64) void k_hub2(const float* __restrict__ t2, float* __restrict__ hubm2){
  int c = threadIdx.x;
  float sum = 0.f;
  for (int hb = 0; hb < 450; hb++) sum += t2[(size_t)(hb * 32) * 64 + c];
  hubm2[c] = sum * (1.f / 450.f);
}

__global__ __launch_bounds__(256) void k_final(const void* __restrict__ x, const float* __restrict__ t2,
                                               const float* __restrict__ hubm2, const float* __restrict__ b2,
                                               const float* __restrict__ imgA, void* __restrict__ out,
                                               const int* __restrict__ flag){
  int idx = blockIdx.x * 256 + threadIdx.x;
  int l = idx % MT, c = idx / MT;
  int fp32 = *flag;
  float gval = (((l & 31) == 0) ? hubm2[c] : t2[(size_t)l * 64 + c]) + b2[c];
  float a0 = imgA[idx];
  float a1 = imgA[(size_t)64 * MT + (size_t)c * MT + (l % 120) * 120 + l / 120];
  float xv = fp32 ? ((const float*)x)[idx] : b2f(((const u16*)x)[idx]);
  float val = gval + xv + a0 + a1;
  if (fp32) ((float*)out)[idx] = val;
  else      ((u16*)out)[idx] = f2b(val);
}

extern "C" void kernel_launch(void* const* d_in, const int* in_sizes, int n_in,
                              void* d_out, int out_size, void* d_ws, size_t ws_size,
                              hipStream_t stream){
  int I_X=0,I_PIW=1,I_PCW=2,I_PCB=3,I_PXP=4,I_PDTW=5,I_PDTB=6,I_PAL=7,I_PD=8,I_PLG=9,I_PLB=10,
      I_WIW=11,I_WCW=12,I_WCB=13,I_WXP=14,I_WDTW=15,I_WDTB=16,I_WAL=17,I_WD=18,I_WLG=19,I_WLB=20,
      I_POW=21,I_WOW=22,I_WOBW=23,I_G1=24,I_GB1=25,I_G2=26,I_GB2=27;
  if (n_in >= 28 && in_sizes[9] == 131072){
    I_WIW=9;I_WCW=10;I_WCB=11;I_WXP=12;I_WDTW=13;I_WDTB=14;I_WAL=15;I_WD=16;
    I_PLG=17;I_PLB=18;I_WLG=19;I_WLB=20;
  }
  if (n_in < 28 || in_sizes[I_PIW] != 131072 || out_size != 921600) return;

  float* Wp = (float*)d_ws;
  size_t off = 0;
  auto alloc = [&](size_t n){ size_t r = off; off += (n + 63) & ~(size_t)63; return r; };
  size_t oFlag=alloc(64);
  size_t oPIW=alloc(131072), oPCW=alloc(4096), oPCB=alloc(1024), oPXP=alloc(36864),
         oPDTW=alloc(4096), oPDTB=alloc(1024), oPA=alloc(16384), oPD=alloc(1024),
         oPLG=alloc(256), oPLB=alloc(256);
  size_t oWIW=alloc(131072), oWCW=alloc(4096), oWCB=alloc(1024), oWXP=alloc(36864),
         oWDTW=alloc(4096), oWDTB=alloc(1024), oWA=alloc(16384), oWD=alloc(1024),
         oWLG=alloc(256), oWLB=alloc(256);
  size_t oPOW=alloc(32768), oWOW=alloc(32768), oWOBW=alloc(32768),
         oG1=alloc(32768), oGB1=alloc(128), oG2=alloc(8192), oGB2=alloc(64);
  size_t oPIWT=alloc(131072), oWIWT=alloc(131072), oW1C=alloc(65536);
  size_t oImgA=alloc(2UL*64*MT), oImgB=alloc(2UL*64*MT), oXn=alloc(2UL*MT*64);
  size_t oRaw=alloc(4UL*MT*128);             // xh_raw; aliased as ys after conv
  size_t oZ=alloc(4UL*MT*128), oXhs=alloc(4UL*MT*128), oDelta=alloc(4UL*MT*128);
  size_t oBm=alloc(4UL*MT*16), oCm=alloc(4UL*MT*16);
  size_t oAc=alloc(4UL*WNC*2048), oBc=alloc(4UL*WNC*2048), oHin=alloc(4UL*WNC*2048);
  size_t oT1=alloc((size_t)MT*128), oHub1=alloc(128), oT2=alloc((size_t)MT*64), oHub2=alloc(64);
  if (ws_size < off * sizeof(float)) return;

  int* flag = (int*)(Wp + oFlag);
  k_detect<<<dim3(1), dim3(256), 0, stream>>>((const u16*)d_in[I_PAL], 16384, flag);

  PTab tb;
  int ti = 0;
  auto add = [&](int inIdx, size_t o, int n, int neg){
    tb.src[ti] = d_in[inIdx]; tb.dst[ti] = Wp + o; tb.n[ti] = n; tb.neg[ti] = neg; ti++;
  };
  add(I_PIW,oPIW,131072,0); add(I_PCW,oPCW,4096,0); add(I_PCB,oPCB,1024,0); add(I_PXP,oPXP,36864,0);
  add(I_PDTW,oPDTW,4096,0); add(I_PDTB,oPDTB,1024,0); add(I_PAL,oPA,16384,1); add(I_PD,oPD,1024,0);
  add(I_PLG,oPLG,256,0); add(I_PLB,oPLB,256,0);
  add(I_WIW,oWIW,131072,0); add(I_WCW,oWCW,4096,0); add(I_WCB,oWCB,1024,0); add(I_WXP,oWXP,36864,0);
  add(I_WDTW,oWDTW,4096,0); add(I_WDTB,oWDTB,1024,0); add(I_WAL,oWA,16384,1); add(I_WD,oWD,1024,0);
  add(I_WLG,oWLG,256,0); add(I_WLB,oWLB,256,0);
  add(I_POW,oPOW,32768,0); add(I_WOW,oWOW,32768,0); add(I_WOBW,oWOBW,32768,0);
  add(I_G1,oG1,32768,0); add(I_GB1,oGB1,128,0); add(I_G2,oG2,8192,0); add(I_GB2,oGB2,64,0);

  k_cvt<<<dim3(128, 27), dim3(256), 0, stream>>>(tb, flag);
  k_wtrans<<<dim3(64, 16), dim3(256), 0, stream>>>(Wp+oPIW, Wp+oWIW, Wp+oPIWT, Wp+oWIWT);
  k_gcn1w<<<dim3(64, 4), dim3(256), 0, stream>>>(Wp+oWOW, Wp+oWOBW, Wp+oG1, Wp+oW1C);
  k_cvt_x<<<dim3(3600), dim3(256), 0, stream>>>(d_in[I_X], Wp + oImgA, flag);

  float *imgA = Wp+oImgA, *imgB = Wp+oImgB, *xn = Wp+oXn, *raw = Wp+oRaw, *ys = Wp+oRaw,
        *zz = Wp+oZ, *xhs = Wp+oXhs, *delta = Wp+oDelta, *Bm = Wp+oBm, *Cm = Wp+oCm,
        *Ac = Wp+oAc, *Bc = Wp+oBc, *Hin = Wp+oHin;

  for (int s = 0; s < 2; s++){
    // ---- pixel stage ----
    k_prep_xn<<<dim3(7200), dim3(256), 0, stream>>>(imgA, Wp+oPLG, Wp+oPLB, xn, s, 1);
    k_inproj <<<dim3(450, 4), dim3(256), 0, stream>>>(xn, Wp+oPIWT, raw, zz, s, 1);
    k_conv   <<<dim3(7200, 4), dim3(256), 0, stream>>>(raw, Wp+oPCW, Wp+oPCB, xhs, s, 1);
    k_xproj  <<<dim3(225, 4), dim3(256), 0, stream>>>(xhs, Wp+oPXP, Wp+oPDTW, Wp+oPDTB, delta, Bm, Cm, s);
    k_scan_p1<<<dim3(WNC, 4), dim3(256), 0, stream>>>(delta, xhs, Bm, Wp+oPA, Ac, Bc, s);
    k_scan_p2<<<dim3(32), dim3(256), 0, stream>>>(Ac, Bc, Hin, 6);
    k_scan_p3<<<dim3(WNC, 4), dim3(256), 0, stream>>>(delta, xhs, Bm, Cm, zz, Wp+oPA, Wp+oPD, Hin, ys, s);
    k_outproj_pixel<<<dim3(225, 2), dim3(256), 0, stream>>>(ys, Wp+oPOW, imgA, imgB, s);

    // ---- window stage ----
    k_prep_xn<<<dim3(7200), dim3(256), 0, stream>>>(imgB, Wp+oWLG, Wp+oWLB, xn, s, 0);
    k_inproj <<<dim3(450, 4), dim3(256), 0, stream>>>(xn, Wp+oWIWT, raw, zz, s, 0);
    k_conv   <<<dim3(7200, 4), dim3(256), 0, stream>>>(raw, Wp+oWCW, Wp+oWCB, xhs, s, 0);
    k_xproj  <<<dim3(225, 4), dim3(256), 0, stream>>>(xhs, Wp+oWXP, Wp+oWDTW, Wp+oWDTB, delta, Bm, Cm, s);
    k_scan_p1<<<dim3(WNC, 4), dim3(256), 0, stream>>>(delta, xhs, Bm, Wp+oWA, Ac, Bc, s);
    k_scan_p2<<<dim3(32), dim3(256), 0, stream>>>(Ac, Bc, Hin, WNC);
    k_scan_p3<<<dim3(WNC, 4), dim3(256), 0, stream>>>(delta, xhs, Bm, Cm, zz, Wp+oWA, Wp+oWD, Hin, ys, s);
    k_outproj_win<<<dim3(225, 2), dim3(256), 0, stream>>>(ys, Wp+oWOW, imgA, imgB, s);
  }

  k_gcn1<<<dim3(225), dim3(256), 0, stream>>>(ys, Wp+oW1C, Wp+oT1);
  k_hub1<<<dim3(1), dim3(128), 0, stream>>>(Wp+oT1, Wp+oHub1);
  k_gcn2<<<dim3(225), dim3(256), 0, stream>>>(Wp+oT1, Wp+oHub1, Wp+oGB1, Wp+oG2, Wp+oT2);
  k_hub2<<<dim3(1), dim3(64), 0, stream>>>(Wp+oT2, Wp+oHub2);
  k_final<<<dim3(3600), dim3(256), 0, stream>>>(d_in[I_X], Wp+oT2, Wp+oHub2, Wp+oGB2, imgA, d_out, flag);
}

// Round 8
// 1332.429 us; speedup vs baseline: 4.0929x; 1.0154x over previous
//
#include <hip/hip_runtime.h>
#include <hip/hip_bf16.h>

#define MT 14400
#define WNC 300     // scan chunks per (gd)
#define WCL 48      // chunk length (WNC*WCL = MT; 576 = 12*48 so pixel seqs align)
#define PT 16       // LDS tile (timesteps)

typedef unsigned short u16;

__device__ __forceinline__ float b2f(u16 u){
  union { unsigned int i; float f; } v; v.i = ((unsigned int)u) << 16; return v.f;
}
__device__ __forceinline__ u16 f2b(float f){
  union { unsigned int i; float f; } v; v.f = f;
  unsigned int x = v.i;
  return (u16)((x + 0x7fffu + ((x >> 16) & 1u)) >> 16);
}
__device__ __forceinline__ unsigned int pk2(float a, float b){
  return (unsigned int)f2b(a) | ((unsigned int)f2b(b) << 16);
}
// store 8 bf16 (uint4) as fp32 to LDS
__device__ __forceinline__ void st8(float* p, uint4 v){
  *(float4*)p = make_float4(b2f((u16)v.x), b2f((u16)(v.x >> 16)), b2f((u16)v.y), b2f((u16)(v.y >> 16)));
  *(float4*)(p + 4) = make_float4(b2f((u16)v.z), b2f((u16)(v.z >> 16)), b2f((u16)v.w), b2f((u16)(v.w >> 16)));
}
__device__ __forceinline__ float siluf(float x){ return x / (1.f + expf(-x)); }
__device__ __forceinline__ float softplusf(float x){ return (x > 20.f) ? x : log1pf(expf(x)); }

// ---------------- dtype detection ----------------
__global__ __launch_bounds__(256) void k_detect(const u16* __restrict__ a, int n, int* __restrict__ flag){
  __shared__ int found;
  if (threadIdx.x == 0) found = 0;
  __syncthreads();
  int f = 0;
  for (int i = threadIdx.x; i < n; i += 256){
    float v = b2f(a[i]);
    if (!(fabsf(v) <= 1e9f)) f = 1;
  }
  if (f) atomicOr(&found, 1);
  __syncthreads();
  if (threadIdx.x == 0) *flag = found;
}

// ---------------- param conversion ----------------
struct PTab {
  const void* src[27];
  float* dst[27];
  int n[27];
  int neg[27];
};

__global__ __launch_bounds__(256) void k_cvt(PTab tb, const int* __restrict__ flag){
  int id = blockIdx.y;
  int n = tb.n[id];
  int fp32 = *flag;
  float* d = tb.dst[id];
  int ng = tb.neg[id];
  for (int i = blockIdx.x * 256 + threadIdx.x; i < n; i += gridDim.x * 256){
    float v = fp32 ? ((const float*)tb.src[id])[i] : b2f(((const u16*)tb.src[id])[i]);
    if (ng) v = -expf(v) * 1.4426950408889634f;
    d[i] = v;
  }
}

// transpose in_w: W[mat][256][64] -> WT[mat][64][256]
__global__ __launch_bounds__(256) void k_wtrans(const float* __restrict__ Wpix, const float* __restrict__ Wwin,
                                                float* __restrict__ WTpix, float* __restrict__ WTwin){
  int mat = blockIdx.y;
  const float* src = (mat < 8) ? (Wpix + (size_t)mat * 16384) : (Wwin + (size_t)(mat - 8) * 16384);
  float* dst = (mat < 8) ? (WTpix + (size_t)mat * 16384) : (WTwin + (size_t)(mat - 8) * 16384);
  int idx = blockIdx.x * 256 + threadIdx.x;
  int e = idx >> 6, k = idx & 63;
  dst[k * 256 + e] = src[idx];
}

// combined GCN-1 weights
__global__ __launch_bounds__(256) void k_gcn1w(const float* __restrict__ ow, const float* __restrict__ obw,
                                               const float* __restrict__ G1, float* __restrict__ W1c){
  int str = blockIdx.y;
  int g = str >> 1, d = str & 1;
  int i2 = g * 2 + 1;
  const float* W = (d ? obw : ow) + (size_t)(i2 * 64) * 128;
  int idx = blockIdx.x * 256 + threadIdx.x;
  int kk = idx >> 7, f = idx & 127;
  float acc = 0.f;
  #pragma unroll 8
  for (int c = 0; c < 64; c++)
    acc += W[(size_t)c * 128 + kk] * G1[(size_t)f * 256 + str * 64 + c];
  W1c[((size_t)str * 128 + kk) * 128 + f] = acc;
}

__global__ __launch_bounds__(256) void k_cvt_x(const void* __restrict__ x, float* __restrict__ imgA,
                                               const int* __restrict__ flag){
  int idx = blockIdx.x * 256 + threadIdx.x;
  int l = idx % MT, c = idx / MT;
  float v = (*flag) ? ((const float*)x)[idx] : b2f(((const u16*)x)[idx]);
  imgA[idx] = v;
  imgA[(size_t)64 * MT + (size_t)c * MT + (l % 120) * 120 + l / 120] = v;
}

// ---------------- layernorm + token-order gather (xn -> bf16) ----------------
__global__ __launch_bounds__(256) void k_prep_xn(const float* __restrict__ img, const float* __restrict__ lng,
                                                 const float* __restrict__ lnb, u16* __restrict__ xn,
                                                 int s, int pixelMode){
  int tid = threadIdx.x;
  int q = blockIdx.x * 4 + (tid >> 6);
  int c = tid & 63;
  int g = q / MT, t = q % MT;
  int hw;
  if (pixelMode){
    int b = t / 576, l = t % 576;
    int ph = b / 5, pw = b % 5, nh = l / 24, nw = l % 24;
    hw = (nh * 5 + ph) * 120 + (nw * 5 + pw);
  } else hw = t;
  float v = img[(size_t)g * 64 * MT + (size_t)c * MT + hw];
  float sm = v;
  #pragma unroll
  for (int m = 32; m >= 1; m >>= 1) sm += __shfl_xor(sm, m);
  float mean = sm * (1.f / 64.f);
  float dv = v - mean;
  float s2 = dv * dv;
  #pragma unroll
  for (int m = 32; m >= 1; m >>= 1) s2 += __shfl_xor(s2, m);
  float var = s2 * (1.f / 64.f);
  int i2 = g * 2 + s;
  float o = dv * rsqrtf(var + 1e-5f) * lng[i2 * 64 + c] + lnb[i2 * 64 + c];
  xn[(size_t)g * MT * 64 + (size_t)t * 64 + c] = f2b(o);
}

// ---------------- in-projection: register-tiled GEMM (bf16 in/out) ----------------
__global__ __launch_bounds__(256) void k_inproj(const u16* __restrict__ xn, const float* __restrict__ WT,
                                                u16* __restrict__ xh, u16* __restrict__ z,
                                                int s, int pixelMode){
  int gd = blockIdx.y, g = gd >> 1, dir = gd & 1;
  int i2 = (g * 2 + s) * 2 + dir;
  int ttile = blockIdx.x >> 1, ntile = blockIdx.x & 1;
  int t0 = ttile * 64;
  const float* WTm = WT + (size_t)i2 * 16384 + ntile * 128;

  __shared__ __align__(16) float sA[64 * 68];
  __shared__ __align__(16) float sB[64 * 128];
  int tid = threadIdx.x;

  {
    int k0 = (tid & 15) * 4;
    #pragma unroll
    for (int it = 0; it < 4; it++){
      int t = (tid >> 4) + it * 16;
      int tq = t0 + t, src = tq;
      if (dir){
        if (pixelMode){ int b = tq / 576, l = tq % 576; src = b * 576 + 575 - l; }
        else src = MT - 1 - tq;
      }
      uint2 v = *(const uint2*)&xn[(size_t)g * MT * 64 + (size_t)src * 64 + k0];
      sA[t * 68 + k0]     = b2f((u16)v.x);
      sA[t * 68 + k0 + 1] = b2f((u16)(v.x >> 16));
      sA[t * 68 + k0 + 2] = b2f((u16)v.y);
      sA[t * 68 + k0 + 3] = b2f((u16)(v.y >> 16));
    }
  }
  {
    #pragma unroll
    for (int it = 0; it < 8; it++){
      int idx = it * 256 + tid;
      int k = idx >> 5, e4 = (idx & 31) * 4;
      float4 v = *(const float4*)&WTm[(size_t)k * 256 + e4];
      *(float4*)&sB[k * 128 + e4] = v;
    }
  }
  __syncthreads();

  int tr = tid >> 4, tc = tid & 15;
  float acc[4][8];
  #pragma unroll
  for (int i = 0; i < 4; i++)
    #pragma unroll
    for (int j = 0; j < 8; j++) acc[i][j] = 0.f;

  for (int k0 = 0; k0 < 64; k0 += 4){
    float4 a4[4];
    #pragma unroll
    for (int i = 0; i < 4; i++) a4[i] = *(const float4*)&sA[(tr * 4 + i) * 68 + k0];
    #pragma unroll
    for (int kk = 0; kk < 4; kk++){
      float4 b0 = *(const float4*)&sB[(k0 + kk) * 128 + tc * 8];
      float4 b1 = *(const float4*)&sB[(k0 + kk) * 128 + tc * 8 + 4];
      float bv[8] = {b0.x, b0.y, b0.z, b0.w, b1.x, b1.y, b1.z, b1.w};
      #pragma unroll
      for (int i = 0; i < 4; i++){
        const float* ap = (const float*)&a4[i];
        float av = ap[kk];
        #pragma unroll
        for (int j = 0; j < 8; j++) acc[i][j] += av * bv[j];
      }
    }
  }

  u16* dst = ntile ? z : xh;
  #pragma unroll
  for (int i = 0; i < 4; i++){
    int t_out = t0 + tr * 4 + i;
    size_t base = (size_t)gd * MT * 128 + (size_t)t_out * 128 + tc * 8;
    uint4 o;
    o.x = pk2(acc[i][0], acc[i][1]); o.y = pk2(acc[i][2], acc[i][3]);
    o.z = pk2(acc[i][4], acc[i][5]); o.w = pk2(acc[i][6], acc[i][7]);
    *(uint4*)&dst[base] = o;
  }
}

// ---------------- causal depthwise conv (K=4) + SiLU (bf16 in/out) ----------------
__global__ __launch_bounds__(256) void k_conv(const u16* __restrict__ raw, const float* __restrict__ cw,
                                              const float* __restrict__ cb, u16* __restrict__ xhs,
                                              int s, int pixelMode){
  int gd = blockIdx.y, g = gd >> 1, dir = gd & 1;
  int i2 = (g * 2 + s) * 2 + dir;
  int idx = blockIdx.x * 256 + threadIdx.x;
  int t = idx >> 7, ch = idx & 127;
  int SL = pixelMode ? 576 : MT;
  int pos = t % SL;
  const u16* src = raw + (size_t)gd * MT * 128;
  const float* wrow = cw + (size_t)(i2 * 128 + ch) * 4;
  float acc = cb[i2 * 128 + ch];
  #pragma unroll
  for (int i = 0; i < 4; i++){
    int d = 3 - i;
    if (pos >= d) acc += b2f(src[(size_t)(t - d) * 128 + ch]) * wrow[i];
  }
  xhs[(size_t)gd * MT * 128 + idx] = f2b(siluf(acc));
}

// ---------------- x-projection: tiled GEMM + fused delta/B/C (bf16 in/out) ----------------
__global__ __launch_bounds__(256) void k_xproj(const u16* __restrict__ xhs, const float* __restrict__ xpb,
                                               const float* __restrict__ dtw, const float* __restrict__ dtb,
                                               u16* __restrict__ delta, u16* __restrict__ Bm,
                                               u16* __restrict__ Cm, int s){
  int gd = blockIdx.y, g = gd >> 1, dir = gd & 1;
  int i2 = (g * 2 + s) * 2 + dir;
  const float* XP = xpb + (size_t)i2 * 36 * 128;
  const float* DW = dtw + (size_t)i2 * 128 * 4;
  const float* DB = dtb + (size_t)i2 * 128;
  int t0 = blockIdx.x * 64;
  size_t gb = (size_t)gd * MT * 128;
  size_t gb16 = (size_t)gd * MT * 16;

  __shared__ __align__(16) float sX[64 * 132];
  __shared__ __align__(16) float sW[48 * 132];
  float* sDbl = sX;
  int tid = threadIdx.x;

  #pragma unroll
  for (int it = 0; it < 8; it++){
    int idx = it * 256 + tid;
    int tok = idx >> 5, k4 = (idx & 31) * 4;
    uint2 v = *(const uint2*)&xhs[gb + (size_t)(t0 + tok) * 128 + k4];
    sX[tok * 132 + k4]     = b2f((u16)v.x);
    sX[tok * 132 + k4 + 1] = b2f((u16)(v.x >> 16));
    sX[tok * 132 + k4 + 2] = b2f((u16)v.y);
    sX[tok * 132 + k4 + 3] = b2f((u16)(v.y >> 16));
  }
  for (int idx = tid; idx < 48 * 32; idx += 256){
    int out = idx >> 5, k4 = (idx & 31) * 4;
    float4 v = (out < 36) ? *(const float4*)&XP[(size_t)out * 128 + k4]
                          : make_float4(0.f, 0.f, 0.f, 0.f);
    *(float4*)&sW[out * 132 + k4] = v;
  }
  __syncthreads();

  int tr = tid >> 4, tc = tid & 15;
  float acc[4][3];
  #pragma unroll
  for (int i = 0; i < 4; i++){ acc[i][0]=0.f; acc[i][1]=0.f; acc[i][2]=0.f; }

  for (int k0 = 0; k0 < 128; k0 += 4){
    float4 a4[4], bw[3];
    #pragma unroll
    for (int i = 0; i < 4; i++) a4[i] = *(const float4*)&sX[(tr * 4 + i) * 132 + k0];
    #pragma unroll
    for (int j = 0; j < 3; j++) bw[j] = *(const float4*)&sW[(tc * 3 + j) * 132 + k0];
    #pragma unroll
    for (int kk = 0; kk < 4; kk++){
      #pragma unroll
      for (int i = 0; i < 4; i++){
        float av = ((const float*)&a4[i])[kk];
        #pragma unroll
        for (int j = 0; j < 3; j++) acc[i][j] += av * ((const float*)&bw[j])[kk];
      }
    }
  }
  __syncthreads();

  #pragma unroll
  for (int i = 0; i < 4; i++){
    #pragma unroll
    for (int j = 0; j < 3; j++){
      int out = tc * 3 + j;
      if (out < 36) sDbl[(tr * 4 + i) * 52 + out] = acc[i][j];
    }
  }
  __syncthreads();

  {
    int d = tid & 127, half = tid >> 7;
    float4 dw = *(const float4*)&DW[(size_t)d * 4];
    float db = DB[d];
    #pragma unroll
    for (int it = 0; it < 32; it++){
      int t = it * 2 + half;
      const float* row = &sDbl[t * 52];
      float v = db + row[0] * dw.x + row[1] * dw.y + row[2] * dw.z + row[3] * dw.w;
      delta[gb + (size_t)(t0 + t) * 128 + d] = f2b(softplusf(v));
    }
  }
  #pragma unroll
  for (int it = 0; it < 8; it++){
    int flat = it * 256 + tid;
    int t = flat >> 5, n = flat & 31;
    float v = sDbl[t * 52 + 4 + n];
    if (n < 16) Bm[gb16 + (size_t)(t0 + t) * 16 + n] = f2b(v);
    else        Cm[gb16 + (size_t)(t0 + t) * 16 + (n - 16)] = f2b(v);
  }
}

// ---------------- unified 3-phase chunked scan (bf16 streams, fp32 carries) ----------------
__global__ __launch_bounds__(256) void k_scan_p1(const u16* __restrict__ delta, const u16* __restrict__ xhs,
                                                 const u16* __restrict__ Bm, const float* __restrict__ A2b,
                                                 float* __restrict__ Acar, float* __restrict__ Bcar, int s){
  int gd = blockIdx.y, g = gd >> 1, dir = gd & 1;
  int i2 = (g * 2 + s) * 2 + dir;
  int chunk = blockIdx.x;
  int tid = threadIdx.x, ch = tid >> 1, nb = (tid & 1) * 8;
  float A2[8], ap[8], bc[8];
  #pragma unroll
  for (int j = 0; j < 8; j++){
    A2[j] = A2b[((size_t)i2 * 128 + ch) * 16 + nb + j];
    ap[j] = 1.f; bc[j] = 0.f;
  }
  size_t so = (size_t)gd * MT * 128 + (size_t)chunk * WCL * 128;
  size_t bo = (size_t)gd * MT * 16  + (size_t)chunk * WCL * 16;
  __shared__ __align__(16) float sd[PT * 128];
  __shared__ __align__(16) float su[PT * 128];
  __shared__ __align__(16) float sb[PT * 16];
  uint4 rd, ru; float rbf;
  rd = *(const uint4*)&delta[so + 8 * (size_t)tid];
  ru = *(const uint4*)&xhs[so + 8 * (size_t)tid];
  rbf = b2f(Bm[bo + tid]);
  const int NT = WCL / PT;
  for (int tile = 0; tile < NT; tile++){
    __syncthreads();
    st8(&sd[8 * tid], rd);
    st8(&su[8 * tid], ru);
    sb[tid] = rbf;
    __syncthreads();
    if (tile + 1 < NT){
      rd = *(const uint4*)&delta[so + (size_t)(tile + 1) * PT * 128 + 8 * (size_t)tid];
      ru = *(const uint4*)&xhs[so + (size_t)(tile + 1) * PT * 128 + 8 * (size_t)tid];
      rbf = b2f(Bm[bo + (size_t)(tile + 1) * PT * 16 + tid]);
    }
    #pragma unroll
    for (int t = 0; t < PT; t++){
      float dt = sd[t * 128 + ch];
      float u  = su[t * 128 + ch];
      float du = dt * u;
      #pragma unroll
      for (int j = 0; j < 8; j++){
        float e = exp2f(dt * A2[j]);
        bc[j] = bc[j] * e + du * sb[t * 16 + nb + j];
        ap[j] *= e;
      }
    }
  }
  size_t o = ((size_t)gd * WNC + chunk) * 2048 + (size_t)ch * 16 + nb;
  float4* A4 = (float4*)(Acar + o);
  float4* B4 = (float4*)(Bcar + o);
  A4[0] = make_float4(ap[0], ap[1], ap[2], ap[3]);
  A4[1] = make_float4(ap[4], ap[5], ap[6], ap[7]);
  B4[0] = make_float4(bc[0], bc[1], bc[2], bc[3]);
  B4[1] = make_float4(bc[4], bc[5], bc[6], bc[7]);
}

__global__ __launch_bounds__(256) void k_scan_p2(const float* __restrict__ Acar, const float* __restrict__ Bcar,
                                                 float* __restrict__ Hin, int resetPeriod){
  int flat = blockIdx.x * 256 + threadIdx.x;
  int cs = flat & 2047, gd = flat >> 11;
  float h = 0.f;
  int cnt = 0;
  for (int c = 0; c < WNC; c++){
    if (cnt == resetPeriod) { h = 0.f; cnt = 0; }
    cnt++;
    size_t o = ((size_t)gd * WNC + c) * 2048 + cs;
    Hin[o] = h;
    h = Acar[o] * h + Bcar[o];
  }
}

__global__ __launch_bounds__(256) void k_scan_p3(const u16* __restrict__ delta, const u16* __restrict__ xhs,
                                                 const u16* __restrict__ Bm, const u16* __restrict__ Cm,
                                                 const u16* __restrict__ zz, const float* __restrict__ A2b,
                                                 const float* __restrict__ Db, const float* __restrict__ Hin,
                                                 u16* __restrict__ ys, int s){
  int gd = blockIdx.y, g = gd >> 1, dir = gd & 1;
  int i2 = (g * 2 + s) * 2 + dir;
  int chunk = blockIdx.x;
  int tid = threadIdx.x, ch = tid >> 1, nb = (tid & 1) * 8;
  float A2[8], h[8];
  size_t ho = ((size_t)gd * WNC + chunk) * 2048 + (size_t)ch * 16 + nb;
  {
    const float4* H4 = (const float4*)(Hin + ho);
    float4 h0 = H4[0], h1 = H4[1];
    h[0]=h0.x; h[1]=h0.y; h[2]=h0.z; h[3]=h0.w;
    h[4]=h1.x; h[5]=h1.y; h[6]=h1.z; h[7]=h1.w;
  }
  #pragma unroll
  for (int j = 0; j < 8; j++) A2[j] = A2b[((size_t)i2 * 128 + ch) * 16 + nb + j];
  float Dv = Db[(size_t)i2 * 128 + ch];
  size_t so = (size_t)gd * MT * 128 + (size_t)chunk * WCL * 128;
  size_t bo = (size_t)gd * MT * 16  + (size_t)chunk * WCL * 16;
  __shared__ __align__(16) float sd[PT * 128];
  __shared__ __align__(16) float su[PT * 128];
  __shared__ __align__(16) float sb[PT * 16];
  __shared__ __align__(16) float sc[PT * 16];
  __shared__ __align__(16) float sy[PT * 128];
  uint4 rd, ru; float rbf, rcf;
  rd = *(const uint4*)&delta[so + 8 * (size_t)tid];
  ru = *(const uint4*)&xhs[so + 8 * (size_t)tid];
  rbf = b2f(Bm[bo + tid]); rcf = b2f(Cm[bo + tid]);
  const int NT = WCL / PT;
  for (int tile = 0; tile < NT; tile++){
    __syncthreads();
    st8(&sd[8 * tid], rd);
    st8(&su[8 * tid], ru);
    sb[tid] = rbf; sc[tid] = rcf;
    __syncthreads();
    if (tile + 1 < NT){
      rd = *(const uint4*)&delta[so + (size_t)(tile + 1) * PT * 128 + 8 * (size_t)tid];
      ru = *(const uint4*)&xhs[so + (size_t)(tile + 1) * PT * 128 + 8 * (size_t)tid];
      rbf = b2f(Bm[bo + (size_t)(tile + 1) * PT * 16 + tid]);
      rcf = b2f(Cm[bo + (size_t)(tile + 1) * PT * 16 + tid]);
    }
    #pragma unroll
    for (int t = 0; t < PT; t++){
      float dt = sd[t * 128 + ch];
      float u  = su[t * 128 + ch];
      float du = dt * u;
      float acc = 0.f;
      #pragma unroll
      for (int j = 0; j < 8; j++){
        float e = exp2f(dt * A2[j]);
        h[j] = h[j] * e + du * sb[t * 16 + nb + j];
        acc += h[j] * sc[t * 16 + nb + j];
      }
      acc += __shfl_xor(acc, 1);
      if (!(tid & 1)) sy[t * 128 + ch] = acc + u * Dv;
    }
    __syncthreads();
    {
      uint4 zv = *(const uint4*)&zz[so + (size_t)tile * PT * 128 + 8 * (size_t)tid];
      const float* py = &sy[8 * tid];
      float y[8];
      y[0] = py[0] * siluf(b2f((u16)zv.x));       y[1] = py[1] * siluf(b2f((u16)(zv.x >> 16)));
      y[2] = py[2] * siluf(b2f((u16)zv.y));       y[3] = py[3] * siluf(b2f((u16)(zv.y >> 16)));
      y[4] = py[4] * siluf(b2f((u16)zv.z));       y[5] = py[5] * siluf(b2f((u16)(zv.z >> 16)));
      y[6] = py[6] * siluf(b2f((u16)zv.w));       y[7] = py[7] * siluf(b2f((u16)(zv.w >> 16)));
      uint4 o;
      o.x = pk2(y[0], y[1]); o.y = pk2(y[2], y[3]); o.z = pk2(y[4], y[5]); o.w = pk2(y[6], y[7]);
      *(uint4*)&ys[so + (size_t)tile * PT * 128 + 8 * (size_t)tid] = o;
    }
    __syncthreads();
  }
}

// ---------------- out-projection (tiled GEMM, bf16 ys) + residual ----------------
__global__ __launch_bounds__(256) void k_outproj_pixel(const u16* __restrict__ ys, const float* __restrict__ owb,
                                                       const float* __restrict__ imgA, float* __restrict__ imgB, int s){
  int g = blockIdx.y;
  int i2 = g * 2 + s;
  int tile = blockIdx.x;
  int t0 = tile * 64;
  int b = tile / 9, l0 = (tile % 9) * 64;
  const float* W = owb + (size_t)(i2 * 64) * 128;
  const u16* Yf = ys + (size_t)(g * 2 + 0) * MT * 128;
  const u16* Yb = ys + (size_t)(g * 2 + 1) * MT * 128;
  __shared__ __align__(16) float sA[64 * 36];
  __shared__ __align__(16) float sW[32 * 68];
  __shared__ __align__(16) float sO[64 * 68];
  int tid = threadIdx.x;
  int tr = tid >> 4, tc = tid & 15;
  float acc[4][4];
  #pragma unroll
  for (int i = 0; i < 4; i++){ acc[i][0]=0.f; acc[i][1]=0.f; acc[i][2]=0.f; acc[i][3]=0.f; }

  for (int kt = 0; kt < 4; kt++){
    int k0 = kt * 32;
    {
      int t = tid >> 2, f8 = (tid & 3) * 8;
      int rt = b * 576 + 575 - (l0 + t);
      uint4 vf = *(const uint4*)&Yf[(size_t)(t0 + t) * 128 + k0 + f8];
      uint4 vb = *(const uint4*)&Yb[(size_t)rt * 128 + k0 + f8];
      float* pa = &sA[t * 36 + f8];
      pa[0] = b2f((u16)vf.x) + b2f((u16)vb.x);
      pa[1] = b2f((u16)(vf.x >> 16)) + b2f((u16)(vb.x >> 16));
      pa[2] = b2f((u16)vf.y) + b2f((u16)vb.y);
      pa[3] = b2f((u16)(vf.y >> 16)) + b2f((u16)(vb.y >> 16));
      pa[4] = b2f((u16)vf.z) + b2f((u16)vb.z);
      pa[5] = b2f((u16)(vf.z >> 16)) + b2f((u16)(vb.z >> 16));
      pa[6] = b2f((u16)vf.w) + b2f((u16)vb.w);
      pa[7] = b2f((u16)(vf.w >> 16)) + b2f((u16)(vb.w >> 16));
    }
    {
      int c = tid >> 2, f8 = (tid & 3) * 8;
      const float* wr = &W[(size_t)c * 128 + k0 + f8];
      #pragma unroll
      for (int j = 0; j < 8; j++) sW[(f8 + j) * 68 + c] = wr[j];
    }
    __syncthreads();
    #pragma unroll
    for (int k4 = 0; k4 < 32; k4 += 4){
      float4 a[4];
      #pragma unroll
      for (int i = 0; i < 4; i++) a[i] = *(const float4*)&sA[(tr * 4 + i) * 36 + k4];
      #pragma unroll
      for (int kk = 0; kk < 4; kk++){
        float4 bv = *(const float4*)&sW[(k4 + kk) * 68 + tc * 4];
        #pragma unroll
        for (int i = 0; i < 4; i++){
          float av = ((const float*)&a[i])[kk];
          acc[i][0] += av * bv.x; acc[i][1] += av * bv.y;
          acc[i][2] += av * bv.z; acc[i][3] += av * bv.w;
        }
      }
    }
    __syncthreads();
  }
  #pragma unroll
  for (int j = 0; j < 4; j++)
    *(float4*)&sO[(tc * 4 + j) * 68 + tr * 4] = make_float4(acc[0][j], acc[1][j], acc[2][j], acc[3][j]);
  __syncthreads();
  {
    int c = tid >> 2, q = tid & 3;
    int ph = b / 5, pw = b % 5;
    size_t base = (size_t)g * 64 * MT + (size_t)c * MT;
    #pragma unroll
    for (int v = 0; v < 16; v++){
      int l = l0 + q * 16 + v;
      int nh = l / 24, nw = l % 24;
      size_t io = base + (nh * 5 + ph) * 120 + (nw * 5 + pw);
      imgB[io] = imgA[io] + sO[c * 68 + q * 16 + v];
    }
  }
}

__global__ __launch_bounds__(256) void k_outproj_win(const u16* __restrict__ ys, const float* __restrict__ owb,
                                                     float* __restrict__ imgA, float* __restrict__ imgB, int s){
  int g = blockIdx.y;
  int i2 = g * 2 + s;
  int t0 = blockIdx.x * 64;
  const float* W = owb + (size_t)(i2 * 64) * 128;
  const u16* Yf = ys + (size_t)(g * 2 + 0) * MT * 128;
  const u16* Yb = ys + (size_t)(g * 2 + 1) * MT * 128;
  __shared__ __align__(16) float sA[64 * 36];
  __shared__ __align__(16) float sW[32 * 68];
  __shared__ __align__(16) float sO[64 * 68];
  int tid = threadIdx.x;
  int tr = tid >> 4, tc = tid & 15;
  float acc[4][4];
  #pragma unroll
  for (int i = 0; i < 4; i++){ acc[i][0]=0.f; acc[i][1]=0.f; acc[i][2]=0.f; acc[i][3]=0.f; }

  for (int kt = 0; kt < 4; kt++){
    int k0 = kt * 32;
    {
      int t = tid >> 2, f8 = (tid & 3) * 8;
      int l = t0 + t;
      uint4 vf = *(const uint4*)&Yf[(size_t)l * 128 + k0 + f8];
      uint4 vb = *(const uint4*)&Yb[(size_t)(MT - 1 - l) * 128 + k0 + f8];
      float* pa = &sA[t * 36 + f8];
      pa[0] = b2f((u16)vf.x) + b2f((u16)vb.x);
      pa[1] = b2f((u16)(vf.x >> 16)) + b2f((u16)(vb.x >> 16));
      pa[2] = b2f((u16)vf.y) + b2f((u16)vb.y);
      pa[3] = b2f((u16)(vf.y >> 16)) + b2f((u16)(vb.y >> 16));
      pa[4] = b2f((u16)vf.z) + b2f((u16)vb.z);
      pa[5] = b2f((u16)(vf.z >> 16)) + b2f((u16)(vb.z >> 16));
      pa[6] = b2f((u16)vf.w) + b2f((u16)vb.w);
      pa[7] = b2f((u16)(vf.w >> 16)) + b2f((u16)(vb.w >> 16));
    }
    {
      int c = tid >> 2, f8 = (tid & 3) * 8;
      const float* wr = &W[(size_t)c * 128 + k0 + f8];
      #pragma unroll
      for (int j = 0; j < 8; j++) sW[(f8 + j) * 68 + c] = wr[j];
    }
    __syncthreads();
    #pragma unroll
    for (int k4 = 0; k4 < 32; k4 += 4){
      float4 a[4];
      #pragma unroll
      for (int i = 0; i < 4; i++) a[i] = *(const float4*)&sA[(tr * 4 + i) * 36 + k4];
      #pragma unroll
      for (int kk = 0; kk < 4; kk++){
        float4 bv = *(const float4*)&sW[(k4 + kk) * 68 + tc * 4];
        #pragma unroll
        for (int i = 0; i < 4; i++){
          float av = ((const float*)&a[i])[kk];
          acc[i][0] += av * bv.x; acc[i][1] += av * bv.y;
          acc[i][2] += av * bv.z; acc[i][3] += av * bv.w;
        }
      }
    }
    __syncthreads();
  }
  #pragma unroll
  for (int j = 0; j < 4; j++)
    *(float4*)&sO[(tc * 4 + j) * 68 + tr * 4] = make_float4(acc[0][j], acc[1][j], acc[2][j], acc[3][j]);
  __syncthreads();
  {
    int c = tid >> 2, q = tid & 3;
    size_t base = (size_t)g * 64 * MT + (size_t)c * MT + t0 + q * 16;
    float* pB = &imgB[base];
    float* pA = &imgA[base];
    const float* pS = &sO[c * 68 + q * 16];
    #pragma unroll
    for (int v = 0; v < 4; v++){
      float4 d = *(const float4*)&pS[v * 4];
      float4 bb = *(const float4*)&pB[v * 4];
      bb.x += d.x; bb.y += d.y; bb.z += d.z; bb.w += d.w;
      *(float4*)&pB[v * 4] = bb;
      float4 aa = *(const float4*)&pA[v * 4];
      aa.x += bb.x; aa.y += bb.y; aa.z += bb.z; aa.w += bb.w;
      *(float4*)&pA[v * 4] = aa;
    }
  }
}

// ---------------- GCN layer 1 (K=512 GEMM over 4 bf16 ys streams) ----------------
__global__ __launch_bounds__(256) void k_gcn1(const u16* __restrict__ ys, const float* __restrict__ W1c,
                                              float* __restrict__ t1){
  int t0 = blockIdx.x * 64;
  __shared__ __align__(16) float sA[64 * 36];
  __shared__ __align__(16) float sB[32 * 132];
  int tid = threadIdx.x, tr = tid >> 4, tc = tid & 15;
  float acc[4][8];
  #pragma unroll
  for (int i = 0; i < 4; i++)
    #pragma unroll
    for (int j = 0; j < 8; j++) acc[i][j] = 0.f;

  for (int kt = 0; kt < 16; kt++){
    int str = kt >> 2, k0 = (kt & 3) * 32;
    const u16* Y = ys + (size_t)str * MT * 128;
    {
      int t = tid >> 2, f8 = (tid & 3) * 8;
      uint4 p = *(const uint4*)&Y[(size_t)(t0 + t) * 128 + k0 + f8];
      st8(&sA[t * 36 + f8], p);
    }
    {
      const float* Wc = W1c + ((size_t)str * 128 + k0) * 128;
      int kk = tid >> 3, f16 = (tid & 7) * 16;
      #pragma unroll
      for (int v = 0; v < 4; v++)
        *(float4*)&sB[kk * 132 + f16 + v * 4] = *(const float4*)&Wc[(size_t)kk * 128 + f16 + v * 4];
    }
    __syncthreads();
    #pragma unroll
    for (int k4 = 0; k4 < 32; k4 += 4){
      float4 a[4];
      #pragma unroll
      for (int i = 0; i < 4; i++) a[i] = *(const float4*)&sA[(tr * 4 + i) * 36 + k4];
      #pragma unroll
      for (int kk = 0; kk < 4; kk++){
        float4 b0 = *(const float4*)&sB[(k4 + kk) * 132 + tc * 8];
        float4 b1 = *(const float4*)&sB[(k4 + kk) * 132 + tc * 8 + 4];
        float bv[8] = {b0.x, b0.y, b0.z, b0.w, b1.x, b1.y, b1.z, b1.w};
        #pragma unroll
        for (int i = 0; i < 4; i++){
          float av = ((const float*)&a[i])[kk];
          #pragma unroll
          for (int j = 0; j < 8; j++) acc[i][j] += av * bv[j];
        }
      }
    }
    __syncthreads();
  }
  #pragma unroll
  for (int i = 0; i < 4; i++){
    size_t base = (size_t)(t0 + tr * 4 + i) * 128 + tc * 8;
    *(float4*)&t1[base]     = make_float4(acc[i][0], acc[i][1], acc[i][2], acc[i][3]);
    *(float4*)&t1[base + 4] = make_float4(acc[i][4], acc[i][5], acc[i][6], acc[i][7]);
  }
}

__global__ __launch_bounds__(128) void k_hub1(const float* __restrict__ t1, float* __restrict__ hubm){
  int f = threadIdx.x;
  float sum = 0.f;
  for (int hb = 0; hb < 450; hb++) sum += t1[(size_t)(hb * 32) * 128 + f];
  hubm[f] = sum * (1.f / 450.f);
}

__global__ __launch_bounds__(256) void k_gcn2(const float* __restrict__ t1, const float* __restrict__ hubm,
                                              const float* __restrict__ b1, const float* __restrict__ W2,
                                              float* __restrict__ t2){
  int t0 = blockIdx.x * 64;
  __shared__ __align__(16) float sA[64 * 36];
  __shared__ __align__(16) float sW[32 * 68];
  int tid = threadIdx.x, tr = tid >> 4, tc = tid & 15;
  float acc[4][4];
  #pragma unroll
  for (int i = 0; i < 4; i++){ acc[i][0]=0.f; acc[i][1]=0.f; acc[i][2]=0.f; acc[i][3]=0.f; }

  for (int kt = 0; kt < 4; kt++){
    int k0 = kt * 32;
    {
      int t = tid >> 2, f8 = (tid & 3) * 8;
      int l = t0 + t;
      const float* src = ((l & 31) == 0) ? &hubm[k0 + f8] : &t1[(size_t)l * 128 + k0 + f8];
      #pragma unroll
      for (int j = 0; j < 8; j++)
        sA[t * 36 + f8 + j] = fmaxf(src[j] + b1[k0 + f8 + j], 0.f);
    }
    {
      int c = tid >> 2, f8 = (tid & 3) * 8;
      const float* wr = &W2[(size_t)c * 128 + k0 + f8];
      #pragma unroll
      for (int j = 0; j < 8; j++) sW[(f8 + j) * 68 + c] = wr[j];
    }
    __syncthreads();
    #pragma unroll
    for (int k4 = 0; k4 < 32; k4 += 4){
      float4 a[4];
      #pragma unroll
      for (int i = 0; i < 4; i++) a[i] = *(const float4*)&sA[(tr * 4 + i) * 36 + k4];
      #pragma unroll
      for (int kk = 0; kk < 4; kk++){
        float4 bv = *(const float4*)&sW[(k4 + kk) * 68 + tc * 4];
        #pragma unroll
        for (int i = 0; i < 4; i++){
          float av = ((const float*)&a[i])[kk];
          acc[i][0] += av * bv.x; acc[i][1] += av * bv.y;
          acc[i][2] += av * bv.z; acc[i][3] += av * bv.w;
        }
      }
    }
    __syncthreads();
  }
  #pragma unroll
  for (int i = 0; i < 4; i++)
    *(float4*)&t2[(size_t)(t0 + tr * 4 + i) * 64 + tc * 4] = make_float4(acc[i][0], acc[i][1], acc[i][2], acc[i][3]);
}

__global__ __launch_bounds__(64) void k_hub2(const float* __restrict__ t2, float* __restrict__ hubm2){
  int c = threadIdx.x;
  float sum = 0.f;
  for (int hb = 0; hb < 450; hb++) sum += t2[(size_t)(hb * 32) * 64 + c];
  hubm2[c] = sum * (1.f / 450.f);
}

__global__ __launch_bounds__(256) void k_final(const void* __restrict__ x, const float* __restrict__ t2,
                                               const float* __restrict__ hubm2, const float* __restrict__ b2,
                                               const float* __restrict__ imgA, void* __restrict__ out,
                                               const int* __restrict__ flag){
  int idx = blockIdx.x * 256 + threadIdx.x;
  int l = idx % MT, c = idx / MT;
  int fp32 = *flag;
  float gval = (((l & 31) == 0) ? hubm2[c] : t2[(size_t)l * 64 + c]) + b2[c];
  float a0 = imgA[idx];
  float a1 = imgA[(size_t)64 * MT + (size_t)c * MT + (l % 120) * 120 + l / 120];
  float xv = fp32 ? ((const float*)x)[idx] : b2f(((const u16*)x)[idx]);
  float val = gval + xv + a0 + a1;
  if (fp32) ((float*)out)[idx] = val;
  else      ((u16*)out)[idx] = f2b(val);
}

extern "C" void kernel_launch(void* const* d_in, const int* in_sizes, int n_in,
                              void* d_out, int out_size, void* d_ws, size_t ws_size,
                              hipStream_t stream){
  int I_X=0,I_PIW=1,I_PCW=2,I_PCB=3,I_PXP=4,I_PDTW=5,I_PDTB=6,I_PAL=7,I_PD=8,I_PLG=9,I_PLB=10,
      I_WIW=11,I_WCW=12,I_WCB=13,I_WXP=14,I_WDTW=15,I_WDTB=16,I_WAL=17,I_WD=18,I_WLG=19,I_WLB=20,
      I_POW=21,I_WOW=22,I_WOBW=23,I_G1=24,I_GB1=25,I_G2=26,I_GB2=27;
  if (n_in >= 28 && in_sizes[9] == 131072){
    I_WIW=9;I_WCW=10;I_WCB=11;I_WXP=12;I_WDTW=13;I_WDTB=14;I_WAL=15;I_WD=16;
    I_PLG=17;I_PLB=18;I_WLG=19;I_WLB=20;
  }
  if (n_in < 28 || in_sizes[I_PIW] != 131072 || out_size != 921600) return;

  float* Wp = (float*)d_ws;
  size_t off = 0;
  auto alloc = [&](size_t n){ size_t r = off; off += (n + 63) & ~(size_t)63; return r; };
  size_t oFlag=alloc(64);
  size_t oPIW=alloc(131072), oPCW=alloc(4096), oPCB=alloc(1024), oPXP=alloc(36864),
         oPDTW=alloc(4096), oPDTB=alloc(1024), oPA=alloc(16384), oPD=alloc(1024),
         oPLG=alloc(256), oPLB=alloc(256);
  size_t oWIW=alloc(131072), oWCW=alloc(4096), oWCB=alloc(1024), oWXP=alloc(36864),
         oWDTW=alloc(4096), oWDTB=alloc(1024), oWA=alloc(16384), oWD=alloc(1024),
         oWLG=alloc(256), oWLB=alloc(256);
  size_t oPOW=alloc(32768), oWOW=alloc(32768), oWOBW=alloc(32768),
         oG1=alloc(32768), oGB1=alloc(128), oG2=alloc(8192), oGB2=alloc(64);
  size_t oPIWT=alloc(131072), oWIWT=alloc(131072), oW1C=alloc(65536);
  size_t oImgA=alloc(2UL*64*MT), oImgB=alloc(2UL*64*MT);
  size_t oXn=alloc((size_t)MT*64);           // bf16: 2*MT*64 u16
  size_t oRaw=alloc(2UL*MT*128);             // bf16: 4*MT*128 u16; aliased as ys
  size_t oZ=alloc(2UL*MT*128), oXhs=alloc(2UL*MT*128), oDelta=alloc(2UL*MT*128);
  size_t oBm=alloc(2UL*MT*16), oCm=alloc(2UL*MT*16);
  size_t oAc=alloc(4UL*WNC*2048), oBc=alloc(4UL*WNC*2048), oHin=alloc(4UL*WNC*2048);
  size_t oT1=alloc((size_t)MT*128), oHub1=alloc(128), oT2=alloc((size_t)MT*64), oHub2=alloc(64);
  if (ws_size < off * sizeof(float)) return;

  int* flag = (int*)(Wp + oFlag);
  k_detect<<<dim3(1), dim3(256), 0, stream>>>((const u16*)d_in[I_PAL], 16384, flag);

  PTab tb;
  int ti = 0;
  auto add = [&](int inIdx, size_t o, int n, int neg){
    tb.src[ti] = d_in[inIdx]; tb.dst[ti] = Wp + o; tb.n[ti] = n; tb.neg[ti] = neg; ti++;
  };
  add(I_PIW,oPIW,131072,0); add(I_PCW,oPCW,4096,0); add(I_PCB,oPCB,1024,0); add(I_PXP,oPXP,36864,0);
  add(I_PDTW,oPDTW,4096,0); add(I_PDTB,oPDTB,1024,0); add(I_PAL,oPA,16384,1); add(I_PD,oPD,1024,0);
  add(I_PLG,oPLG,256,0); add(I_PLB,oPLB,256,0);
  add(I_WIW,oWIW,131072,0); add(I_WCW,oWCW,4096,0); add(I_WCB,oWCB,1024,0); add(I_WXP,oWXP,36864,0);
  add(I_WDTW,oWDTW,4096,0); add(I_WDTB,oWDTB,1024,0); add(I_WAL,oWA,16384,1); add(I_WD,oWD,1024,0);
  add(I_WLG,oWLG,256,0); add(I_WLB,oWLB,256,0);
  add(I_POW,oPOW,32768,0); add(I_WOW,oWOW,32768,0); add(I_WOBW,oWOBW,32768,0);
  add(I_G1,oG1,32768,0); add(I_GB1,oGB1,128,0); add(I_G2,oG2,8192,0); add(I_GB2,oGB2,64,0);

  k_cvt<<<dim3(128, 27), dim3(256), 0, stream>>>(tb, flag);
  k_wtrans<<<dim3(64, 16), dim3(256), 0, stream>>>(Wp+oPIW, Wp+oWIW, Wp+oPIWT, Wp+oWIWT);
  k_gcn1w<<<dim3(64, 4), dim3(256), 0, stream>>>(Wp+oWOW, Wp+oWOBW, Wp+oG1, Wp+oW1C);
  k_cvt_x<<<dim3(3600), dim3(256), 0, stream>>>(d_in[I_X], Wp + oImgA, flag);

  float *imgA = Wp+oImgA, *imgB = Wp+oImgB,
        *Ac = Wp+oAc, *Bc = Wp+oBc, *Hin = Wp+oHin;
  u16 *xn = (u16*)(Wp+oXn), *raw = (u16*)(Wp+oRaw), *ys = (u16*)(Wp+oRaw),
      *zz = (u16*)(Wp+oZ), *xhs = (u16*)(Wp+oXhs), *delta = (u16*)(Wp+oDelta),
      *Bm = (u16*)(Wp+oBm), *Cm = (u16*)(Wp+oCm);

  for (int s = 0; s < 2; s++){
    // ---- pixel stage ----
    k_prep_xn<<<dim3(7200), dim3(256), 0, stream>>>(imgA, Wp+oPLG, Wp+oPLB, xn, s, 1);
    k_inproj <<<dim3(450, 4), dim3(256), 0, stream>>>(xn, Wp+oPIWT, raw, zz, s, 1);
    k_conv   <<<dim3(7200, 4), dim3(256), 0, stream>>>(raw, Wp+oPCW, Wp+oPCB, xhs, s, 1);
    k_xproj  <<<dim3(225, 4), dim3(256), 0, stream>>>(xhs, Wp+oPXP, Wp+oPDTW, Wp+oPDTB, delta, Bm, Cm, s);
    k_scan_p1<<<dim3(WNC, 4), dim3(256), 0, stream>>>(delta, xhs, Bm, Wp+oPA, Ac, Bc, s);
    k_scan_p2<<<dim3(32), dim3(256), 0, stream>>>(Ac, Bc, Hin, 12);
    k_scan_p3<<<dim3(WNC, 4), dim3(256), 0, stream>>>(delta, xhs, Bm, Cm, zz, Wp+oPA, Wp+oPD, Hin, ys, s);
    k_outproj_pixel<<<dim3(225, 2), dim3(256), 0, stream>>>(ys, Wp+oPOW, imgA, imgB, s);

    // ---- window stage ----
    k_prep_xn<<<dim3(7200), dim3(256), 0, stream>>>(imgB, Wp+oWLG, Wp+oWLB, xn, s, 0);
    k_inproj <<<dim3(450, 4), dim3(256), 0, stream>>>(xn, Wp+oWIWT, raw, zz, s, 0);
    k_conv   <<<dim3(7200, 4), dim3(256), 0, stream>>>(raw, Wp+oWCW, Wp+oWCB, xhs, s, 0);
    k_xproj  <<<dim3(225, 4), dim3(256), 0, stream>>>(xhs, Wp+oWXP, Wp+oWDTW, Wp+oWDTB, delta, Bm, Cm, s);
    k_scan_p1<<<dim3(WNC, 4), dim3(256), 0, stream>>>(delta, xhs, Bm, Wp+oWA, Ac, Bc, s);
    k_scan_p2<<<dim3(32), dim3(256), 0, stream>>>(Ac, Bc, Hin, WNC);
    k_scan_p3<<<dim3(WNC, 4), dim3(256), 0, stream>>>(delta, xhs, Bm, Cm, zz, Wp+oWA, Wp+oWD, Hin, ys, s);
    k_outproj_win<<<dim3(225, 2), dim3(256), 0, stream>>>(ys, Wp+oWOW, imgA, imgB, s);
  }

  k_gcn1<<<dim3(225), dim3(256), 0, stream>>>(ys, Wp+oW1C, Wp+oT1);
  k_hub1<<<dim3(1), dim3(128), 0, stream>>>(Wp+oT1, Wp+oHub1);
  k_gcn2<<<dim3(225), dim3(256), 0, stream>>>(Wp+oT1, Wp+oHub1, Wp+oGB1, Wp+oG2, Wp+oT2);
  k_hub2<<<dim3(1), dim3(64), 0, stream>>>(Wp+oT2, Wp+oHub2);
  k_final<<<dim3(3600), dim3(256), 0, stream>>>(d_in[I_X], Wp+oT2, Wp+oHub2, Wp+oGB2, imgA, d_out, flag);
}

// Round 9
// 1239.927 us; speedup vs baseline: 4.3983x; 1.0746x over previous
//
#include <hip/hip_runtime.h>
#include <hip/hip_bf16.h>

#define MT 14400
#define WNC 300     // scan chunks per (gd)
#define WCL 48      // chunk length (WNC*WCL = MT; 576 = 12*48)
#define PT 16       // LDS tile (timesteps)

typedef unsigned short u16;

__device__ __forceinline__ float b2f(u16 u){
  union { unsigned int i; float f; } v; v.i = ((unsigned int)u) << 16; return v.f;
}
__device__ __forceinline__ u16 f2b(float f){
  union { unsigned int i; float f; } v; v.f = f;
  unsigned int x = v.i;
  return (u16)((x + 0x7fffu + ((x >> 16) & 1u)) >> 16);
}
__device__ __forceinline__ unsigned int pk2(float a, float b){
  return (unsigned int)f2b(a) | ((unsigned int)f2b(b) << 16);
}
__device__ __forceinline__ void st8(float* p, uint4 v){
  *(float4*)p = make_float4(b2f((u16)v.x), b2f((u16)(v.x >> 16)), b2f((u16)v.y), b2f((u16)(v.y >> 16)));
  *(float4*)(p + 4) = make_float4(b2f((u16)v.z), b2f((u16)(v.z >> 16)), b2f((u16)v.w), b2f((u16)(v.w >> 16)));
}
__device__ __forceinline__ float siluf(float x){ return x / (1.f + expf(-x)); }
__device__ __forceinline__ float softplusf(float x){ return (x > 20.f) ? x : log1pf(expf(x)); }

// ---------------- dtype detection ----------------
__global__ __launch_bounds__(256) void k_detect(const u16* __restrict__ a, int n, int* __restrict__ flag){
  __shared__ int found;
  if (threadIdx.x == 0) found = 0;
  __syncthreads();
  int f = 0;
  for (int i = threadIdx.x; i < n; i += 256){
    float v = b2f(a[i]);
    if (!(fabsf(v) <= 1e9f)) f = 1;
  }
  if (f) atomicOr(&found, 1);
  __syncthreads();
  if (threadIdx.x == 0) *flag = found;
}

// ---------------- param conversion ----------------
struct PTab {
  const void* src[27];
  float* dst[27];
  int n[27];
  int neg[27];
};

__global__ __launch_bounds__(256) void k_cvt(PTab tb, const int* __restrict__ flag){
  int id = blockIdx.y;
  int n = tb.n[id];
  int fp32 = *flag;
  float* d = tb.dst[id];
  int ng = tb.neg[id];
  for (int i = blockIdx.x * 256 + threadIdx.x; i < n; i += gridDim.x * 256){
    float v = fp32 ? ((const float*)tb.src[id])[i] : b2f(((const u16*)tb.src[id])[i]);
    if (ng) v = -expf(v) * 1.4426950408889634f;
    d[i] = v;
  }
}

__global__ __launch_bounds__(256) void k_wtrans(const float* __restrict__ Wpix, const float* __restrict__ Wwin,
                                                float* __restrict__ WTpix, float* __restrict__ WTwin){
  int mat = blockIdx.y;
  const float* src = (mat < 8) ? (Wpix + (size_t)mat * 16384) : (Wwin + (size_t)(mat - 8) * 16384);
  float* dst = (mat < 8) ? (WTpix + (size_t)mat * 16384) : (WTwin + (size_t)(mat - 8) * 16384);
  int idx = blockIdx.x * 256 + threadIdx.x;
  int e = idx >> 6, k = idx & 63;
  dst[k * 256 + e] = src[idx];
}

__global__ __launch_bounds__(256) void k_gcn1w(const float* __restrict__ ow, const float* __restrict__ obw,
                                               const float* __restrict__ G1, float* __restrict__ W1c){
  int str = blockIdx.y;
  int g = str >> 1, d = str & 1;
  int i2 = g * 2 + 1;
  const float* W = (d ? obw : ow) + (size_t)(i2 * 64) * 128;
  int idx = blockIdx.x * 256 + threadIdx.x;
  int kk = idx >> 7, f = idx & 127;
  float acc = 0.f;
  #pragma unroll 8
  for (int c = 0; c < 64; c++)
    acc += W[(size_t)c * 128 + kk] * G1[(size_t)f * 256 + str * 64 + c];
  W1c[((size_t)str * 128 + kk) * 128 + f] = acc;
}

__global__ __launch_bounds__(256) void k_cvt_x(const void* __restrict__ x, float* __restrict__ imgA,
                                               const int* __restrict__ flag){
  int idx = blockIdx.x * 256 + threadIdx.x;
  int l = idx % MT, c = idx / MT;
  float v = (*flag) ? ((const float*)x)[idx] : b2f(((const u16*)x)[idx]);
  imgA[idx] = v;
  imgA[(size_t)64 * MT + (size_t)c * MT + (l % 120) * 120 + l / 120] = v;
}

// ---------------- fused LN + gather + in-projection GEMM ----------------
// 16 threads (one row-group, same wave) cover one token's 64 channels: shuffle-LN
__global__ __launch_bounds__(256) void k_inproj(const float* __restrict__ img, const float* __restrict__ lng,
                                                const float* __restrict__ lnb, const float* __restrict__ WT,
                                                u16* __restrict__ xh, u16* __restrict__ z,
                                                int s, int pixelMode){
  int gd = blockIdx.y, g = gd >> 1, dir = gd & 1;
  int i2 = (g * 2 + s) * 2 + dir;
  int iln = g * 2 + s;
  int ttile = blockIdx.x >> 1, ntile = blockIdx.x & 1;
  int t0 = ttile * 64;
  const float* WTm = WT + (size_t)i2 * 16384 + ntile * 128;

  __shared__ __align__(16) float sA[64 * 68];
  __shared__ __align__(16) float sB[64 * 128];
  int tid = threadIdx.x;
  int row = tid >> 4, col = tid & 15;

  // stage A: gather 4 channels of token, LN via 16-lane shuffle reduce
  {
    const float* base = img + (size_t)g * 64 * MT;
    float g0 = lng[iln * 64 + col * 4],     g1 = lng[iln * 64 + col * 4 + 1],
          g2 = lng[iln * 64 + col * 4 + 2], g3 = lng[iln * 64 + col * 4 + 3];
    float b0 = lnb[iln * 64 + col * 4],     b1 = lnb[iln * 64 + col * 4 + 1],
          b2 = lnb[iln * 64 + col * 4 + 2], b3 = lnb[iln * 64 + col * 4 + 3];
    #pragma unroll
    for (int it = 0; it < 4; it++){
      int t = row + it * 16;
      int tq = t0 + t, src = tq;
      if (dir){
        if (pixelMode){ int b = tq / 576, l = tq % 576; src = b * 576 + 575 - l; }
        else src = MT - 1 - tq;
      }
      int hw;
      if (pixelMode){
        int b = src / 576, l = src % 576;
        int ph = b / 5, pw = b % 5, nh = l / 24, nw = l % 24;
        hw = (nh * 5 + ph) * 120 + (nw * 5 + pw);
      } else hw = src;
      float v0 = base[(size_t)(col * 4)     * MT + hw];
      float v1 = base[(size_t)(col * 4 + 1) * MT + hw];
      float v2 = base[(size_t)(col * 4 + 2) * MT + hw];
      float v3 = base[(size_t)(col * 4 + 3) * MT + hw];
      float sm = v0 + v1 + v2 + v3;
      sm += __shfl_xor(sm, 1); sm += __shfl_xor(sm, 2);
      sm += __shfl_xor(sm, 4); sm += __shfl_xor(sm, 8);
      float mean = sm * (1.f / 64.f);
      float d0 = v0 - mean, d1 = v1 - mean, d2 = v2 - mean, d3 = v3 - mean;
      float s2 = d0 * d0 + d1 * d1 + d2 * d2 + d3 * d3;
      s2 += __shfl_xor(s2, 1); s2 += __shfl_xor(s2, 2);
      s2 += __shfl_xor(s2, 4); s2 += __shfl_xor(s2, 8);
      float rs = rsqrtf(s2 * (1.f / 64.f) + 1e-5f);
      float* pa = &sA[t * 68 + col * 4];
      pa[0] = d0 * rs * g0 + b0; pa[1] = d1 * rs * g1 + b1;
      pa[2] = d2 * rs * g2 + b2; pa[3] = d3 * rs * g3 + b3;
    }
  }
  {
    #pragma unroll
    for (int it = 0; it < 8; it++){
      int idx = it * 256 + tid;
      int k = idx >> 5, e4 = (idx & 31) * 4;
      float4 v = *(const float4*)&WTm[(size_t)k * 256 + e4];
      *(float4*)&sB[k * 128 + e4] = v;
    }
  }
  __syncthreads();

  int tr = tid >> 4, tc = tid & 15;
  float acc[4][8];
  #pragma unroll
  for (int i = 0; i < 4; i++)
    #pragma unroll
    for (int j = 0; j < 8; j++) acc[i][j] = 0.f;

  for (int k0 = 0; k0 < 64; k0 += 4){
    float4 a4[4];
    #pragma unroll
    for (int i = 0; i < 4; i++) a4[i] = *(const float4*)&sA[(tr * 4 + i) * 68 + k0];
    #pragma unroll
    for (int kk = 0; kk < 4; kk++){
      float4 b0 = *(const float4*)&sB[(k0 + kk) * 128 + tc * 8];
      float4 b1 = *(const float4*)&sB[(k0 + kk) * 128 + tc * 8 + 4];
      float bv[8] = {b0.x, b0.y, b0.z, b0.w, b1.x, b1.y, b1.z, b1.w};
      #pragma unroll
      for (int i = 0; i < 4; i++){
        const float* ap = (const float*)&a4[i];
        float av = ap[kk];
        #pragma unroll
        for (int j = 0; j < 8; j++) acc[i][j] += av * bv[j];
      }
    }
  }

  u16* dst = ntile ? z : xh;
  #pragma unroll
  for (int i = 0; i < 4; i++){
    int t_out = t0 + tr * 4 + i;
    size_t base = (size_t)gd * MT * 128 + (size_t)t_out * 128 + tc * 8;
    uint4 o;
    o.x = pk2(acc[i][0], acc[i][1]); o.y = pk2(acc[i][2], acc[i][3]);
    o.z = pk2(acc[i][4], acc[i][5]); o.w = pk2(acc[i][6], acc[i][7]);
    *(uint4*)&dst[base] = o;
  }
}

// ---------------- fused conv+SiLU + x-projection + delta/B/C ----------------
// stages conv(raw) into sX (fp32) and writes xhs (bf16); then GEMM + delta/B/C
__global__ __launch_bounds__(256) void k_xproj(const u16* __restrict__ raw, const float* __restrict__ cw,
                                               const float* __restrict__ cb, const float* __restrict__ xpb,
                                               const float* __restrict__ dtw, const float* __restrict__ dtb,
                                               u16* __restrict__ delta, u16* __restrict__ Bm,
                                               u16* __restrict__ Cm, u16* __restrict__ xhs,
                                               int s, int pixelMode){
  int gd = blockIdx.y, g = gd >> 1, dir = gd & 1;
  int i2 = (g * 2 + s) * 2 + dir;
  const float* XP = xpb + (size_t)i2 * 36 * 128;
  const float* DW = dtw + (size_t)i2 * 128 * 4;
  const float* DB = dtb + (size_t)i2 * 128;
  int t0 = blockIdx.x * 64;
  int SL = pixelMode ? 576 : MT;
  int posBase = t0 % SL;
  size_t gb = (size_t)gd * MT * 128;
  size_t gb16 = (size_t)gd * MT * 16;
  const u16* rawg = raw + gb;

  __shared__ __align__(16) float sX[64 * 132];
  __shared__ __align__(16) float sW[36 * 132];
  float* sDbl = sX;
  int tid = threadIdx.x;

  // stage: conv + silu for (tok, 4 channels), write sX + xhs
  #pragma unroll
  for (int it = 0; it < 8; it++){
    int idx = it * 256 + tid;
    int tok = idx >> 5, k4 = (idx & 31) * 4;
    int t = t0 + tok, pos = posBase + tok;
    const float4* wr0 = (const float4*)&cw[(size_t)(i2 * 128 + k4) * 4];
    float4 w0 = wr0[0], w1 = wr0[1], w2 = wr0[2], w3 = wr0[3];
    float4 cbv = *(const float4*)&cb[i2 * 128 + k4];
    float a0 = cbv.x, a1 = cbv.y, a2 = cbv.z, a3 = cbv.w;
    #pragma unroll
    for (int i = 0; i < 4; i++){
      int d = 3 - i;
      if (pos >= d){
        uint2 rv = *(const uint2*)&rawg[(size_t)(t - d) * 128 + k4];
        float r0 = b2f((u16)rv.x), r1 = b2f((u16)(rv.x >> 16));
        float r2 = b2f((u16)rv.y), r3 = b2f((u16)(rv.y >> 16));
        a0 += r0 * ((const float*)&w0)[i];
        a1 += r1 * ((const float*)&w1)[i];
        a2 += r2 * ((const float*)&w2)[i];
        a3 += r3 * ((const float*)&w3)[i];
      }
    }
    a0 = siluf(a0); a1 = siluf(a1); a2 = siluf(a2); a3 = siluf(a3);
    sX[tok * 132 + k4] = a0; sX[tok * 132 + k4 + 1] = a1;
    sX[tok * 132 + k4 + 2] = a2; sX[tok * 132 + k4 + 3] = a3;
    uint2 o; o.x = pk2(a0, a1); o.y = pk2(a2, a3);
    *(uint2*)&xhs[gb + (size_t)t * 128 + k4] = o;
  }
  for (int idx = tid; idx < 36 * 32; idx += 256){
    int out = idx >> 5, k4 = (idx & 31) * 4;
    *(float4*)&sW[out * 132 + k4] = *(const float4*)&XP[(size_t)out * 128 + k4];
  }
  __syncthreads();

  int tr = tid >> 4, tc = tid & 15;
  float acc[4][3];
  #pragma unroll
  for (int i = 0; i < 4; i++){ acc[i][0]=0.f; acc[i][1]=0.f; acc[i][2]=0.f; }
  int o0 = tc * 3;     if (o0 > 35) o0 = 35;
  int o1 = tc * 3 + 1; if (o1 > 35) o1 = 35;
  int o2 = tc * 3 + 2; if (o2 > 35) o2 = 35;

  for (int k0 = 0; k0 < 128; k0 += 4){
    float4 a4[4], bw[3];
    #pragma unroll
    for (int i = 0; i < 4; i++) a4[i] = *(const float4*)&sX[(tr * 4 + i) * 132 + k0];
    bw[0] = *(const float4*)&sW[o0 * 132 + k0];
    bw[1] = *(const float4*)&sW[o1 * 132 + k0];
    bw[2] = *(const float4*)&sW[o2 * 132 + k0];
    #pragma unroll
    for (int kk = 0; kk < 4; kk++){
      #pragma unroll
      for (int i = 0; i < 4; i++){
        float av = ((const float*)&a4[i])[kk];
        #pragma unroll
        for (int j = 0; j < 3; j++) acc[i][j] += av * ((const float*)&bw[j])[kk];
      }
    }
  }
  __syncthreads();

  #pragma unroll
  for (int i = 0; i < 4; i++){
    #pragma unroll
    for (int j = 0; j < 3; j++){
      int out = tc * 3 + j;
      if (out < 36) sDbl[(tr * 4 + i) * 52 + out] = acc[i][j];
    }
  }
  __syncthreads();

  {
    int d = tid & 127, half = tid >> 7;
    float4 dw = *(const float4*)&DW[(size_t)d * 4];
    float db = DB[d];
    #pragma unroll
    for (int it = 0; it < 32; it++){
      int t = it * 2 + half;
      const float* row = &sDbl[t * 52];
      float v = db + row[0] * dw.x + row[1] * dw.y + row[2] * dw.z + row[3] * dw.w;
      delta[gb + (size_t)(t0 + t) * 128 + d] = f2b(softplusf(v));
    }
  }
  #pragma unroll
  for (int it = 0; it < 8; it++){
    int flat = it * 256 + tid;
    int t = flat >> 5, n = flat & 31;
    float v = sDbl[t * 52 + 4 + n];
    if (n < 16) Bm[gb16 + (size_t)(t0 + t) * 16 + n] = f2b(v);
    else        Cm[gb16 + (size_t)(t0 + t) * 16 + (n - 16)] = f2b(v);
  }
}

// ---------------- unified 3-phase chunked scan (bf16 streams, fp32 carries) ----------------
__global__ __launch_bounds__(256) void k_scan_p1(const u16* __restrict__ delta, const u16* __restrict__ xhs,
                                                 const u16* __restrict__ Bm, const float* __restrict__ A2b,
                                                 float* __restrict__ Acar, float* __restrict__ Bcar, int s){
  int gd = blockIdx.y, g = gd >> 1, dir = gd & 1;
  int i2 = (g * 2 + s) * 2 + dir;
  int chunk = blockIdx.x;
  int tid = threadIdx.x, ch = tid >> 1, nb = (tid & 1) * 8;
  float A2[8], ap[8], bc[8];
  #pragma unroll
  for (int j = 0; j < 8; j++){
    A2[j] = A2b[((size_t)i2 * 128 + ch) * 16 + nb + j];
    ap[j] = 1.f; bc[j] = 0.f;
  }
  size_t so = (size_t)gd * MT * 128 + (size_t)chunk * WCL * 128;
  size_t bo = (size_t)gd * MT * 16  + (size_t)chunk * WCL * 16;
  __shared__ __align__(16) float sd[PT * 128];
  __shared__ __align__(16) float su[PT * 128];
  __shared__ __align__(16) float sb[PT * 16];
  uint4 rd, ru; float rbf;
  rd = *(const uint4*)&delta[so + 8 * (size_t)tid];
  ru = *(const uint4*)&xhs[so + 8 * (size_t)tid];
  rbf = b2f(Bm[bo + tid]);
  const int NT = WCL / PT;
  for (int tile = 0; tile < NT; tile++){
    __syncthreads();
    st8(&sd[8 * tid], rd);
    st8(&su[8 * tid], ru);
    sb[tid] = rbf;
    __syncthreads();
    if (tile + 1 < NT){
      rd = *(const uint4*)&delta[so + (size_t)(tile + 1) * PT * 128 + 8 * (size_t)tid];
      ru = *(const uint4*)&xhs[so + (size_t)(tile + 1) * PT * 128 + 8 * (size_t)tid];
      rbf = b2f(Bm[bo + (size_t)(tile + 1) * PT * 16 + tid]);
    }
    #pragma unroll
    for (int t = 0; t < PT; t++){
      float dt = sd[t * 128 + ch];
      float u  = su[t * 128 + ch];
      float du = dt * u;
      #pragma unroll
      for (int j = 0; j < 8; j++){
        float e = exp2f(dt * A2[j]);
        bc[j] = bc[j] * e + du * sb[t * 16 + nb + j];
        ap[j] *= e;
      }
    }
  }
  size_t o = ((size_t)gd * WNC + chunk) * 2048 + (size_t)ch * 16 + nb;
  float4* A4 = (float4*)(Acar + o);
  float4* B4 = (float4*)(Bcar + o);
  A4[0] = make_float4(ap[0], ap[1], ap[2], ap[3]);
  A4[1] = make_float4(ap[4], ap[5], ap[6], ap[7]);
  B4[0] = make_float4(bc[0], bc[1], bc[2], bc[3]);
  B4[1] = make_float4(bc[4], bc[5], bc[6], bc[7]);
}

__global__ __launch_bounds__(256) void k_scan_p2(const float* __restrict__ Acar, const float* __restrict__ Bcar,
                                                 float* __restrict__ Hin, int resetPeriod){
  int flat = blockIdx.x * 256 + threadIdx.x;
  int cs = flat & 2047, gd = flat >> 11;
  float h = 0.f;
  int cnt = 0;
  for (int c = 0; c < WNC; c++){
    if (cnt == resetPeriod) { h = 0.f; cnt = 0; }
    cnt++;
    size_t o = ((size_t)gd * WNC + c) * 2048 + cs;
    Hin[o] = h;
    h = Acar[o] * h + Bcar[o];
  }
}

__global__ __launch_bounds__(256) void k_scan_p3(const u16* __restrict__ delta, const u16* __restrict__ xhs,
                                                 const u16* __restrict__ Bm, const u16* __restrict__ Cm,
                                                 const u16* __restrict__ zz, const float* __restrict__ A2b,
                                                 const float* __restrict__ Db, const float* __restrict__ Hin,
                                                 u16* __restrict__ ys, int s){
  int gd = blockIdx.y, g = gd >> 1, dir = gd & 1;
  int i2 = (g * 2 + s) * 2 + dir;
  int chunk = blockIdx.x;
  int tid = threadIdx.x, ch = tid >> 1, nb = (tid & 1) * 8;
  float A2[8], h[8];
  size_t ho = ((size_t)gd * WNC + chunk) * 2048 + (size_t)ch * 16 + nb;
  {
    const float4* H4 = (const float4*)(Hin + ho);
    float4 h0 = H4[0], h1 = H4[1];
    h[0]=h0.x; h[1]=h0.y; h[2]=h0.z; h[3]=h0.w;
    h[4]=h1.x; h[5]=h1.y; h[6]=h1.z; h[7]=h1.w;
  }
  #pragma unroll
  for (int j = 0; j < 8; j++) A2[j] = A2b[((size_t)i2 * 128 + ch) * 16 + nb + j];
  float Dv = Db[(size_t)i2 * 128 + ch];
  size_t so = (size_t)gd * MT * 128 + (size_t)chunk * WCL * 128;
  size_t bo = (size_t)gd * MT * 16  + (size_t)chunk * WCL * 16;
  __shared__ __align__(16) float sd[PT * 128];
  __shared__ __align__(16) float su[PT * 128];
  __shared__ __align__(16) float sb[PT * 16];
  __shared__ __align__(16) float sc[PT * 16];
  __shared__ __align__(16) float sy[PT * 128];
  uint4 rd, ru; float rbf, rcf;
  rd = *(const uint4*)&delta[so + 8 * (size_t)tid];
  ru = *(const uint4*)&xhs[so + 8 * (size_t)tid];
  rbf = b2f(Bm[bo + tid]); rcf = b2f(Cm[bo + tid]);
  const int NT = WCL / PT;
  for (int tile = 0; tile < NT; tile++){
    __syncthreads();
    st8(&sd[8 * tid], rd);
    st8(&su[8 * tid], ru);
    sb[tid] = rbf; sc[tid] = rcf;
    __syncthreads();
    if (tile + 1 < NT){
      rd = *(const uint4*)&delta[so + (size_t)(tile + 1) * PT * 128 + 8 * (size_t)tid];
      ru = *(const uint4*)&xhs[so + (size_t)(tile + 1) * PT * 128 + 8 * (size_t)tid];
      rbf = b2f(Bm[bo + (size_t)(tile + 1) * PT * 16 + tid]);
      rcf = b2f(Cm[bo + (size_t)(tile + 1) * PT * 16 + tid]);
    }
    #pragma unroll
    for (int t = 0; t < PT; t++){
      float dt = sd[t * 128 + ch];
      float u  = su[t * 128 + ch];
      float du = dt * u;
      float acc = 0.f;
      #pragma unroll
      for (int j = 0; j < 8; j++){
        float e = exp2f(dt * A2[j]);
        h[j] = h[j] * e + du * sb[t * 16 + nb + j];
        acc += h[j] * sc[t * 16 + nb + j];
      }
      acc += __shfl_xor(acc, 1);
      if (!(tid & 1)) sy[t * 128 + ch] = acc + u * Dv;
    }
    __syncthreads();
    {
      uint4 zv = *(const uint4*)&zz[so + (size_t)tile * PT * 128 + 8 * (size_t)tid];
      const float* py = &sy[8 * tid];
      float y[8];
      y[0] = py[0] * siluf(b2f((u16)zv.x));       y[1] = py[1] * siluf(b2f((u16)(zv.x >> 16)));
      y[2] = py[2] * siluf(b2f((u16)zv.y));       y[3] = py[3] * siluf(b2f((u16)(zv.y >> 16)));
      y[4] = py[4] * siluf(b2f((u16)zv.z));       y[5] = py[5] * siluf(b2f((u16)(zv.z >> 16)));
      y[6] = py[6] * siluf(b2f((u16)zv.w));       y[7] = py[7] * siluf(b2f((u16)(zv.w >> 16)));
      uint4 o;
      o.x = pk2(y[0], y[1]); o.y = pk2(y[2], y[3]); o.z = pk2(y[4], y[5]); o.w = pk2(y[6], y[7]);
      *(uint4*)&ys[so + (size_t)tile * PT * 128 + 8 * (size_t)tid] = o;
    }
    __syncthreads();
  }
}

// ---------------- out-projection (tiled GEMM, bf16 ys) + residual ----------------
__global__ __launch_bounds__(256) void k_outproj_pixel(const u16* __restrict__ ys, const float* __restrict__ owb,
                                                       const float* __restrict__ imgA, float* __restrict__ imgB, int s){
  int g = blockIdx.y;
  int i2 = g * 2 + s;
  int tile = blockIdx.x;
  int t0 = tile * 64;
  int b = tile / 9, l0 = (tile % 9) * 64;
  const float* W = owb + (size_t)(i2 * 64) * 128;
  const u16* Yf = ys + (size_t)(g * 2 + 0) * MT * 128;
  const u16* Yb = ys + (size_t)(g * 2 + 1) * MT * 128;
  __shared__ __align__(16) float sA[64 * 36];
  __shared__ __align__(16) float sW[32 * 68];
  __shared__ __align__(16) float sO[64 * 68];
  int tid = threadIdx.x;
  int tr = tid >> 4, tc = tid & 15;
  float acc[4][4];
  #pragma unroll
  for (int i = 0; i < 4; i++){ acc[i][0]=0.f; acc[i][1]=0.f; acc[i][2]=0.f; acc[i][3]=0.f; }

  for (int kt = 0; kt < 4; kt++){
    int k0 = kt * 32;
    {
      int t = tid >> 2, f8 = (tid & 3) * 8;
      int rt = b * 576 + 575 - (l0 + t);
      uint4 vf = *(const uint4*)&Yf[(size_t)(t0 + t) * 128 + k0 + f8];
      uint4 vb = *(const uint4*)&Yb[(size_t)rt * 128 + k0 + f8];
      float* pa = &sA[t * 36 + f8];
      pa[0] = b2f((u16)vf.x) + b2f((u16)vb.x);
      pa[1] = b2f((u16)(vf.x >> 16)) + b2f((u16)(vb.x >> 16));
      pa[2] = b2f((u16)vf.y) + b2f((u16)vb.y);
      pa[3] = b2f((u16)(vf.y >> 16)) + b2f((u16)(vb.y >> 16));
      pa[4] = b2f((u16)vf.z) + b2f((u16)vb.z);
      pa[5] = b2f((u16)(vf.z >> 16)) + b2f((u16)(vb.z >> 16));
      pa[6] = b2f((u16)vf.w) + b2f((u16)vb.w);
      pa[7] = b2f((u16)(vf.w >> 16)) + b2f((u16)(vb.w >> 16));
    }
    {
      int c = tid >> 2, f8 = (tid & 3) * 8;
      const float* wr = &W[(size_t)c * 128 + k0 + f8];
      #pragma unroll
      for (int j = 0; j < 8; j++) sW[(f8 + j) * 68 + c] = wr[j];
    }
    __syncthreads();
    #pragma unroll
    for (int k4 = 0; k4 < 32; k4 += 4){
      float4 a[4];
      #pragma unroll
      for (int i = 0; i < 4; i++) a[i] = *(const float4*)&sA[(tr * 4 + i) * 36 + k4];
      #pragma unroll
      for (int kk = 0; kk < 4; kk++){
        float4 bv = *(const float4*)&sW[(k4 + kk) * 68 + tc * 4];
        #pragma unroll
        for (int i = 0; i < 4; i++){
          float av = ((const float*)&a[i])[kk];
          acc[i][0] += av * bv.x; acc[i][1] += av * bv.y;
          acc[i][2] += av * bv.z; acc[i][3] += av * bv.w;
        }
      }
    }
    __syncthreads();
  }
  #pragma unroll
  for (int j = 0; j < 4; j++)
    *(float4*)&sO[(tc * 4 + j) * 68 + tr * 4] = make_float4(acc[0][j], acc[1][j], acc[2][j], acc[3][j]);
  __syncthreads();
  {
    int c = tid >> 2, q = tid & 3;
    int ph = b / 5, pw = b % 5;
    size_t base = (size_t)g * 64 * MT + (size_t)c * MT;
    #pragma unroll
    for (int v = 0; v < 16; v++){
      int l = l0 + q * 16 + v;
      int nh = l / 24, nw = l % 24;
      size_t io = base + (nh * 5 + ph) * 120 + (nw * 5 + pw);
      imgB[io] = imgA[io] + sO[c * 68 + q * 16 + v];
    }
  }
}

__global__ __launch_bounds__(256) void k_outproj_win(const u16* __restrict__ ys, const float* __restrict__ owb,
                                                     float* __restrict__ imgA, float* __restrict__ imgB, int s){
  int g = blockIdx.y;
  int i2 = g * 2 + s;
  int t0 = blockIdx.x * 64;
  const float* W = owb + (size_t)(i2 * 64) * 128;
  const u16* Yf = ys + (size_t)(g * 2 + 0) * MT * 128;
  const u16* Yb = ys + (size_t)(g * 2 + 1) * MT * 128;
  __shared__ __align__(16) float sA[64 * 36];
  __shared__ __align__(16) float sW[32 * 68];
  __shared__ __align__(16) float sO[64 * 68];
  int tid = threadIdx.x;
  int tr = tid >> 4, tc = tid & 15;
  float acc[4][4];
  #pragma unroll
  for (int i = 0; i < 4; i++){ acc[i][0]=0.f; acc[i][1]=0.f; acc[i][2]=0.f; acc[i][3]=0.f; }

  for (int kt = 0; kt < 4; kt++){
    int k0 = kt * 32;
    {
      int t = tid >> 2, f8 = (tid & 3) * 8;
      int l = t0 + t;
      uint4 vf = *(const uint4*)&Yf[(size_t)l * 128 + k0 + f8];
      uint4 vb = *(const uint4*)&Yb[(size_t)(MT - 1 - l) * 128 + k0 + f8];
      float* pa = &sA[t * 36 + f8];
      pa[0] = b2f((u16)vf.x) + b2f((u16)vb.x);
      pa[1] = b2f((u16)(vf.x >> 16)) + b2f((u16)(vb.x >> 16));
      pa[2] = b2f((u16)vf.y) + b2f((u16)vb.y);
      pa[3] = b2f((u16)(vf.y >> 16)) + b2f((u16)(vb.y >> 16));
      pa[4] = b2f((u16)vf.z) + b2f((u16)vb.z);
      pa[5] = b2f((u16)(vf.z >> 16)) + b2f((u16)(vb.z >> 16));
      pa[6] = b2f((u16)vf.w) + b2f((u16)vb.w);
      pa[7] = b2f((u16)(vf.w >> 16)) + b2f((u16)(vb.w >> 16));
    }
    {
      int c = tid >> 2, f8 = (tid & 3) * 8;
      const float* wr = &W[(size_t)c * 128 + k0 + f8];
      #pragma unroll
      for (int j = 0; j < 8; j++) sW[(f8 + j) * 68 + c] = wr[j];
    }
    __syncthreads();
    #pragma unroll
    for (int k4 = 0; k4 < 32; k4 += 4){
      float4 a[4];
      #pragma unroll
      for (int i = 0; i < 4; i++) a[i] = *(const float4*)&sA[(tr * 4 + i) * 36 + k4];
      #pragma unroll
      for (int kk = 0; kk < 4; kk++){
        float4 bv = *(const float4*)&sW[(k4 + kk) * 68 + tc * 4];
        #pragma unroll
        for (int i = 0; i < 4; i++){
          float av = ((const float*)&a[i])[kk];
          acc[i][0] += av * bv.x; acc[i][1] += av * bv.y;
          acc[i][2] += av * bv.z; acc[i][3] += av * bv.w;
        }
      }
    }
    __syncthreads();
  }
  #pragma unroll
  for (int j = 0; j < 4; j++)
    *(float4*)&sO[(tc * 4 + j) * 68 + tr * 4] = make_float4(acc[0][j], acc[1][j], acc[2][j], acc[3][j]);
  __syncthreads();
  {
    int c = tid >> 2, q = tid & 3;
    size_t base = (size_t)g * 64 * MT + (size_t)c * MT + t0 + q * 16;
    float* pB = &imgB[base];
    float* pA = &imgA[base];
    const float* pS = &sO[c * 68 + q * 16];
    #pragma unroll
    for (int v = 0; v < 4; v++){
      float4 d = *(const float4*)&pS[v * 4];
      float4 bb = *(const float4*)&pB[v * 4];
      bb.x += d.x; bb.y += d.y; bb.z += d.z; bb.w += d.w;
      *(float4*)&pB[v * 4] = bb;
      float4 aa = *(const float4*)&pA[v * 4];
      aa.x += bb.x; aa.y += bb.y; aa.z += bb.z; aa.w += bb.w;
      *(float4*)&pA[v * 4] = aa;
    }
  }
}

// ---------------- GCN layer 1 (K=512 GEMM over 4 bf16 ys streams) ----------------
__global__ __launch_bounds__(256) void k_gcn1(const u16* __restrict__ ys, const float* __restrict__ W1c,
                                              float* __restrict__ t1){
  int t0 = blockIdx.x * 64;
  __shared__ __align__(16) float sA[64 * 36];
  __shared__ __align__(16) float sB[32 * 132];
  int tid = threadIdx.x, tr = tid >> 4, tc = tid & 15;
  float acc[4][8];
  #pragma unroll
  for (int i = 0; i < 4; i++)
    #pragma unroll
    for (int j = 0; j < 8; j++) acc[i][j] = 0.f;

  for (int kt = 0; kt < 16; kt++){
    int str = kt >> 2, k0 = (kt & 3) * 32;
    const u16* Y = ys + (size_t)str * MT * 128;
    {
      int t = tid >> 2, f8 = (tid & 3) * 8;
      uint4 p = *(const uint4*)&Y[(size_t)(t0 + t) * 128 + k0 + f8];
      st8(&sA[t * 36 + f8], p);
    }
    {
      const float* Wc = W1c + ((size_t)str * 128 + k0) * 128;
      int kk = tid >> 3, f16 = (tid & 7) * 16;
      #pragma unroll
      for (int v = 0; v < 4; v++)
        *(float4*)&sB[kk * 132 + f16 + v * 4] = *(const float4*)&Wc[(size_t)kk * 128 + f16 + v * 4];
    }
    __syncthreads();
    #pragma unroll
    for (int k4 = 0; k4 < 32; k4 += 4){
      float4 a[4];
      #pragma unroll
      for (int i = 0; i < 4; i++) a[i] = *(const float4*)&sA[(tr * 4 + i) * 36 + k4];
      #pragma unroll
      for (int kk = 0; kk < 4; kk++){
        float4 b0 = *(const float4*)&sB[(k4 + kk) * 132 + tc * 8];
        float4 b1 = *(const float4*)&sB[(k4 + kk) * 132 + tc * 8 + 4];
        float bv[8] = {b0.x, b0.y, b0.z, b0.w, b1.x, b1.y, b1.z, b1.w};
        #pragma unroll
        for (int i = 0; i < 4; i++){
          float av = ((const float*)&a[i])[kk];
          #pragma unroll
          for (int j = 0; j < 8; j++) acc[i][j] += av * bv[j];
        }
      }
    }
    __syncthreads();
  }
  #pragma unroll
  for (int i = 0; i < 4; i++){
    size_t base = (size_t)(t0 + tr * 4 + i) * 128 + tc * 8;
    *(float4*)&t1[base]     = make_float4(acc[i][0], acc[i][1], acc[i][2], acc[i][3]);
    *(float4*)&t1[base + 4] = make_float4(acc[i][4], acc[i][5], acc[i][6], acc[i][7]);
  }
}

__global__ __launch_bounds__(128) void k_hub1(const float* __restrict__ t1, float* __restrict__ hubm){
  int f = threadIdx.x;
  float sum = 0.f;
  for (int hb = 0; hb < 450; hb++) sum += t1[(size_t)(hb * 32) * 128 + f];
  hubm[f] = sum * (1.f / 450.f);
}

__global__ __launch_bounds__(256) void k_gcn2(const float* __restrict__ t1, const float* __restrict__ hubm,
                                              const float* __restrict__ b1, const float* __restrict__ W2,
                                              float* __restrict__ t2){
  int t0 = blockIdx.x * 64;
  __shared__ __align__(16) float sA[64 * 36];
  __shared__ __align__(16) float sW[32 * 68];
  int tid = threadIdx.x, tr = tid >> 4, tc = tid & 15;
  float acc[4][4];
  #pragma unroll
  for (int i = 0; i < 4; i++){ acc[i][0]=0.f; acc[i][1]=0.f; acc[i][2]=0.f; acc[i][3]=0.f; }

  for (int kt = 0; kt < 4; kt++){
    int k0 = kt * 32;
    {
      int t = tid >> 2, f8 = (tid & 3) * 8;
      int l = t0 + t;
      const float* src = ((l & 31) == 0) ? &hubm[k0 + f8] : &t1[(size_t)l * 128 + k0 + f8];
      #pragma unroll
      for (int j = 0; j < 8; j++)
        sA[t * 36 + f8 + j] = fmaxf(src[j] + b1[k0 + f8 + j], 0.f);
    }
    {
      int c = tid >> 2, f8 = (tid & 3) * 8;
      const float* wr = &W2[(size_t)c * 128 + k0 + f8];
      #pragma unroll
      for (int j = 0; j < 8; j++) sW[(f8 + j) * 68 + c] = wr[j];
    }
    __syncthreads();
    #pragma unroll
    for (int k4 = 0; k4 < 32; k4 += 4){
      float4 a[4];
      #pragma unroll
      for (int i = 0; i < 4; i++) a[i] = *(const float4*)&sA[(tr * 4 + i) * 36 + k4];
      #pragma unroll
      for (int kk = 0; kk < 4; kk++){
        float4 bv = *(const float4*)&sW[(k4 + kk) * 68 + tc * 4];
        #pragma unroll
        for (int i = 0; i < 4; i++){
          float av = ((const float*)&a[i])[kk];
          acc[i][0] += av * bv.x; acc[i][1] += av * bv.y;
          acc[i][2] += av * bv.z; acc[i][3] += av * bv.w;
        }
      }
    }
    __syncthreads();
  }
  #pragma unroll
  for (int i = 0; i < 4; i++)
    *(float4*)&t2[(size_t)(t0 + tr * 4 + i) * 64 + tc * 4] = make_float4(acc[i][0], acc[i][1], acc[i][2], acc[i][3]);
}

__global__ __launch_bounds__(64) void k_hub2(const float* __restrict__ t2, float* __restrict__ hubm2){
  int c = threadIdx.x;
  float sum = 0.f;
  for (int hb = 0; hb < 450; hb++) sum += t2[(size_t)(hb * 32) * 64 + c];
  hubm2[c] = sum * (1.f / 450.f);
}

__global__ __launch_bounds__(256) void k_final(const void* __restrict__ x, const float* __restrict__ t2,
                                               const float* __restrict__ hubm2, const float* __restrict__ b2,
                                               const float* __restrict__ imgA, void* __restrict__ out,
                                               const int* __restrict__ flag){
  int idx = blockIdx.x * 256 + threadIdx.x;
  int l = idx % MT, c = idx / MT;
  int fp32 = *flag;
  float gval = (((l & 31) == 0) ? hubm2[c] : t2[(size_t)l * 64 + c]) + b2[c];
  float a0 = imgA[idx];
  float a1 = imgA[(size_t)64 * MT + (size_t)c * MT + (l % 120) * 120 + l / 120];
  float xv = fp32 ? ((const float*)x)[idx] : b2f(((const u16*)x)[idx]);
  float val = gval + xv + a0 + a1;
  if (fp32) ((float*)out)[idx] = val;
  else      ((u16*)out)[idx] = f2b(val);
}

extern "C" void kernel_launch(void* const* d_in, const int* in_sizes, int n_in,
                              void* d_out, int out_size, void* d_ws, size_t ws_size,
                              hipStream_t stream){
  int I_X=0,I_PIW=1,I_PCW=2,I_PCB=3,I_PXP=4,I_PDTW=5,I_PDTB=6,I_PAL=7,I_PD=8,I_PLG=9,I_PLB=10,
      I_WIW=11,I_WCW=12,I_WCB=13,I_WXP=14,I_WDTW=15,I_WDTB=16,I_WAL=17,I_WD=18,I_WLG=19,I_WLB=20,
      I_POW=21,I_WOW=22,I_WOBW=23,I_G1=24,I_GB1=25,I_G2=26,I_GB2=27;
  if (n_in >= 28 && in_sizes[9] == 131072){
    I_WIW=9;I_WCW=10;I_WCB=11;I_WXP=12;I_WDTW=13;I_WDTB=14;I_WAL=15;I_WD=16;
    I_PLG=17;I_PLB=18;I_WLG=19;I_WLB=20;
  }
  if (n_in < 28 || in_sizes[I_PIW] != 131072 || out_size != 921600) return;

  float* Wp = (float*)d_ws;
  size_t off = 0;
  auto alloc = [&](size_t n){ size_t r = off; off += (n + 63) & ~(size_t)63; return r; };
  size_t oFlag=alloc(64);
  size_t oPIW=alloc(131072), oPCW=alloc(4096), oPCB=alloc(1024), oPXP=alloc(36864),
         oPDTW=alloc(4096), oPDTB=alloc(1024), oPA=alloc(16384), oPD=alloc(1024),
         oPLG=alloc(256), oPLB=alloc(256);
  size_t oWIW=alloc(131072), oWCW=alloc(4096), oWCB=alloc(1024), oWXP=alloc(36864),
         oWDTW=alloc(4096), oWDTB=alloc(1024), oWA=alloc(16384), oWD=alloc(1024),
         oWLG=alloc(256), oWLB=alloc(256);
  size_t oPOW=alloc(32768), oWOW=alloc(32768), oWOBW=alloc(32768),
         oG1=alloc(32768), oGB1=alloc(128), oG2=alloc(8192), oGB2=alloc(64);
  size_t oPIWT=alloc(131072), oWIWT=alloc(131072), oW1C=alloc(65536);
  size_t oImgA=alloc(2UL*64*MT), oImgB=alloc(2UL*64*MT);
  size_t oRaw=alloc(2UL*MT*128);             // bf16; aliased as ys
  size_t oZ=alloc(2UL*MT*128), oXhs=alloc(2UL*MT*128), oDelta=alloc(2UL*MT*128);
  size_t oBm=alloc(2UL*MT*16), oCm=alloc(2UL*MT*16);
  size_t oAc=alloc(4UL*WNC*2048), oBc=alloc(4UL*WNC*2048), oHin=alloc(4UL*WNC*2048);
  size_t oT1=alloc((size_t)MT*128), oHub1=alloc(128), oT2=alloc((size_t)MT*64), oHub2=alloc(64);
  if (ws_size < off * sizeof(float)) return;

  int* flag = (int*)(Wp + oFlag);
  k_detect<<<dim3(1), dim3(256), 0, stream>>>((const u16*)d_in[I_PAL], 16384, flag);

  PTab tb;
  int ti = 0;
  auto add = [&](int inIdx, size_t o, int n, int neg){
    tb.src[ti] = d_in[inIdx]; tb.dst[ti] = Wp + o; tb.n[ti] = n; tb.neg[ti] = neg; ti++;
  };
  add(I_PIW,oPIW,131072,0); add(I_PCW,oPCW,4096,0); add(I_PCB,oPCB,1024,0); add(I_PXP,oPXP,36864,0);
  add(I_PDTW,oPDTW,4096,0); add(I_PDTB,oPDTB,1024,0); add(I_PAL,oPA,16384,1); add(I_PD,oPD,1024,0);
  add(I_PLG,oPLG,256,0); add(I_PLB,oPLB,256,0);
  add(I_WIW,oWIW,131072,0); add(I_WCW,oWCW,4096,0); add(I_WCB,oWCB,1024,0); add(I_WXP,oWXP,36864,0);
  add(I_WDTW,oWDTW,4096,0); add(I_WDTB,oWDTB,1024,0); add(I_WAL,oWA,16384,1); add(I_WD,oWD,1024,0);
  add(I_WLG,oWLG,256,0); add(I_WLB,oWLB,256,0);
  add(I_POW,oPOW,32768,0); add(I_WOW,oWOW,32768,0); add(I_WOBW,oWOBW,32768,0);
  add(I_G1,oG1,32768,0); add(I_GB1,oGB1,128,0); add(I_G2,oG2,8192,0); add(I_GB2,oGB2,64,0);

  k_cvt<<<dim3(128, 27), dim3(256), 0, stream>>>(tb, flag);
  k_wtrans<<<dim3(64, 16), dim3(256), 0, stream>>>(Wp+oPIW, Wp+oWIW, Wp+oPIWT, Wp+oWIWT);
  k_gcn1w<<<dim3(64, 4), dim3(256), 0, stream>>>(Wp+oWOW, Wp+oWOBW, Wp+oG1, Wp+oW1C);
  k_cvt_x<<<dim3(3600), dim3(256), 0, stream>>>(d_in[I_X], Wp + oImgA, flag);

  float *imgA = Wp+oImgA, *imgB = Wp+oImgB,
        *Ac = Wp+oAc, *Bc = Wp+oBc, *Hin = Wp+oHin;
  u16 *raw = (u16*)(Wp+oRaw), *ys = (u16*)(Wp+oRaw),
      *zz = (u16*)(Wp+oZ), *xhs = (u16*)(Wp+oXhs), *delta = (u16*)(Wp+oDelta),
      *Bm = (u16*)(Wp+oBm), *Cm = (u16*)(Wp+oCm);

  for (int s = 0; s < 2; s++){
    // ---- pixel stage ----
    k_inproj<<<dim3(450, 4), dim3(256), 0, stream>>>(imgA, Wp+oPLG, Wp+oPLB, Wp+oPIWT, raw, zz, s, 1);
    k_xproj <<<dim3(225, 4), dim3(256), 0, stream>>>(raw, Wp+oPCW, Wp+oPCB, Wp+oPXP, Wp+oPDTW, Wp+oPDTB,
                                                     delta, Bm, Cm, xhs, s, 1);
    k_scan_p1<<<dim3(WNC, 4), dim3(256), 0, stream>>>(delta, xhs, Bm, Wp+oPA, Ac, Bc, s);
    k_scan_p2<<<dim3(32), dim3(256), 0, stream>>>(Ac, Bc, Hin, 12);
    k_scan_p3<<<dim3(WNC, 4), dim3(256), 0, stream>>>(delta, xhs, Bm, Cm, zz, Wp+oPA, Wp+oPD, Hin, ys, s);
    k_outproj_pixel<<<dim3(225, 2), dim3(256), 0, stream>>>(ys, Wp+oPOW, imgA, imgB, s);

    // ---- window stage ----
    k_inproj<<<dim3(450, 4), dim3(256), 0, stream>>>(imgB, Wp+oWLG, Wp+oWLB, Wp+oWIWT, raw, zz, s, 0);
    k_xproj <<<dim3(225, 4), dim3(256), 0, stream>>>(raw, Wp+oWCW, Wp+oWCB, Wp+oWXP, Wp+oWDTW, Wp+oWDTB,
                                                     delta, Bm, Cm, xhs, s, 0);
    k_scan_p1<<<dim3(WNC, 4), dim3(256), 0, stream>>>(delta, xhs, Bm, Wp+oWA, Ac, Bc, s);
    k_scan_p2<<<dim3(32), dim3(256), 0, stream>>>(Ac, Bc, Hin, WNC);
    k_scan_p3<<<dim3(WNC, 4), dim3(256), 0, stream>>>(delta, xhs, Bm, Cm, zz, Wp+oWA, Wp+oWD, Hin, ys, s);
    k_outproj_win<<<dim3(225, 2), dim3(256), 0, stream>>>(ys, Wp+oWOW, imgA, imgB, s);
  }

  k_gcn1<<<dim3(225), dim3(256), 0, stream>>>(ys, Wp+oW1C, Wp+oT1);
  k_hub1<<<dim3(1), dim3(128), 0, stream>>>(Wp+oT1, Wp+oHub1);
  k_gcn2<<<dim3(225), dim3(256), 0, stream>>>(Wp+oT1, Wp+oHub1, Wp+oGB1, Wp+oG2, Wp+oT2);
  k_hub2<<<dim3(1), dim3(64), 0, stream>>>(Wp+oT2, Wp+oHub2);
  k_final<<<dim3(3600), dim3(256), 0, stream>>>(d_in[I_X], Wp+oT2, Wp+oHub2, Wp+oGB2, imgA, d_out, flag);
}

// Round 10
// 1220.207 us; speedup vs baseline: 4.4694x; 1.0162x over previous
//
#include <hip/hip_runtime.h>
#include <hip/hip_bf16.h>

#define MT 14400
#define WNC 300     // scan chunks per (gd)
#define WCL 48      // chunk length (WNC*WCL = MT; 576 = 12*48)
#define PT 16       // LDS tile (timesteps)

typedef unsigned short u16;

__device__ __forceinline__ float b2f(u16 u){
  union { unsigned int i; float f; } v; v.i = ((unsigned int)u) << 16; return v.f;
}
__device__ __forceinline__ u16 f2b(float f){
  union { unsigned int i; float f; } v; v.f = f;
  unsigned int x = v.i;
  return (u16)((x + 0x7fffu + ((x >> 16) & 1u)) >> 16);
}
__device__ __forceinline__ unsigned int pk2(float a, float b){
  return (unsigned int)f2b(a) | ((unsigned int)f2b(b) << 16);
}
__device__ __forceinline__ void st8(float* p, uint4 v){
  *(float4*)p = make_float4(b2f((u16)v.x), b2f((u16)(v.x >> 16)), b2f((u16)v.y), b2f((u16)(v.y >> 16)));
  *(float4*)(p + 4) = make_float4(b2f((u16)v.z), b2f((u16)(v.z >> 16)), b2f((u16)v.w), b2f((u16)(v.w >> 16)));
}
__device__ __forceinline__ float siluf(float x){ return x / (1.f + expf(-x)); }
__device__ __forceinline__ float softplusf(float x){ return (x > 20.f) ? x : log1pf(expf(x)); }

// ---------------- dtype detection ----------------
__global__ __launch_bounds__(256) void k_detect(const u16* __restrict__ a, int n, int* __restrict__ flag){
  __shared__ int found;
  if (threadIdx.x == 0) found = 0;
  __syncthreads();
  int f = 0;
  for (int i = threadIdx.x; i < n; i += 256){
    float v = b2f(a[i]);
    if (!(fabsf(v) <= 1e9f)) f = 1;
  }
  if (f) atomicOr(&found, 1);
  __syncthreads();
  if (threadIdx.x == 0) *flag = found;
}

// ---------------- param conversion ----------------
struct PTab {
  const void* src[27];
  float* dst[27];
  int n[27];
  int neg[27];
};

__global__ __launch_bounds__(256) void k_cvt(PTab tb, const int* __restrict__ flag){
  int id = blockIdx.y;
  int n = tb.n[id];
  int fp32 = *flag;
  float* d = tb.dst[id];
  int ng = tb.neg[id];
  for (int i = blockIdx.x * 256 + threadIdx.x; i < n; i += gridDim.x * 256){
    float v = fp32 ? ((const float*)tb.src[id])[i] : b2f(((const u16*)tb.src[id])[i]);
    if (ng) v = -expf(v) * 1.4426950408889634f;
    d[i] = v;
  }
}

__global__ __launch_bounds__(256) void k_wtrans(const float* __restrict__ Wpix, const float* __restrict__ Wwin,
                                                float* __restrict__ WTpix, float* __restrict__ WTwin){
  int mat = blockIdx.y;
  const float* src = (mat < 8) ? (Wpix + (size_t)mat * 16384) : (Wwin + (size_t)(mat - 8) * 16384);
  float* dst = (mat < 8) ? (WTpix + (size_t)mat * 16384) : (WTwin + (size_t)(mat - 8) * 16384);
  int idx = blockIdx.x * 256 + threadIdx.x;
  int e = idx >> 6, k = idx & 63;
  dst[k * 256 + e] = src[idx];
}

__global__ __launch_bounds__(256) void k_gcn1w(const float* __restrict__ ow, const float* __restrict__ obw,
                                               const float* __restrict__ G1, float* __restrict__ W1c){
  int str = blockIdx.y;
  int g = str >> 1, d = str & 1;
  int i2 = g * 2 + 1;
  const float* W = (d ? obw : ow) + (size_t)(i2 * 64) * 128;
  int idx = blockIdx.x * 256 + threadIdx.x;
  int kk = idx >> 7, f = idx & 127;
  float acc = 0.f;
  #pragma unroll 8
  for (int c = 0; c < 64; c++)
    acc += W[(size_t)c * 128 + kk] * G1[(size_t)f * 256 + str * 64 + c];
  W1c[((size_t)str * 128 + kk) * 128 + f] = acc;
}

__global__ __launch_bounds__(256) void k_cvt_x(const void* __restrict__ x, float* __restrict__ imgA,
                                               const int* __restrict__ flag){
  int idx = blockIdx.x * 256 + threadIdx.x;
  int l = idx % MT, c = idx / MT;
  float v = (*flag) ? ((const float*)x)[idx] : b2f(((const u16*)x)[idx]);
  imgA[idx] = v;
  imgA[(size_t)64 * MT + (size_t)c * MT + (l % 120) * 120 + l / 120] = v;
}

// ---------------- fused LN + gather + in-projection GEMM (coalesced, transposed A) ----------------
// lane = token (64 lanes), wave splits channels 16 each; sAT[k][t] conflict-free
__global__ __launch_bounds__(256) void k_inproj(const float* __restrict__ img, const float* __restrict__ lng,
                                                const float* __restrict__ lnb, const float* __restrict__ WT,
                                                u16* __restrict__ xh, u16* __restrict__ z,
                                                int s, int pixelMode){
  int gd = blockIdx.y, g = gd >> 1, dir = gd & 1;
  int i2 = (g * 2 + s) * 2 + dir;
  int iln = g * 2 + s;
  int ttile = blockIdx.x >> 1, ntile = blockIdx.x & 1;
  int t0 = ttile * 64;
  const float* WTm = WT + (size_t)i2 * 16384 + ntile * 128;

  __shared__ __align__(16) float sAT[64 * 68];   // [k=64][t=64] stride 68
  __shared__ __align__(16) float sB[64 * 128];
  __shared__ float ps[4][64], pq[4][64];
  int tid = threadIdx.x;
  int w = tid >> 6, lane = tid & 63;

  // token for this lane
  {
    int tq = t0 + lane, src = tq;
    if (dir){
      if (pixelMode){ int b = tq / 576, l = tq % 576; src = b * 576 + 575 - l; }
      else src = MT - 1 - tq;
    }
    int hw;
    if (pixelMode){
      int b = src / 576, l = src % 576;
      int ph = b / 5, pw = b % 5, nh = l / 24, nw = l % 24;
      hw = (nh * 5 + ph) * 120 + (nw * 5 + pw);
    } else hw = src;
    const float* base = img + (size_t)g * 64 * MT + hw;
    float sum = 0.f, sq = 0.f;
    #pragma unroll
    for (int j = 0; j < 16; j++){
      int c = w * 16 + j;
      float v = base[(size_t)c * MT];
      sAT[c * 68 + lane] = v;
      sum += v; sq += v * v;
    }
    ps[w][lane] = sum; pq[w][lane] = sq;
  }
  // stage B
  {
    #pragma unroll
    for (int it = 0; it < 8; it++){
      int idx = it * 256 + tid;
      int k = idx >> 5, e4 = (idx & 31) * 4;
      float4 v = *(const float4*)&WTm[(size_t)k * 256 + e4];
      *(float4*)&sB[k * 128 + e4] = v;
    }
  }
  __syncthreads();
  {
    float tot = ps[0][lane] + ps[1][lane] + ps[2][lane] + ps[3][lane];
    float tq2 = pq[0][lane] + pq[1][lane] + pq[2][lane] + pq[3][lane];
    float mean = tot * (1.f / 64.f);
    float var = tq2 * (1.f / 64.f) - mean * mean;
    float rs = rsqrtf(fmaxf(var, 0.f) + 1e-5f);
    #pragma unroll
    for (int j = 0; j < 16; j++){
      int c = w * 16 + j;
      float v = sAT[c * 68 + lane];
      sAT[c * 68 + lane] = (v - mean) * rs * lng[iln * 64 + c] + lnb[iln * 64 + c];
    }
  }
  __syncthreads();

  int tr = tid >> 4, tc = tid & 15;
  float acc[4][8];
  #pragma unroll
  for (int i = 0; i < 4; i++)
    #pragma unroll
    for (int j = 0; j < 8; j++) acc[i][j] = 0.f;

  for (int k0 = 0; k0 < 64; k0 += 4){
    #pragma unroll
    for (int kk = 0; kk < 4; kk++){
      float4 at = *(const float4*)&sAT[(k0 + kk) * 68 + tr * 4];
      float4 b0 = *(const float4*)&sB[(k0 + kk) * 128 + tc * 8];
      float4 b1 = *(const float4*)&sB[(k0 + kk) * 128 + tc * 8 + 4];
      float bv[8] = {b0.x, b0.y, b0.z, b0.w, b1.x, b1.y, b1.z, b1.w};
      #pragma unroll
      for (int i = 0; i < 4; i++){
        float av = ((const float*)&at)[i];
        #pragma unroll
        for (int j = 0; j < 8; j++) acc[i][j] += av * bv[j];
      }
    }
  }

  u16* dst = ntile ? z : xh;
  #pragma unroll
  for (int i = 0; i < 4; i++){
    int t_out = t0 + tr * 4 + i;
    size_t base = (size_t)gd * MT * 128 + (size_t)t_out * 128 + tc * 8;
    uint4 o;
    o.x = pk2(acc[i][0], acc[i][1]); o.y = pk2(acc[i][2], acc[i][3]);
    o.z = pk2(acc[i][4], acc[i][5]); o.w = pk2(acc[i][6], acc[i][7]);
    *(uint4*)&dst[base] = o;
  }
}

// ---------------- fused conv+SiLU + x-projection + delta/B/C ----------------
__global__ __launch_bounds__(256) void k_xproj(const u16* __restrict__ raw, const float* __restrict__ cw,
                                               const float* __restrict__ cb, const float* __restrict__ xpb,
                                               const float* __restrict__ dtw, const float* __restrict__ dtb,
                                               u16* __restrict__ delta, u16* __restrict__ Bm,
                                               u16* __restrict__ Cm, u16* __restrict__ xhs,
                                               int s, int pixelMode){
  int gd = blockIdx.y, g = gd >> 1, dir = gd & 1;
  int i2 = (g * 2 + s) * 2 + dir;
  const float* XP = xpb + (size_t)i2 * 36 * 128;
  const float* DW = dtw + (size_t)i2 * 128 * 4;
  const float* DB = dtb + (size_t)i2 * 128;
  int t0 = blockIdx.x * 64;
  int SL = pixelMode ? 576 : MT;
  int posBase = t0 % SL;
  size_t gb = (size_t)gd * MT * 128;
  size_t gb16 = (size_t)gd * MT * 16;
  const u16* rawg = raw + gb;

  __shared__ __align__(16) float sX[64 * 132];
  __shared__ __align__(16) float sW[36 * 132];
  float* sDbl = sX;
  int tid = threadIdx.x;

  #pragma unroll
  for (int it = 0; it < 8; it++){
    int idx = it * 256 + tid;
    int tok = idx >> 5, k4 = (idx & 31) * 4;
    int t = t0 + tok, pos = posBase + tok;
    const float4* wr0 = (const float4*)&cw[(size_t)(i2 * 128 + k4) * 4];
    float4 w0 = wr0[0], w1 = wr0[1], w2 = wr0[2], w3 = wr0[3];
    float4 cbv = *(const float4*)&cb[i2 * 128 + k4];
    float a0 = cbv.x, a1 = cbv.y, a2 = cbv.z, a3 = cbv.w;
    #pragma unroll
    for (int i = 0; i < 4; i++){
      int d = 3 - i;
      if (pos >= d){
        uint2 rv = *(const uint2*)&rawg[(size_t)(t - d) * 128 + k4];
        float r0 = b2f((u16)rv.x), r1 = b2f((u16)(rv.x >> 16));
        float r2 = b2f((u16)rv.y), r3 = b2f((u16)(rv.y >> 16));
        a0 += r0 * ((const float*)&w0)[i];
        a1 += r1 * ((const float*)&w1)[i];
        a2 += r2 * ((const float*)&w2)[i];
        a3 += r3 * ((const float*)&w3)[i];
      }
    }
    a0 = siluf(a0); a1 = siluf(a1); a2 = siluf(a2); a3 = siluf(a3);
    *(float4*)&sX[tok * 132 + k4] = make_float4(a0, a1, a2, a3);
    uint2 o; o.x = pk2(a0, a1); o.y = pk2(a2, a3);
    *(uint2*)&xhs[gb + (size_t)t * 128 + k4] = o;
  }
  for (int idx = tid; idx < 36 * 32; idx += 256){
    int out = idx >> 5, k4 = (idx & 31) * 4;
    *(float4*)&sW[out * 132 + k4] = *(const float4*)&XP[(size_t)out * 128 + k4];
  }
  __syncthreads();

  int tr = tid >> 4, tc = tid & 15;
  float acc[4][3];
  #pragma unroll
  for (int i = 0; i < 4; i++){ acc[i][0]=0.f; acc[i][1]=0.f; acc[i][2]=0.f; }
  int o0 = tc * 3;     if (o0 > 35) o0 = 35;
  int o1 = tc * 3 + 1; if (o1 > 35) o1 = 35;
  int o2 = tc * 3 + 2; if (o2 > 35) o2 = 35;

  for (int k0 = 0; k0 < 128; k0 += 4){
    float4 a4[4], bw[3];
    #pragma unroll
    for (int i = 0; i < 4; i++) a4[i] = *(const float4*)&sX[(tr * 4 + i) * 132 + k0];
    bw[0] = *(const float4*)&sW[o0 * 132 + k0];
    bw[1] = *(const float4*)&sW[o1 * 132 + k0];
    bw[2] = *(const float4*)&sW[o2 * 132 + k0];
    #pragma unroll
    for (int kk = 0; kk < 4; kk++){
      #pragma unroll
      for (int i = 0; i < 4; i++){
        float av = ((const float*)&a4[i])[kk];
        #pragma unroll
        for (int j = 0; j < 3; j++) acc[i][j] += av * ((const float*)&bw[j])[kk];
      }
    }
  }
  __syncthreads();

  #pragma unroll
  for (int i = 0; i < 4; i++){
    #pragma unroll
    for (int j = 0; j < 3; j++){
      int out = tc * 3 + j;
      if (out < 36) sDbl[(tr * 4 + i) * 52 + out] = acc[i][j];
    }
  }
  __syncthreads();

  {
    int d = tid & 127, half = tid >> 7;
    float4 dw = *(const float4*)&DW[(size_t)d * 4];
    float db = DB[d];
    #pragma unroll
    for (int it = 0; it < 32; it++){
      int t = it * 2 + half;
      const float* row = &sDbl[t * 52];
      float v = db + row[0] * dw.x + row[1] * dw.y + row[2] * dw.z + row[3] * dw.w;
      delta[gb + (size_t)(t0 + t) * 128 + d] = f2b(softplusf(v));
    }
  }
  #pragma unroll
  for (int it = 0; it < 8; it++){
    int flat = it * 256 + tid;
    int t = flat >> 5, n = flat & 31;
    float v = sDbl[t * 52 + 4 + n];
    if (n < 16) Bm[gb16 + (size_t)(t0 + t) * 16 + n] = f2b(v);
    else        Cm[gb16 + (size_t)(t0 + t) * 16 + (n - 16)] = f2b(v);
  }
}

// ---------------- unified 3-phase chunked scan (bf16 streams, fp32 carries) ----------------
__global__ __launch_bounds__(256) void k_scan_p1(const u16* __restrict__ delta, const u16* __restrict__ xhs,
                                                 const u16* __restrict__ Bm, const float* __restrict__ A2b,
                                                 float* __restrict__ Acar, float* __restrict__ Bcar, int s){
  int gd = blockIdx.y, g = gd >> 1, dir = gd & 1;
  int i2 = (g * 2 + s) * 2 + dir;
  int chunk = blockIdx.x;
  int tid = threadIdx.x, ch = tid >> 1, nb = (tid & 1) * 8;
  float A2[8], ap[8], bc[8];
  #pragma unroll
  for (int j = 0; j < 8; j++){
    A2[j] = A2b[((size_t)i2 * 128 + ch) * 16 + nb + j];
    ap[j] = 1.f; bc[j] = 0.f;
  }
  size_t so = (size_t)gd * MT * 128 + (size_t)chunk * WCL * 128;
  size_t bo = (size_t)gd * MT * 16  + (size_t)chunk * WCL * 16;
  __shared__ __align__(16) float sd[PT * 128];
  __shared__ __align__(16) float su[PT * 128];
  __shared__ __align__(16) float sb[PT * 16];
  uint4 rd, ru; float rbf;
  rd = *(const uint4*)&delta[so + 8 * (size_t)tid];
  ru = *(const uint4*)&xhs[so + 8 * (size_t)tid];
  rbf = b2f(Bm[bo + tid]);
  const int NT = WCL / PT;
  for (int tile = 0; tile < NT; tile++){
    __syncthreads();
    st8(&sd[8 * tid], rd);
    st8(&su[8 * tid], ru);
    sb[tid] = rbf;
    __syncthreads();
    if (tile + 1 < NT){
      rd = *(const uint4*)&delta[so + (size_t)(tile + 1) * PT * 128 + 8 * (size_t)tid];
      ru = *(const uint4*)&xhs[so + (size_t)(tile + 1) * PT * 128 + 8 * (size_t)tid];
      rbf = b2f(Bm[bo + (size_t)(tile + 1) * PT * 16 + tid]);
    }
    #pragma unroll
    for (int t = 0; t < PT; t++){
      float dt = sd[t * 128 + ch];
      float u  = su[t * 128 + ch];
      float du = dt * u;
      #pragma unroll
      for (int j = 0; j < 8; j++){
        float e = exp2f(dt * A2[j]);
        bc[j] = bc[j] * e + du * sb[t * 16 + nb + j];
        ap[j] *= e;
      }
    }
  }
  size_t o = ((size_t)gd * WNC + chunk) * 2048 + (size_t)ch * 16 + nb;
  float4* A4 = (float4*)(Acar + o);
  float4* B4 = (float4*)(Bcar + o);
  A4[0] = make_float4(ap[0], ap[1], ap[2], ap[3]);
  A4[1] = make_float4(ap[4], ap[5], ap[6], ap[7]);
  B4[0] = make_float4(bc[0], bc[1], bc[2], bc[3]);
  B4[1] = make_float4(bc[4], bc[5], bc[6], bc[7]);
}

__global__ __launch_bounds__(256) void k_scan_p2(const float* __restrict__ Acar, const float* __restrict__ Bcar,
                                                 float* __restrict__ Hin, int resetPeriod){
  int flat = blockIdx.x * 256 + threadIdx.x;
  int cs = flat & 2047, gd = flat >> 11;
  float h = 0.f;
  int cnt = 0;
  for (int c = 0; c < WNC; c++){
    if (cnt == resetPeriod) { h = 0.f; cnt = 0; }
    cnt++;
    size_t o = ((size_t)gd * WNC + c) * 2048 + cs;
    Hin[o] = h;
    h = Acar[o] * h + Bcar[o];
  }
}

__global__ __launch_bounds__(256) void k_scan_p3(const u16* __restrict__ delta, const u16* __restrict__ xhs,
                                                 const u16* __restrict__ Bm, const u16* __restrict__ Cm,
                                                 const u16* __restrict__ zz, const float* __restrict__ A2b,
                                                 const float* __restrict__ Db, const float* __restrict__ Hin,
                                                 u16* __restrict__ ys, int s){
  int gd = blockIdx.y, g = gd >> 1, dir = gd & 1;
  int i2 = (g * 2 + s) * 2 + dir;
  int chunk = blockIdx.x;
  int tid = threadIdx.x, ch = tid >> 1, nb = (tid & 1) * 8;
  float A2[8], h[8];
  size_t ho = ((size_t)gd * WNC + chunk) * 2048 + (size_t)ch * 16 + nb;
  {
    const float4* H4 = (const float4*)(Hin + ho);
    float4 h0 = H4[0], h1 = H4[1];
    h[0]=h0.x; h[1]=h0.y; h[2]=h0.z; h[3]=h0.w;
    h[4]=h1.x; h[5]=h1.y; h[6]=h1.z; h[7]=h1.w;
  }
  #pragma unroll
  for (int j = 0; j < 8; j++) A2[j] = A2b[((size_t)i2 * 128 + ch) * 16 + nb + j];
  float Dv = Db[(size_t)i2 * 128 + ch];
  size_t so = (size_t)gd * MT * 128 + (size_t)chunk * WCL * 128;
  size_t bo = (size_t)gd * MT * 16  + (size_t)chunk * WCL * 16;
  __shared__ __align__(16) float sd[PT * 128];
  __shared__ __align__(16) float su[PT * 128];
  __shared__ __align__(16) float sb[PT * 16];
  __shared__ __align__(16) float sc[PT * 16];
  __shared__ __align__(16) float sy[PT * 128];
  uint4 rd, ru; float rbf, rcf;
  rd = *(const uint4*)&delta[so + 8 * (size_t)tid];
  ru = *(const uint4*)&xhs[so + 8 * (size_t)tid];
  rbf = b2f(Bm[bo + tid]); rcf = b2f(Cm[bo + tid]);
  const int NT = WCL / PT;
  for (int tile = 0; tile < NT; tile++){
    __syncthreads();
    st8(&sd[8 * tid], rd);
    st8(&su[8 * tid], ru);
    sb[tid] = rbf; sc[tid] = rcf;
    __syncthreads();
    if (tile + 1 < NT){
      rd = *(const uint4*)&delta[so + (size_t)(tile + 1) * PT * 128 + 8 * (size_t)tid];
      ru = *(const uint4*)&xhs[so + (size_t)(tile + 1) * PT * 128 + 8 * (size_t)tid];
      rbf = b2f(Bm[bo + (size_t)(tile + 1) * PT * 16 + tid]);
      rcf = b2f(Cm[bo + (size_t)(tile + 1) * PT * 16 + tid]);
    }
    #pragma unroll
    for (int t = 0; t < PT; t++){
      float dt = sd[t * 128 + ch];
      float u  = su[t * 128 + ch];
      float du = dt * u;
      float acc = 0.f;
      #pragma unroll
      for (int j = 0; j < 8; j++){
        float e = exp2f(dt * A2[j]);
        h[j] = h[j] * e + du * sb[t * 16 + nb + j];
        acc += h[j] * sc[t * 16 + nb + j];
      }
      acc += __shfl_xor(acc, 1);
      if (!(tid & 1)) sy[t * 128 + ch] = acc + u * Dv;
    }
    __syncthreads();
    {
      uint4 zv = *(const uint4*)&zz[so + (size_t)tile * PT * 128 + 8 * (size_t)tid];
      const float* py = &sy[8 * tid];
      float y[8];
      y[0] = py[0] * siluf(b2f((u16)zv.x));       y[1] = py[1] * siluf(b2f((u16)(zv.x >> 16)));
      y[2] = py[2] * siluf(b2f((u16)zv.y));       y[3] = py[3] * siluf(b2f((u16)(zv.y >> 16)));
      y[4] = py[4] * siluf(b2f((u16)zv.z));       y[5] = py[5] * siluf(b2f((u16)(zv.z >> 16)));
      y[6] = py[6] * siluf(b2f((u16)zv.w));       y[7] = py[7] * siluf(b2f((u16)(zv.w >> 16)));
      uint4 o;
      o.x = pk2(y[0], y[1]); o.y = pk2(y[2], y[3]); o.z = pk2(y[4], y[5]); o.w = pk2(y[6], y[7]);
      *(uint4*)&ys[so + (size_t)tile * PT * 128 + 8 * (size_t)tid] = o;
    }
    __syncthreads();
  }
}

// ---------------- out-projection (tiled GEMM, bf16 ys) + residual ----------------
__global__ __launch_bounds__(256) void k_outproj_pixel(const u16* __restrict__ ys, const float* __restrict__ owb,
                                                       const float* __restrict__ imgA, float* __restrict__ imgB, int s){
  int g = blockIdx.y;
  int i2 = g * 2 + s;
  int tile = blockIdx.x;
  int t0 = tile * 64;
  int b = tile / 9, l0 = (tile % 9) * 64;
  const float* W = owb + (size_t)(i2 * 64) * 128;
  const u16* Yf = ys + (size_t)(g * 2 + 0) * MT * 128;
  const u16* Yb = ys + (size_t)(g * 2 + 1) * MT * 128;
  __shared__ __align__(16) float sA[64 * 36];
  __shared__ __align__(16) float sW[32 * 68];
  __shared__ __align__(16) float sO[64 * 68];
  int tid = threadIdx.x;
  int tr = tid >> 4, tc = tid & 15;
  float acc[4][4];
  #pragma unroll
  for (int i = 0; i < 4; i++){ acc[i][0]=0.f; acc[i][1]=0.f; acc[i][2]=0.f; acc[i][3]=0.f; }

  for (int kt = 0; kt < 4; kt++){
    int k0 = kt * 32;
    {
      int t = tid >> 2, f8 = (tid & 3) * 8;
      int rt = b * 576 + 575 - (l0 + t);
      uint4 vf = *(const uint4*)&Yf[(size_t)(t0 + t) * 128 + k0 + f8];
      uint4 vb = *(const uint4*)&Yb[(size_t)rt * 128 + k0 + f8];
      float* pa = &sA[t * 36 + f8];
      pa[0] = b2f((u16)vf.x) + b2f((u16)vb.x);
      pa[1] = b2f((u16)(vf.x >> 16)) + b2f((u16)(vb.x >> 16));
      pa[2] = b2f((u16)vf.y) + b2f((u16)vb.y);
      pa[3] = b2f((u16)(vf.y >> 16)) + b2f((u16)(vb.y >> 16));
      pa[4] = b2f((u16)vf.z) + b2f((u16)vb.z);
      pa[5] = b2f((u16)(vf.z >> 16)) + b2f((u16)(vb.z >> 16));
      pa[6] = b2f((u16)vf.w) + b2f((u16)vb.w);
      pa[7] = b2f((u16)(vf.w >> 16)) + b2f((u16)(vb.w >> 16));
    }
    {
      int c = tid >> 2, f8 = (tid & 3) * 8;
      const float* wr = &W[(size_t)c * 128 + k0 + f8];
      #pragma unroll
      for (int j = 0; j < 8; j++) sW[(f8 + j) * 68 + c] = wr[j];
    }
    __syncthreads();
    #pragma unroll
    for (int k4 = 0; k4 < 32; k4 += 4){
      float4 a[4];
      #pragma unroll
      for (int i = 0; i < 4; i++) a[i] = *(const float4*)&sA[(tr * 4 + i) * 36 + k4];
      #pragma unroll
      for (int kk = 0; kk < 4; kk++){
        float4 bv = *(const float4*)&sW[(k4 + kk) * 68 + tc * 4];
        #pragma unroll
        for (int i = 0; i < 4; i++){
          float av = ((const float*)&a[i])[kk];
          acc[i][0] += av * bv.x; acc[i][1] += av * bv.y;
          acc[i][2] += av * bv.z; acc[i][3] += av * bv.w;
        }
      }
    }
    __syncthreads();
  }
  #pragma unroll
  for (int j = 0; j < 4; j++)
    *(float4*)&sO[(tc * 4 + j) * 68 + tr * 4] = make_float4(acc[0][j], acc[1][j], acc[2][j], acc[3][j]);
  __syncthreads();
  {
    int c = tid >> 2, q = tid & 3;
    int ph = b / 5, pw = b % 5;
    size_t base = (size_t)g * 64 * MT + (size_t)c * MT;
    #pragma unroll
    for (int v = 0; v < 16; v++){
      int l = l0 + q * 16 + v;
      int nh = l / 24, nw = l % 24;
      size_t io = base + (nh * 5 + ph) * 120 + (nw * 5 + pw);
      imgB[io] = imgA[io] + sO[c * 68 + q * 16 + v];
    }
  }
}

__global__ __launch_bounds__(256) void k_outproj_win(const u16* __restrict__ ys, const float* __restrict__ owb,
                                                     float* __restrict__ imgA, float* __restrict__ imgB, int s){
  int g = blockIdx.y;
  int i2 = g * 2 + s;
  int t0 = blockIdx.x * 64;
  const float* W = owb + (size_t)(i2 * 64) * 128;
  const u16* Yf = ys + (size_t)(g * 2 + 0) * MT * 128;
  const u16* Yb = ys + (size_t)(g * 2 + 1) * MT * 128;
  __shared__ __align__(16) float sA[64 * 36];
  __shared__ __align__(16) float sW[32 * 68];
  __shared__ __align__(16) float sO[64 * 68];
  int tid = threadIdx.x;
  int tr = tid >> 4, tc = tid & 15;
  float acc[4][4];
  #pragma unroll
  for (int i = 0; i < 4; i++){ acc[i][0]=0.f; acc[i][1]=0.f; acc[i][2]=0.f; acc[i][3]=0.f; }

  for (int kt = 0; kt < 4; kt++){
    int k0 = kt * 32;
    {
      int t = tid >> 2, f8 = (tid & 3) * 8;
      int l = t0 + t;
      uint4 vf = *(const uint4*)&Yf[(size_t)l * 128 + k0 + f8];
      uint4 vb = *(const uint4*)&Yb[(size_t)(MT - 1 - l) * 128 + k0 + f8];
      float* pa = &sA[t * 36 + f8];
      pa[0] = b2f((u16)vf.x) + b2f((u16)vb.x);
      pa[1] = b2f((u16)(vf.x >> 16)) + b2f((u16)(vb.x >> 16));
      pa[2] = b2f((u16)vf.y) + b2f((u16)vb.y);
      pa[3] = b2f((u16)(vf.y >> 16)) + b2f((u16)(vb.y >> 16));
      pa[4] = b2f((u16)vf.z) + b2f((u16)vb.z);
      pa[5] = b2f((u16)(vf.z >> 16)) + b2f((u16)(vb.z >> 16));
      pa[6] = b2f((u16)vf.w) + b2f((u16)vb.w);
      pa[7] = b2f((u16)(vf.w >> 16)) + b2f((u16)(vb.w >> 16));
    }
    {
      int c = tid >> 2, f8 = (tid & 3) * 8;
      const float* wr = &W[(size_t)c * 128 + k0 + f8];
      #pragma unroll
      for (int j = 0; j < 8; j++) sW[(f8 + j) * 68 + c] = wr[j];
    }
    __syncthreads();
    #pragma unroll
    for (int k4 = 0; k4 < 32; k4 += 4){
      float4 a[4];
      #pragma unroll
      for (int i = 0; i < 4; i++) a[i] = *(const float4*)&sA[(tr * 4 + i) * 36 + k4];
      #pragma unroll
      for (int kk = 0; kk < 4; kk++){
        float4 bv = *(const float4*)&sW[(k4 + kk) * 68 + tc * 4];
        #pragma unroll
        for (int i = 0; i < 4; i++){
          float av = ((const float*)&a[i])[kk];
          acc[i][0] += av * bv.x; acc[i][1] += av * bv.y;
          acc[i][2] += av * bv.z; acc[i][3] += av * bv.w;
        }
      }
    }
    __syncthreads();
  }
  #pragma unroll
  for (int j = 0; j < 4; j++)
    *(float4*)&sO[(tc * 4 + j) * 68 + tr * 4] = make_float4(acc[0][j], acc[1][j], acc[2][j], acc[3][j]);
  __syncthreads();
  {
    int c = tid >> 2, q = tid & 3;
    size_t base = (size_t)g * 64 * MT + (size_t)c * MT + t0 + q * 16;
    float* pB = &imgB[base];
    float* pA = &imgA[base];
    const float* pS = &sO[c * 68 + q * 16];
    #pragma unroll
    for (int v = 0; v < 4; v++){
      float4 d = *(const float4*)&pS[v * 4];
      float4 bb = *(const float4*)&pB[v * 4];
      bb.x += d.x; bb.y += d.y; bb.z += d.z; bb.w += d.w;
      *(float4*)&pB[v * 4] = bb;
      float4 aa = *(const float4*)&pA[v * 4];
      aa.x += bb.x; aa.y += bb.y; aa.z += bb.z; aa.w += bb.w;
      *(float4*)&pA[v * 4] = aa;
    }
  }
}

// ---------------- GCN layer 1 (K=512 GEMM over 4 bf16 ys streams) ----------------
__global__ __launch_bounds__(256) void k_gcn1(const u16* __restrict__ ys, const float* __restrict__ W1c,
                                              float* __restrict__ t1){
  int t0 = blockIdx.x * 64;
  __shared__ __align__(16) float sA[64 * 36];
  __shared__ __align__(16) float sB[32 * 132];
  int tid = threadIdx.x, tr = tid >> 4, tc = tid & 15;
  float acc[4][8];
  #pragma unroll
  for (int i = 0; i < 4; i++)
    #pragma unroll
    for (int j = 0; j < 8; j++) acc[i][j] = 0.f;

  for (int kt = 0; kt < 16; kt++){
    int str = kt >> 2, k0 = (kt & 3) * 32;
    const u16* Y = ys + (size_t)str * MT * 128;
    {
      int t = tid >> 2, f8 = (tid & 3) * 8;
      uint4 p = *(const uint4*)&Y[(size_t)(t0 + t) * 128 + k0 + f8];
      st8(&sA[t * 36 + f8], p);
    }
    {
      const float* Wc = W1c + ((size_t)str * 128 + k0) * 128;
      int kk = tid >> 3, f16 = (tid & 7) * 16;
      #pragma unroll
      for (int v = 0; v < 4; v++)
        *(float4*)&sB[kk * 132 + f16 + v * 4] = *(const float4*)&Wc[(size_t)kk * 128 + f16 + v * 4];
    }
    __syncthreads();
    #pragma unroll
    for (int k4 = 0; k4 < 32; k4 += 4){
      float4 a[4];
      #pragma unroll
      for (int i = 0; i < 4; i++) a[i] = *(const float4*)&sA[(tr * 4 + i) * 36 + k4];
      #pragma unroll
      for (int kk = 0; kk < 4; kk++){
        float4 b0 = *(const float4*)&sB[(k4 + kk) * 132 + tc * 8];
        float4 b1 = *(const float4*)&sB[(k4 + kk) * 132 + tc * 8 + 4];
        float bv[8] = {b0.x, b0.y, b0.z, b0.w, b1.x, b1.y, b1.z, b1.w};
        #pragma unroll
        for (int i = 0; i < 4; i++){
          float av = ((const float*)&a[i])[kk];
          #pragma unroll
          for (int j = 0; j < 8; j++) acc[i][j] += av * bv[j];
        }
      }
    }
    __syncthreads();
  }
  #pragma unroll
  for (int i = 0; i < 4; i++){
    size_t base = (size_t)(t0 + tr * 4 + i) * 128 + tc * 8;
    *(float4*)&t1[base]     = make_float4(acc[i][0], acc[i][1], acc[i][2], acc[i][3]);
    *(float4*)&t1[base + 4] = make_float4(acc[i][4], acc[i][5], acc[i][6], acc[i][7]);
  }
}

__global__ __launch_bounds__(128) void k_hub1(const float* __restrict__ t1, float* __restrict__ hubm){
  int f = threadIdx.x;
  float sum = 0.f;
  for (int hb = 0; hb < 450; hb++) sum += t1[(size_t)(hb * 32) * 128 + f];
  hubm[f] = sum * (1.f / 450.f);
}

__global__ __launch_bounds__(256) void k_gcn2(const float* __restrict__ t1, const float* __restrict__ hubm,
                                              const float* __restrict__ b1, const float* __restrict__ W2,
                                              float* __restrict__ t2){
  int t0 = blockIdx.x * 64;
  __shared__ __align__(16) float sA[64 * 36];
  __shared__ __align__(16) float sW[32 * 68];
  int tid = threadIdx.x, tr = tid >> 4, tc = tid & 15;
  float acc[4][4];
  #pragma unroll
  for (int i = 0; i < 4; i++){ acc[i][0]=0.f; acc[i][1]=0.f; acc[i][2]=0.f; acc[i][3]=0.f; }

  for (int kt = 0; kt < 4; kt++){
    int k0 = kt * 32;
    {
      int t = tid >> 2, f8 = (tid & 3) * 8;
      int l = t0 + t;
      const float* src = ((l & 31) == 0) ? &hubm[k0 + f8] : &t1[(size_t)l * 128 + k0 + f8];
      #pragma unroll
      for (int j = 0; j < 8; j++)
        sA[t * 36 + f8 + j] = fmaxf(src[j] + b1[k0 + f8 + j], 0.f);
    }
    {
      int c = tid >> 2, f8 = (tid & 3) * 8;
      const float* wr = &W2[(size_t)c * 128 + k0 + f8];
      #pragma unroll
      for (int j = 0; j < 8; j++) sW[(f8 + j) * 68 + c] = wr[j];
    }
    __syncthreads();
    #pragma unroll
    for (int k4 = 0; k4 < 32; k4 += 4){
      float4 a[4];
      #pragma unroll
      for (int i = 0; i < 4; i++) a[i] = *(const float4*)&sA[(tr * 4 + i) * 36 + k4];
      #pragma unroll
      for (int kk = 0; kk < 4; kk++){
        float4 bv = *(const float4*)&sW[(k4 + kk) * 68 + tc * 4];
        #pragma unroll
        for (int i = 0; i < 4; i++){
          float av = ((const float*)&a[i])[kk];
          acc[i][0] += av * bv.x; acc[i][1] += av * bv.y;
          acc[i][2] += av * bv.z; acc[i][3] += av * bv.w;
        }
      }
    }
    __syncthreads();
  }
  #pragma unroll
  for (int i = 0; i < 4; i++)
    *(float4*)&t2[(size_t)(t0 + tr * 4 + i) * 64 + tc * 4] = make_float4(acc[i][0], acc[i][1], acc[i][2], acc[i][3]);
}

__global__ __launch_bounds__(64) void k_hub2(const float* __restrict__ t2, float* __restrict__ hubm2){
  int c = threadIdx.x;
  float sum = 0.f;
  for (int hb = 0; hb < 450; hb++) sum += t2[(size_t)(hb * 32) * 64 + c];
  hubm2[c] = sum * (1.f / 450.f);
}

__global__ __launch_bounds__(256) void k_final(const void* __restrict__ x, const float* __restrict__ t2,
                                               const float* __restrict__ hubm2, const float* __restrict__ b2,
                                               const float* __restrict__ imgA, void* __restrict__ out,
                                               const int* __restrict__ flag){
  int idx = blockIdx.x * 256 + threadIdx.x;
  int l = idx % MT, c = idx / MT;
  int fp32 = *flag;
  float gval = (((l & 31) == 0) ? hubm2[c] : t2[(size_t)l * 64 + c]) + b2[c];
  float a0 = imgA[idx];
  float a1 = imgA[(size_t)64 * MT + (size_t)c * MT + (l % 120) * 120 + l / 120];
  float xv = fp32 ? ((const float*)x)[idx] : b2f(((const u16*)x)[idx]);
  float val = gval + xv + a0 + a1;
  if (fp32) ((float*)out)[idx] = val;
  else      ((u16*)out)[idx] = f2b(val);
}

extern "C" void kernel_launch(void* const* d_in, const int* in_sizes, int n_in,
                              void* d_out, int out_size, void* d_ws, size_t ws_size,
                              hipStream_t stream){
  int I_X=0,I_PIW=1,I_PCW=2,I_PCB=3,I_PXP=4,I_PDTW=5,I_PDTB=6,I_PAL=7,I_PD=8,I_PLG=9,I_PLB=10,
      I_WIW=11,I_WCW=12,I_WCB=13,I_WXP=14,I_WDTW=15,I_WDTB=16,I_WAL=17,I_WD=18,I_WLG=19,I_WLB=20,
      I_POW=21,I_WOW=22,I_WOBW=23,I_G1=24,I_GB1=25,I_G2=26,I_GB2=27;
  if (n_in >= 28 && in_sizes[9] == 131072){
    I_WIW=9;I_WCW=10;I_WCB=11;I_WXP=12;I_WDTW=13;I_WDTB=14;I_WAL=15;I_WD=16;
    I_PLG=17;I_PLB=18;I_WLG=19;I_WLB=20;
  }
  if (n_in < 28 || in_sizes[I_PIW] != 131072 || out_size != 921600) return;

  float* Wp = (float*)d_ws;
  size_t off = 0;
  auto alloc = [&](size_t n){ size_t r = off; off += (n + 63) & ~(size_t)63; return r; };
  size_t oFlag=alloc(64);
  size_t oPIW=alloc(131072), oPCW=alloc(4096), oPCB=alloc(1024), oPXP=alloc(36864),
         oPDTW=alloc(4096), oPDTB=alloc(1024), oPA=alloc(16384), oPD=alloc(1024),
         oPLG=alloc(256), oPLB=alloc(256);
  size_t oWIW=alloc(131072), oWCW=alloc(4096), oWCB=alloc(1024), oWXP=alloc(36864),
         oWDTW=alloc(4096), oWDTB=alloc(1024), oWA=alloc(16384), oWD=alloc(1024),
         oWLG=alloc(256), oWLB=alloc(256);
  size_t oPOW=alloc(32768), oWOW=alloc(32768), oWOBW=alloc(32768),
         oG1=alloc(32768), oGB1=alloc(128), oG2=alloc(8192), oGB2=alloc(64);
  size_t oPIWT=alloc(131072), oWIWT=alloc(131072), oW1C=alloc(65536);
  size_t oImgA=alloc(2UL*64*MT), oImgB=alloc(2UL*64*MT);
  size_t oRaw=alloc(2UL*MT*128);             // bf16; aliased as ys
  size_t oZ=alloc(2UL*MT*128), oXhs=alloc(2UL*MT*128), oDelta=alloc(2UL*MT*128);
  size_t oBm=alloc(2UL*MT*16), oCm=alloc(2UL*MT*16);
  size_t oAc=alloc(4UL*WNC*2048), oBc=alloc(4UL*WNC*2048), oHin=alloc(4UL*WNC*2048);
  size_t oT1=alloc((size_t)MT*128), oHub1=alloc(128), oT2=alloc((size_t)MT*64), oHub2=alloc(64);
  if (ws_size < off * sizeof(float)) return;

  int* flag = (int*)(Wp + oFlag);
  k_detect<<<dim3(1), dim3(256), 0, stream>>>((const u16*)d_in[I_PAL], 16384, flag);

  PTab tb;
  int ti = 0;
  auto add = [&](int inIdx, size_t o, int n, int neg){
    tb.src[ti] = d_in[inIdx]; tb.dst[ti] = Wp + o; tb.n[ti] = n; tb.neg[ti] = neg; ti++;
  };
  add(I_PIW,oPIW,131072,0); add(I_PCW,oPCW,4096,0); add(I_PCB,oPCB,1024,0); add(I_PXP,oPXP,36864,0);
  add(I_PDTW,oPDTW,4096,0); add(I_PDTB,oPDTB,1024,0); add(I_PAL,oPA,16384,1); add(I_PD,oPD,1024,0);
  add(I_PLG,oPLG,256,0); add(I_PLB,oPLB,256,0);
  add(I_WIW,oWIW,131072,0); add(I_WCW,oWCW,4096,0); add(I_WCB,oWCB,1024,0); add(I_WXP,oWXP,36864,0);
  add(I_WDTW,oWDTW,4096,0); add(I_WDTB,oWDTB,1024,0); add(I_WAL,oWA,16384,1); add(I_WD,oWD,1024,0);
  add(I_WLG,oWLG,256,0); add(I_WLB,oWLB,256,0);
  add(I_POW,oPOW,32768,0); add(I_WOW,oWOW,32768,0); add(I_WOBW,oWOBW,32768,0);
  add(I_G1,oG1,32768,0); add(I_GB1,oGB1,128,0); add(I_G2,oG2,8192,0); add(I_GB2,oGB2,64,0);

  k_cvt<<<dim3(128, 27), dim3(256), 0, stream>>>(tb, flag);
  k_wtrans<<<dim3(64, 16), dim3(256), 0, stream>>>(Wp+oPIW, Wp+oWIW, Wp+oPIWT, Wp+oWIWT);
  k_gcn1w<<<dim3(64, 4), dim3(256), 0, stream>>>(Wp+oWOW, Wp+oWOBW, Wp+oG1, Wp+oW1C);
  k_cvt_x<<<dim3(3600), dim3(256), 0, stream>>>(d_in[I_X], Wp + oImgA, flag);

  float *imgA = Wp+oImgA, *imgB = Wp+oImgB,
        *Ac = Wp+oAc, *Bc = Wp+oBc, *Hin = Wp+oHin;
  u16 *raw = (u16*)(Wp+oRaw), *ys = (u16*)(Wp+oRaw),
      *zz = (u16*)(Wp+oZ), *xhs = (u16*)(Wp+oXhs), *delta = (u16*)(Wp+oDelta),
      *Bm = (u16*)(Wp+oBm), *Cm = (u16*)(Wp+oCm);

  for (int s = 0; s < 2; s++){
    // ---- pixel stage ----
    k_inproj<<<dim3(450, 4), dim3(256), 0, stream>>>(imgA, Wp+oPLG, Wp+oPLB, Wp+oPIWT, raw, zz, s, 1);
    k_xproj <<<dim3(225, 4), dim3(256), 0, stream>>>(raw, Wp+oPCW, Wp+oPCB, Wp+oPXP, Wp+oPDTW, Wp+oPDTB,
                                                     delta, Bm, Cm, xhs, s, 1);
    k_scan_p1<<<dim3(WNC, 4), dim3(256), 0, stream>>>(delta, xhs, Bm, Wp+oPA, Ac, Bc, s);
    k_scan_p2<<<dim3(32), dim3(256), 0, stream>>>(Ac, Bc, Hin, 12);
    k_scan_p3<<<dim3(WNC, 4), dim3(256), 0, stream>>>(delta, xhs, Bm, Cm, zz, Wp+oPA, Wp+oPD, Hin, ys, s);
    k_outproj_pixel<<<dim3(225, 2), dim3(256), 0, stream>>>(ys, Wp+oPOW, imgA, imgB, s);

    // ---- window stage ----
    k_inproj<<<dim3(450, 4), dim3(256), 0, stream>>>(imgB, Wp+oWLG, Wp+oWLB, Wp+oWIWT, raw, zz, s, 0);
    k_xproj <<<dim3(225, 4), dim3(256), 0, stream>>>(raw, Wp+oWCW, Wp+oWCB, Wp+oWXP, Wp+oWDTW, Wp+oWDTB,
                                                     delta, Bm, Cm, xhs, s, 0);
    k_scan_p1<<<dim3(WNC, 4), dim3(256), 0, stream>>>(delta, xhs, Bm, Wp+oWA, Ac, Bc, s);
    k_scan_p2<<<dim3(32), dim3(256), 0, stream>>>(Ac, Bc, Hin, WNC);
    k_scan_p3<<<dim3(WNC, 4), dim3(256), 0, stream>>>(delta, xhs, Bm, Cm, zz, Wp+oWA, Wp+oWD, Hin, ys, s);
    k_outproj_win<<<dim3(225, 2), dim3(256), 0, stream>>>(ys, Wp+oWOW, imgA, imgB, s);
  }

  k_gcn1<<<dim3(225), dim3(256), 0, stream>>>(ys, Wp+oW1C, Wp+oT1);
  k_hub1<<<dim3(1), dim3(128), 0, stream>>>(Wp+oT1, Wp+oHub1);
  k_gcn2<<<dim3(225), dim3(256), 0, stream>>>(Wp+oT1, Wp+oHub1, Wp+oGB1, Wp+oG2, Wp+oT2);
  k_hub2<<<dim3(1), dim3(64), 0, stream>>>(Wp+oT2, Wp+oHub2);
  k_final<<<dim3(3600), dim3(256), 0, stream>>>(d_in[I_X], Wp+oT2, Wp+oHub2, Wp+oGB2, imgA, d_out, flag);
}